// Round 7
// baseline (1774.967 us; speedup 1.0000x reference)
//
#include <hip/hip_runtime.h>
#include <math.h>

#define NB   256
#define ND   63
#define NN   3969        // 63*63
#define MIDc 32

__device__ __forceinline__ float gelu_f(float v){
    return 0.5f * v * (1.0f + erff(v * 0.70710678118654752440f));
}

#define FMA4(A, W, S) { (A).x=fmaf((W).x,(S),(A).x); (A).y=fmaf((W).y,(S),(A).y); \
                        (A).z=fmaf((W).z,(S),(A).z); (A).w=fmaf((W).w,(S),(A).w); }

union F4 { float4 v; float a[4]; };
union W16 { float4 v[4]; float a[16]; };

// ---------------- DFT tables (64x64, row/col 63 zeroed) + acc reset ----------
__global__ void k_tables(float* __restrict__ Fr, float* __restrict__ Fi, float* __restrict__ acc){
    int idx = blockIdx.x * blockDim.x + threadIdx.x;
    if (idx < 4096){
        int r = idx >> 6, c = idx & 63;
        float vr = 0.f, vi = 0.f;
        if (r < 63 && c < 63){
            int m = (r * c) % 63;
            float ang = 6.283185307179586f * (float)m / 63.0f;
            vr = cosf(ang); vi = -sinf(ang);
        }
        Fr[idx] = vr; Fi[idx] = vi;
    }
    if (idx == 0) acc[0] = 0.f;
}

// -------- weight prep ---------------------------------------------------------
__global__ void k_wprep(const float* __restrict__ w1, const float* __restrict__ w2,
                        const float* __restrict__ w3, const float* __restrict__ w4,
                        const float* __restrict__ w5,
                        float* __restrict__ o1, float* __restrict__ o2,
                        float* __restrict__ o3, float* __restrict__ o4,
                        float* __restrict__ o5){
    int idx = blockIdx.x * blockDim.x + threadIdx.x;
    if (idx < 9216){
        int co = idx & 31, t = idx >> 5;
        int ci = t & 31, tap = t >> 5;
        int ky = tap / 3, kx = tap % 3;
        int src = ((ci*32 + co)*3 + ky)*3 + kx;
        o2[idx] = w2[src]; o3[idx] = w3[src]; o4[idx] = w4[src];
    }
    if (idx < 576){
        int co = idx & 1, t = idx >> 1;
        int ci = t & 31, tap = t >> 5;
        int ky = tap / 3, kx = tap % 3;
        o5[idx] = w5[((ci*2 + co)*3 + ky)*3 + kx];
    }
    if (idx < 288){
        int co = idx & 31, tap = idx >> 5;
        int ky = tap / 3, kx = tap % 3;
        o1[idx] = w1[(co*3 + ky)*3 + kx];
    }
}

// ---------------- hypernet ----------------------------------------------------
__global__ void k_hyper(const float* __restrict__ kA,
                        const float* __restrict__ w1a, const float* __restrict__ b1a,
                        const float* __restrict__ w2a, const float* __restrict__ b2a,
                        const float* __restrict__ w1b, const float* __restrict__ b1b,
                        const float* __restrict__ w2b, const float* __restrict__ b2b,
                        float* __restrict__ out1, float* __restrict__ out2){
    __shared__ float a[9];
    __shared__ float hid[100];
    int b = blockIdx.x, tid = threadIdx.x;
    if (tid < 9) a[tid] = kA[b*9 + tid];
    __syncthreads();
    if (tid < 100){
        float s = b1a[tid];
        #pragma unroll
        for (int i = 0; i < 9; i++) s = fmaf(a[i], w1a[i*100 + tid], s);
        hid[tid] = gelu_f(s);
    }
    __syncthreads();
    if (tid < 147){
        float s = b2a[tid];
        for (int k = 0; k < 100; k++) s = fmaf(hid[k], w2a[k*147 + tid], s);
        out1[b*147 + tid] = s;
    }
    __syncthreads();
    if (tid < 100){
        float s = b1b[tid];
        #pragma unroll
        for (int i = 0; i < 9; i++) s = fmaf(a[i], w1b[i*100 + tid], s);
        hid[tid] = gelu_f(s);
    }
    __syncthreads();
    if (tid < 147){
        float s = b2b[tid];
        for (int k = 0; k < 100; k++) s = fmaf(hid[k], w2b[k*147 + tid], s);
        out2[b*147 + tid] = s;
    }
}

// ---------------- ct1: 1->32, channel-last out --------------------------------
__global__ void k_ct1c(const float* __restrict__ kA, const float* __restrict__ wT1,
                       const float* __restrict__ bias, float* __restrict__ out){
    int idx = blockIdx.x * blockDim.x + threadIdx.x;
    if (idx >= NB*25) return;
    int p = idx % 25, b = idx / 25;
    int oy = p / 5, ox = p % 5;
    F4 acc[8];
    #pragma unroll
    for (int q = 0; q < 8; q++) acc[q].v = ((const float4*)bias)[q];
    int nky, kyA[2], iyA[2];
    if (oy & 1){ nky=2; kyA[0]=0; iyA[0]=(oy+1)/2; kyA[1]=2; iyA[1]=(oy-1)/2; }
    else       { nky=1; kyA[0]=1; iyA[0]=oy/2; kyA[1]=1; iyA[1]=0; }
    int nkx, kxA[2], ixA[2];
    if (ox & 1){ nkx=2; kxA[0]=0; ixA[0]=(ox+1)/2; kxA[1]=2; ixA[1]=(ox-1)/2; }
    else       { nkx=1; kxA[0]=1; ixA[0]=ox/2; kxA[1]=1; ixA[1]=0; }
    const float* ab = kA + b*9;
    for (int yi = 0; yi < nky; yi++)
    for (int xi = 0; xi < nkx; xi++){
        float v = ab[iyA[yi]*3 + ixA[xi]];
        const float4* wq = (const float4*)(wT1 + (kyA[yi]*3 + kxA[xi])*32);
        #pragma unroll
        for (int q = 0; q < 8; q++){ float4 w = wq[q]; FMA4(acc[q].v, w, v); }
    }
    float* ob = out + (size_t)idx*32;
    #pragma unroll
    for (int q = 0; q < 8; q++){
        float4 g; g.x=gelu_f(acc[q].a[0]); g.y=gelu_f(acc[q].a[1]);
        g.z=gelu_f(acc[q].a[2]); g.w=gelu_f(acc[q].a[3]);
        ((float4*)ob)[q] = g;
    }
}

// ------------- ct 32->32, stride2 pad1 k3, gelu, channel-last. 2 blocks/sample.
template<int HIN>
__global__ __launch_bounds__(512) void k_ct32c(const float* __restrict__ in,
                                               const float* __restrict__ wT,
                                               const float* __restrict__ bias,
                                               float* __restrict__ out){
    constexpr int HOUT = 2*HIN - 1;
    constexpr int HINP = (HIN + 3) & ~3;
    constexpr int OCT  = (HOUT + 7) / 8;
    constexpr int UPR  = OCT * 4;
    constexpr int NODD = (HOUT/2) * UPR;
    constexpr int TOT  = HOUT * UPR;
    constexpr int HT   = (TOT + 1) / 2;
    constexpr int INEL = 32*HIN*HINP;
    __shared__ __align__(16) float lds[INEL + 9216 + 32];
    float* in_s   = lds;
    float* w_s    = lds + INEL;
    float* bias_s = lds + INEL + 9216;
    const int b = blockIdx.x >> 1, h = blockIdx.x & 1;
    const int tid = threadIdx.x;
    { const float4* src = (const float4*)wT; float4* dst = (float4*)w_s;
      for (int i = tid; i < 2304; i += 512) dst[i] = src[i]; }
    if (tid < 32) bias_s[tid] = bias[tid];
    { const float* gi = in + (size_t)b * (32*HIN*HIN);
      for (int i = tid; i < 32*HIN*HIN; i += 512){
        int ci = i & 31, px = i >> 5;
        int y = px / HIN, x = px % HIN;
        in_s[ci*(HIN*HINP) + y*HINP + x] = gi[i];
      } }
    __syncthreads();
    float* ob0 = out + (size_t)b*(HOUT*HOUT*32);
    const int u0 = h*HT, u1 = (u0 + HT < TOT) ? (u0 + HT) : TOT;
    for (int u = u0 + tid; u < u1; u += 512){
        int r, s;
        if (u < NODD){ r = 2*(u/UPR) + 1; s = u % UPR; }
        else { int v = u - NODD; r = 2*(v/UPR); s = v % UPR; }
        const int m = s >> 2, cog = s & 3;
        const int x4 = 4*m;
        F4 acc[8][2];
        { float4 b0 = ((const float4*)bias_s)[cog*2];
          float4 b1 = ((const float4*)bias_s)[cog*2+1];
          #pragma unroll
          for (int p = 0; p < 8; p++){ acc[p][0].v = b0; acc[p][1].v = b1; } }
        int nky, kyA[2], iyA[2];
        if (r & 1){ int rI = r >> 1; nky = 2; kyA[0]=0; iyA[0]=rI+1; kyA[1]=2; iyA[1]=rI; }
        else      { nky = 1; kyA[0]=1; iyA[0]= r >> 1; kyA[1]=1; iyA[1]=0; }
        for (int yi = 0; yi < nky; yi++){
            const float* ip = in_s + iyA[yi]*HINP + x4;
            const float* wp = w_s + kyA[yi]*3*1024 + cog*8;
            #pragma unroll 2
            for (int ci = 0; ci < 32; ci++){
                F4 iv0, iv1;
                iv0.v = *(const float4*)(ip);
                iv1.v = *(const float4*)(ip + 4);
                float4 w0a = *(const float4*)(wp);
                float4 w0b = *(const float4*)(wp + 4);
                float4 w1a = *(const float4*)(wp + 1024);
                float4 w1b = *(const float4*)(wp + 1028);
                float4 w2a = *(const float4*)(wp + 2048);
                float4 w2b = *(const float4*)(wp + 2052);
                #pragma unroll
                for (int p = 0; p < 4; p++){
                    float ev = iv0.a[p];
                    FMA4(acc[2*p][0].v, w1a, ev);
                    FMA4(acc[2*p][1].v, w1b, ev);
                    float o0 = (p < 3) ? iv0.a[p+1] : iv1.a[0];
                    FMA4(acc[2*p+1][0].v, w0a, o0);
                    FMA4(acc[2*p+1][1].v, w0b, o0);
                    FMA4(acc[2*p+1][0].v, w2a, ev);
                    FMA4(acc[2*p+1][1].v, w2b, ev);
                }
                ip += HIN*HINP;
                wp += 32;
            }
        }
        int lim = HOUT - 8*m; if (lim > 8) lim = 8;
        float* ob = ob0 + ((size_t)r*HOUT + 8*m)*32 + cog*8;
        for (int e = 0; e < lim; e++){
            float4 g0, g1;
            g0.x=gelu_f(acc[e][0].a[0]); g0.y=gelu_f(acc[e][0].a[1]);
            g0.z=gelu_f(acc[e][0].a[2]); g0.w=gelu_f(acc[e][0].a[3]);
            g1.x=gelu_f(acc[e][1].a[0]); g1.y=gelu_f(acc[e][1].a[1]);
            g1.z=gelu_f(acc[e][1].a[2]); g1.w=gelu_f(acc[e][1].a[3]);
            *(float4*)(ob + (size_t)e*32)     = g0;
            *(float4*)(ob + (size_t)e*32 + 4) = g1;
        }
    }
}

// ---- ct5 (32->2) + build v rows 0..31 (interleaved) + dv --------------------
__global__ __launch_bounds__(512) void k_ct5v(const float* __restrict__ in,
                                              const float* __restrict__ wT5,
                                              const float* __restrict__ bias,
                                              float* __restrict__ vcg,
                                              float* __restrict__ dvg){
    __shared__ float ws5[576];
    __shared__ float c5s[2*NN];
    const int b = blockIdx.x, tid = threadIdx.x;
    for (int i = tid; i < 576; i += 512) ws5[i] = wT5[i];
    __syncthreads();
    const float* ib = in + (size_t)b * (32*33*33);
    float b0 = bias[0], b1 = bias[1];
    for (int p = tid; p < NN; p += 512){
        int oy = p / ND, ox = p % ND;
        float a0 = b0, a1 = b1;
        int nky, kyA[2], iyA[2];
        if ((oy & 1) == 0){ nky=2; kyA[0]=0; iyA[0]=oy/2+1; kyA[1]=2; iyA[1]=oy/2; }
        else              { nky=1; kyA[0]=1; iyA[0]=(oy+1)/2; kyA[1]=1; iyA[1]=0; }
        int nkx, kxA[2], ixA[2];
        if ((ox & 1) == 0){ nkx=2; kxA[0]=0; ixA[0]=ox/2+1; kxA[1]=2; ixA[1]=ox/2; }
        else              { nkx=1; kxA[0]=1; ixA[0]=(ox+1)/2; kxA[1]=1; ixA[1]=0; }
        for (int yi = 0; yi < nky; yi++)
        for (int xi = 0; xi < nkx; xi++){
            const float* ip = ib + ((size_t)iyA[yi]*33 + ixA[xi])*32;
            const float* wp = ws5 + (kyA[yi]*3 + kxA[xi])*64;
            #pragma unroll
            for (int g = 0; g < 8; g++){
                F4 iv; iv.v = *(const float4*)(ip + 4*g);
                #pragma unroll
                for (int q = 0; q < 4; q++){
                    int ci = 4*g + q;
                    a0 = fmaf(iv.a[q], wp[ci*2],   a0);
                    a1 = fmaf(iv.a[q], wp[ci*2+1], a1);
                }
            }
        }
        c5s[p]      = a0;
        c5s[NN + p] = a1;
    }
    __syncthreads();
    const float sc = 1.0f / 3969.0f;
    float4* vc4 = (float4*)vcg;
    for (int i = tid; i < 1024; i += 512){
        int ky = i >> 5, ct2 = i & 31;
        float4 o;
        #pragma unroll
        for (int j = 0; j < 2; j++){
            int kx = 2*ct2 + j;
            float re = 0.f, im = 0.f;
            if (kx <= 31){ int o2 = 2*(ky*ND + kx); re = c5s[o2]*sc; im = c5s[o2+1]*sc; }
            else if (kx <= 62){
                int sy = (ND - ky) % ND, sx = ND - kx;
                int o2 = 2*(sy*ND + sx); re = c5s[o2]*sc; im = -c5s[o2+1]*sc;
            }
            if (j == 0){ o.x = re; o.y = im; } else { o.z = re; o.w = im; }
        }
        vc4[(size_t)b*1024 + i] = o;
    }
    if (tid < 32){
        float2* dv2 = (float2*)dvg;
        float2 d = {0.f, 0.f};
        if (tid >= 1){
            int iA = (ND - tid) * ND, iB = tid * ND;
            d.x = (c5s[2*iA]     - c5s[2*iB])     * sc;
            d.y = (c5s[2*iA + 1] + c5s[2*iB + 1]) * sc;
        }
        dv2[b*32 + tid] = d;
    }
}

// ---------------- mega solver, 1024 threads, Hermitian-halved DFT ------------
// NOTE: no min-waves arg — (1024,4) capped VGPR at 64 and spilled 3.9 GB (r6).
__global__ __launch_bounds__(1024) void k_solve(const float* __restrict__ x0g,
                                                const float* __restrict__ f,
                                                const float* __restrict__ kAg,
                                                const float* __restrict__ w1g,
                                                const float* __restrict__ w2g,
                                                const float* __restrict__ Frg,
                                                const float* __restrict__ Fig,
                                                const float* __restrict__ vcg,
                                                const float* __restrict__ dvg,
                                                float* __restrict__ accg){
    __shared__ __align__(16) float xs[63*68 + 4];    // stride 68, cols 63.. pad
    __shared__ __align__(16) float U[8576];          // union: rs+tc | rP,TtC,MC,CC
    __shared__ float w1s[148], w2s[148], dvs[64], ds_r[32], ds_i[32], red[16];
    const int b = blockIdx.x, tid = threadIdx.x;
    float* rs = U;                       // 63*68
    float* tc = U + 4284;                // 63*68
    float*  rP  = U;                     // 64x64
    float2* TtC = (float2*)(U + 4096);   // 64 x 32 f2, swizzled cols
    float2* MC2 = (float2*)U;            // 32 x 64 f2
    float4* MC4 = (float4*)U;
    float4* CC4 = (float4*)(U + 4096);   // 32 x 33 f4
    float2* rP2 = (float2*)U;
    const float* fg = f + (size_t)b*NN;
    float ka[9];
    #pragma unroll
    for (int i = 0; i < 9; i++) ka[i] = kAg[b*9 + i];
    if (tid < 147){ w1s[tid] = w1g[b*147 + tid]; w2s[tid] = w2g[b*147 + tid]; }
    if (tid < 64) dvs[tid] = dvg[b*64 + tid];
    for (int i = tid; i < NN; i += 1024) xs[(i/ND)*68 + (i%ND)] = x0g[(size_t)b*NN + i];
    __syncthreads();

    const int kt5 = tid >> 5, ct2 = tid & 31;      // DFT A/B/D tiling
    const int pE  = tid >> 4, ctE = tid & 15;      // phase E tiling

    for (int it = 0; it < 5; it++){
        // ---- zero union (smoother halos) ----
        { float4 z = {0.f,0.f,0.f,0.f}; float4* U4 = (float4*)U;
          for (int i = tid; i < 2144; i += 1024) U4[i] = z; }
        __syncthreads();
        // ---- residual -> rs (col c at idx c+4) ----
        for (int i = tid; i < NN; i += 1024){
            int y = i / ND, xx = i % ND;
            float s = 0.f;
            #pragma unroll
            for (int dy = 0; dy < 3; dy++){
                int u = y + dy;
                #pragma unroll
                for (int dx = 0; dx < 3; dx++){
                    int v = xx + dx;
                    float p;
                    if (u == 64 || v == 64)    p = 1.0f;
                    else if (u == 0 || v == 0) p = 0.0f;
                    else                       p = xs[(u-1)*68 + (v-1)];
                    s = fmaf(p, ka[dy*3 + dx], s);
                }
            }
            rs[y*68 + 4 + xx] = fg[i] - s;
        }
        __syncthreads();
        // ---- smoother: 2-row x 8-px units, 256 active lanes ----
        const bool act = tid < 256;
        const int rg = tid >> 3, x0c = 8*(tid & 7);
        const int r0 = 2*rg;
        float acc2[2][8] = {};
        for (int c = 0; c < 3; c++){
            if (act){
                float a1[2][8] = {};
                #pragma unroll
                for (int wy = 0; wy < 8; wy++){
                    int ry = r0 - 3 + wy;
                    W16 w; w.v[0]=w.v[1]=w.v[2]=w.v[3] = make_float4(0.f,0.f,0.f,0.f);
                    if (ry >= 0 && ry <= 62){
                        const float4* rp = (const float4*)(rs + ry*68 + x0c);
                        w.v[0]=rp[0]; w.v[1]=rp[1]; w.v[2]=rp[2]; w.v[3]=rp[3];
                    }
                    if (wy <= 6){
                        #pragma unroll
                        for (int dx = 0; dx < 7; dx++){
                            float wv = w1s[c*49 + wy*7 + dx];
                            #pragma unroll
                            for (int t = 0; t < 8; t++) a1[0][t] = fmaf(wv, w.a[t+dx+1], a1[0][t]);
                        }
                    }
                    if (wy >= 1){
                        #pragma unroll
                        for (int dx = 0; dx < 7; dx++){
                            float wv = w1s[c*49 + (wy-1)*7 + dx];
                            #pragma unroll
                            for (int t = 0; t < 8; t++) a1[1][t] = fmaf(wv, w.a[t+dx+1], a1[1][t]);
                        }
                    }
                }
                if (x0c == 56){ a1[0][7] = 0.f; a1[1][7] = 0.f; }
                #pragma unroll
                for (int rr = 0; rr < 2; rr++){
                    int r = r0 + rr;
                    if (r <= 62){
                        float4* tp = (float4*)(tc + r*68 + 4 + x0c);
                        tp[0] = make_float4(a1[rr][0],a1[rr][1],a1[rr][2],a1[rr][3]);
                        tp[1] = make_float4(a1[rr][4],a1[rr][5],a1[rr][6],a1[rr][7]);
                    }
                }
            }
            __syncthreads();
            if (act){
                #pragma unroll
                for (int wy = 0; wy < 8; wy++){
                    int ry = r0 - 3 + wy;
                    W16 w; w.v[0]=w.v[1]=w.v[2]=w.v[3] = make_float4(0.f,0.f,0.f,0.f);
                    if (ry >= 0 && ry <= 62){
                        const float4* tp = (const float4*)(tc + ry*68 + x0c);
                        w.v[0]=tp[0]; w.v[1]=tp[1]; w.v[2]=tp[2]; w.v[3]=tp[3];
                    }
                    if (wy <= 6){
                        #pragma unroll
                        for (int dx = 0; dx < 7; dx++){
                            float wv = w2s[c*49 + wy*7 + dx];
                            #pragma unroll
                            for (int t = 0; t < 8; t++) acc2[0][t] = fmaf(wv, w.a[t+dx+1], acc2[0][t]);
                        }
                    }
                    if (wy >= 1){
                        #pragma unroll
                        for (int dx = 0; dx < 7; dx++){
                            float wv = w2s[c*49 + (wy-1)*7 + dx];
                            #pragma unroll
                            for (int t = 0; t < 8; t++) acc2[1][t] = fmaf(wv, w.a[t+dx+1], acc2[1][t]);
                        }
                    }
                }
            }
            __syncthreads();
        }
        if (act){
            #pragma unroll
            for (int rr = 0; rr < 2; rr++){
                int r = r0 + rr;
                if (r <= 62){
                    float4* xp = (float4*)(xs + r*68 + x0c);
                    float4 x0v = xp[0], x1v = xp[1];
                    x0v.x += acc2[rr][0]; x0v.y += acc2[rr][1];
                    x0v.z += acc2[rr][2]; x0v.w += acc2[rr][3];
                    x1v.x += acc2[rr][4]; x1v.y += acc2[rr][5];
                    x1v.z += acc2[rr][6]; x1v.w += acc2[rr][7];
                    xp[0] = x0v; xp[1] = x1v;
                }
            }
        }
        __syncthreads();
        // ---- residual of updated x -> rP (64x64, zero pad) ----
        for (int i = tid; i < 4096; i += 1024){
            int y = i >> 6, xx = i & 63;
            float val = 0.f;
            if (y < 63 && xx < 63){
                float s = 0.f;
                #pragma unroll
                for (int dy = 0; dy < 3; dy++){
                    int u = y + dy;
                    #pragma unroll
                    for (int dx = 0; dx < 3; dx++){
                        int v = xx + dx;
                        float p;
                        if (u == 64 || v == 64)    p = 1.0f;
                        else if (u == 0 || v == 0) p = 0.0f;
                        else                       p = xs[(u-1)*68 + (v-1)];
                        s = fmaf(p, ka[dy*3 + dx], s);
                    }
                }
                val = fg[y*ND + xx] - s;
            }
            rP[i] = val;
        }
        __syncthreads();
        // ---- Phase A: T[k,c] = sum_m F[k,m] r[m,c], k=0..31 ----
        {
            float t0r=0.f,t0i=0.f,t1r=0.f,t1i=0.f;
            for (int m = 0; m < 63; m++){
                float fr = Frg[m*64 + kt5], fi = Fig[m*64 + kt5];
                float2 rv = rP2[m*32 + ct2];
                t0r = fmaf(fr, rv.x, t0r); t0i = fmaf(fi, rv.x, t0i);
                t1r = fmaf(fr, rv.y, t1r); t1i = fmaf(fi, rv.y, t1i);
            }
            int c0 = 2*ct2;
            TtC[c0*32     + ((kt5 + c0)     & 31)] = make_float2(t0r, t0i);
            TtC[(c0+1)*32 + ((kt5 + c0 + 1) & 31)] = make_float2(t1r, t1i);
        }
        __syncthreads();
        // ---- Phase B: R = T F (rows 0..31), M = R.*v ; d-vector ----
        {
            float R0r=0.f,R0i=0.f,R1r=0.f,R1i=0.f;
            const float2* F2r = (const float2*)Frg;
            const float2* F2i = (const float2*)Fig;
            for (int n = 0; n < 63; n++){
                float2 T = TtC[n*32 + ((kt5 + n) & 31)];
                float2 fr = F2r[n*32 + ct2], fi = F2i[n*32 + ct2];
                R0r = fmaf(T.x, fr.x, R0r); R0r = fmaf(-T.y, fi.x, R0r);
                R0i = fmaf(T.x, fi.x, R0i); R0i = fmaf( T.y, fr.x, R0i);
                R1r = fmaf(T.x, fr.y, R1r); R1r = fmaf(-T.y, fi.y, R1r);
                R1i = fmaf(T.x, fi.y, R1i); R1i = fmaf( T.y, fr.y, R1i);
            }
            if (ct2 == 0){
                float2 dv = ((const float2*)dvs)[kt5];
                ds_r[kt5] = R0r*dv.x + R0i*dv.y;
                ds_i[kt5] = R0r*dv.y - R0i*dv.x;
            }
            float4 vv = ((const float4*)vcg)[(size_t)b*1024 + kt5*32 + ct2];
            float4 Mv;
            Mv.x = R0r*vv.x - R0i*vv.y;  Mv.y = R0r*vv.y + R0i*vv.x;
            Mv.z = R1r*vv.z - R1i*vv.w;  Mv.w = R1r*vv.w + R1i*vv.z;
            MC4[kt5*32 + ct2] = Mv;
        }
        __syncthreads();
        // ---- Phase D: C[n,q] = sum_l M[n,l] conj(F[l,q]), n=0..31 ----
        {
            float C0r=0.f,C0i=0.f,C1r=0.f,C1i=0.f;
            const float2* F2r = (const float2*)Frg;
            const float2* F2i = (const float2*)Fig;
            for (int l = 0; l < 63; l++){
                float2 Mv = MC2[kt5*64 + l];
                float2 fr = F2r[l*32 + ct2], fi = F2i[l*32 + ct2];
                C0r = fmaf(Mv.x, fr.x, C0r); C0r = fmaf( Mv.y, fi.x, C0r);
                C0i = fmaf(Mv.y, fr.x, C0i); C0i = fmaf(-Mv.x, fi.x, C0i);
                C1r = fmaf(Mv.x, fr.y, C1r); C1r = fmaf( Mv.y, fi.y, C1r);
                C1i = fmaf(Mv.y, fr.y, C1i); C1i = fmaf(-Mv.x, fi.y, C1i);
            }
            float scale = (kt5 == 0) ? 0.5f : 1.0f;
            CC4[kt5*33 + ct2] = make_float4(C0r*scale, C0i*scale, C1r*scale, C1i*scale);
        }
        __syncthreads();
        // ---- Phase E: y[p,q] = 2 sum_n (Fr*Cr + Fi*Ci) + e[p]; xs += y ----
        if (pE < 63){
            float yv0=0.f,yv1=0.f,yv2=0.f,yv3=0.f,e=0.f;
            for (int n = 0; n < 32; n++){
                float fr = Frg[n*64 + pE], fi = Fig[n*64 + pE];
                float4 cA = CC4[n*33 + 2*ctE];
                float4 cB = CC4[n*33 + 2*ctE + 1];
                yv0 = fmaf(fr, cA.x, yv0); yv0 = fmaf(fi, cA.y, yv0);
                yv1 = fmaf(fr, cA.z, yv1); yv1 = fmaf(fi, cA.w, yv1);
                yv2 = fmaf(fr, cB.x, yv2); yv2 = fmaf(fi, cB.y, yv2);
                yv3 = fmaf(fr, cB.z, yv3); yv3 = fmaf(fi, cB.w, yv3);
                e   = fmaf(fr, ds_r[n], e); e  = fmaf(-fi, ds_i[n], e);
            }
            float4* xp = (float4*)(xs + pE*68 + 4*ctE);
            float4 xv = *xp;
            xv.x += 2.f*yv0 + e; xv.y += 2.f*yv1 + e;
            xv.z += 2.f*yv2 + e; xv.w += 2.f*yv3 + e;
            *xp = xv;
        }
        __syncthreads();
    }
    // ---- final residual + norm ----
    float s = 0.f;
    for (int i = tid; i < NN; i += 1024){
        int y = i / ND, xx = i % ND;
        float cv = 0.f;
        #pragma unroll
        for (int dy = 0; dy < 3; dy++){
            int u = y + dy;
            #pragma unroll
            for (int dx = 0; dx < 3; dx++){
                int v = xx + dx;
                float p;
                if (u == 64 || v == 64)    p = 1.0f;
                else if (u == 0 || v == 0) p = 0.0f;
                else                       p = xs[(u-1)*68 + (v-1)];
                cv = fmaf(p, ka[dy*3 + dx], cv);
            }
        }
        float r = fg[i] - cv;
        s = fmaf(r, r, s);
    }
    #pragma unroll
    for (int off = 32; off > 0; off >>= 1) s += __shfl_down(s, off, 64);
    int lane = tid & 63, w = tid >> 6;
    if (lane == 0) red[w] = s;
    __syncthreads();
    if (tid == 0){
        float t = 0.f;
        #pragma unroll
        for (int i = 0; i < 16; i++) t += red[i];
        atomicAdd(accg, t);
    }
}

__global__ void k_final(const float* __restrict__ acc, float* __restrict__ out){
    if (threadIdx.x == 0 && blockIdx.x == 0) out[0] = sqrtf(acc[0]) * (1.0f/256.0f);
}

// ---------------- host ------------------------------------------------------
extern "C" void kernel_launch(void* const* d_in, const int* in_sizes, int n_in,
                              void* d_out, int out_size, void* d_ws, size_t ws_size,
                              hipStream_t stream){
    const float* x0     = (const float*)d_in[0];
    const float* f      = (const float*)d_in[1];
    const float* kA     = (const float*)d_in[2];
    const float* fc1_w1 = (const float*)d_in[3];
    const float* fc1_b1 = (const float*)d_in[4];
    const float* fc1_w2 = (const float*)d_in[5];
    const float* fc1_b2 = (const float*)d_in[6];
    const float* fc2_w1 = (const float*)d_in[7];
    const float* fc2_b1 = (const float*)d_in[8];
    const float* fc2_w2 = (const float*)d_in[9];
    const float* fc2_b2 = (const float*)d_in[10];
    const float* ct1_w  = (const float*)d_in[11];
    const float* ct1_b  = (const float*)d_in[12];
    const float* ct2_w  = (const float*)d_in[13];
    const float* ct2_b  = (const float*)d_in[14];
    const float* ct3_w  = (const float*)d_in[15];
    const float* ct3_b  = (const float*)d_in[16];
    const float* ct4_w  = (const float*)d_in[17];
    const float* ct4_b  = (const float*)d_in[18];
    const float* ct5_w  = (const float*)d_in[19];
    const float* ct5_b  = (const float*)d_in[20];
    float* out = (float*)d_out;

    float* ws = (float*)d_ws;
    size_t off = 0;
    auto take = [&](size_t n){ float* p = ws + off; off += (n + 63) & ~(size_t)63; return p; };
    float* Fr  = take(4096);
    float* Fi  = take(4096);
    float* acc = take(64);
    float* w1b = take((size_t)NB*147);
    float* w2b = take((size_t)NB*147);
    float* vc  = take((size_t)NB*4096);
    float* dvg = take((size_t)NB*64);
    float* c1  = take((size_t)NB*32*25);
    float* c2  = take((size_t)NB*32*81);
    float* c3  = take((size_t)NB*32*289);
    float* c4  = take((size_t)NB*32*1089);
    float* wT1 = take(288);
    float* wT2 = take(9216);
    float* wT3 = take(9216);
    float* wT4 = take(9216);
    float* wT5 = take(576);
    (void)ws_size; (void)in_sizes; (void)n_in; (void)out_size;

    k_tables<<<16, 256, 0, stream>>>(Fr, Fi, acc);
    k_wprep<<<36, 256, 0, stream>>>(ct1_w, ct2_w, ct3_w, ct4_w, ct5_w,
                                    wT1, wT2, wT3, wT4, wT5);
    k_hyper<<<NB, 192, 0, stream>>>(kA, fc1_w1, fc1_b1, fc1_w2, fc1_b2,
                                    fc2_w1, fc2_b1, fc2_w2, fc2_b2, w1b, w2b);
    k_ct1c<<<(NB*25 + 255)/256, 256, 0, stream>>>(kA, wT1, ct1_b, c1);
    k_ct32c<5> <<<NB*2, 512, 0, stream>>>(c1, wT2, ct2_b, c2);
    k_ct32c<9> <<<NB*2, 512, 0, stream>>>(c2, wT3, ct3_b, c3);
    k_ct32c<17><<<NB*2, 512, 0, stream>>>(c3, wT4, ct4_b, c4);
    k_ct5v<<<NB, 512, 0, stream>>>(c4, wT5, ct5_b, vc, dvg);
    k_solve<<<NB, 1024, 0, stream>>>(x0, f, kA, w1b, w2b, Fr, Fi, vc, dvg, acc);
    k_final<<<1, 64, 0, stream>>>(acc, out);
}

// Round 8
// 1446.483 us; speedup vs baseline: 1.2271x; 1.2271x over previous
//
#include <hip/hip_runtime.h>
#include <math.h>

#define NB   256
#define ND   63
#define NN   3969        // 63*63
#define MIDc 32

__device__ __forceinline__ float gelu_f(float v){
    return 0.5f * v * (1.0f + erff(v * 0.70710678118654752440f));
}

#define FMA4(A, W, S) { (A).x=fmaf((W).x,(S),(A).x); (A).y=fmaf((W).y,(S),(A).y); \
                        (A).z=fmaf((W).z,(S),(A).z); (A).w=fmaf((W).w,(S),(A).w); }

union F4 { float4 v; float a[4]; };
union W16 { float4 v[4]; float a[16]; };

// ---------------- DFT tables (64x64, row/col 63 zeroed) + acc reset ----------
__global__ void k_tables(float* __restrict__ Fr, float* __restrict__ Fi, float* __restrict__ acc){
    int idx = blockIdx.x * blockDim.x + threadIdx.x;
    if (idx < 4096){
        int r = idx >> 6, c = idx & 63;
        float vr = 0.f, vi = 0.f;
        if (r < 63 && c < 63){
            int m = (r * c) % 63;
            float ang = 6.283185307179586f * (float)m / 63.0f;
            vr = cosf(ang); vi = -sinf(ang);
        }
        Fr[idx] = vr; Fi[idx] = vi;
    }
    if (idx == 0) acc[0] = 0.f;
}

// -------- weight prep ---------------------------------------------------------
__global__ void k_wprep(const float* __restrict__ w1, const float* __restrict__ w2,
                        const float* __restrict__ w3, const float* __restrict__ w4,
                        const float* __restrict__ w5,
                        float* __restrict__ o1, float* __restrict__ o2,
                        float* __restrict__ o3, float* __restrict__ o4,
                        float* __restrict__ o5){
    int idx = blockIdx.x * blockDim.x + threadIdx.x;
    if (idx < 9216){
        int co = idx & 31, t = idx >> 5;
        int ci = t & 31, tap = t >> 5;
        int ky = tap / 3, kx = tap % 3;
        int src = ((ci*32 + co)*3 + ky)*3 + kx;
        o2[idx] = w2[src]; o3[idx] = w3[src]; o4[idx] = w4[src];
    }
    if (idx < 576){
        int co = idx & 1, t = idx >> 1;
        int ci = t & 31, tap = t >> 5;
        int ky = tap / 3, kx = tap % 3;
        o5[idx] = w5[((ci*2 + co)*3 + ky)*3 + kx];
    }
    if (idx < 288){
        int co = idx & 31, tap = idx >> 5;
        int ky = tap / 3, kx = tap % 3;
        o1[idx] = w1[(co*3 + ky)*3 + kx];
    }
}

// ---------------- hypernet ----------------------------------------------------
__global__ void k_hyper(const float* __restrict__ kA,
                        const float* __restrict__ w1a, const float* __restrict__ b1a,
                        const float* __restrict__ w2a, const float* __restrict__ b2a,
                        const float* __restrict__ w1b, const float* __restrict__ b1b,
                        const float* __restrict__ w2b, const float* __restrict__ b2b,
                        float* __restrict__ out1, float* __restrict__ out2){
    __shared__ float a[9];
    __shared__ float hid[100];
    int b = blockIdx.x, tid = threadIdx.x;
    if (tid < 9) a[tid] = kA[b*9 + tid];
    __syncthreads();
    if (tid < 100){
        float s = b1a[tid];
        #pragma unroll
        for (int i = 0; i < 9; i++) s = fmaf(a[i], w1a[i*100 + tid], s);
        hid[tid] = gelu_f(s);
    }
    __syncthreads();
    if (tid < 147){
        float s = b2a[tid];
        for (int k = 0; k < 100; k++) s = fmaf(hid[k], w2a[k*147 + tid], s);
        out1[b*147 + tid] = s;
    }
    __syncthreads();
    if (tid < 100){
        float s = b1b[tid];
        #pragma unroll
        for (int i = 0; i < 9; i++) s = fmaf(a[i], w1b[i*100 + tid], s);
        hid[tid] = gelu_f(s);
    }
    __syncthreads();
    if (tid < 147){
        float s = b2b[tid];
        for (int k = 0; k < 100; k++) s = fmaf(hid[k], w2b[k*147 + tid], s);
        out2[b*147 + tid] = s;
    }
}

// ---------------- ct1: 1->32, channel-last out --------------------------------
__global__ void k_ct1c(const float* __restrict__ kA, const float* __restrict__ wT1,
                       const float* __restrict__ bias, float* __restrict__ out){
    int idx = blockIdx.x * blockDim.x + threadIdx.x;
    if (idx >= NB*25) return;
    int p = idx % 25, b = idx / 25;
    int oy = p / 5, ox = p % 5;
    F4 acc[8];
    #pragma unroll
    for (int q = 0; q < 8; q++) acc[q].v = ((const float4*)bias)[q];
    int nky, kyA[2], iyA[2];
    if (oy & 1){ nky=2; kyA[0]=0; iyA[0]=(oy+1)/2; kyA[1]=2; iyA[1]=(oy-1)/2; }
    else       { nky=1; kyA[0]=1; iyA[0]=oy/2; kyA[1]=1; iyA[1]=0; }
    int nkx, kxA[2], ixA[2];
    if (ox & 1){ nkx=2; kxA[0]=0; ixA[0]=(ox+1)/2; kxA[1]=2; ixA[1]=(ox-1)/2; }
    else       { nkx=1; kxA[0]=1; ixA[0]=ox/2; kxA[1]=1; ixA[1]=0; }
    const float* ab = kA + b*9;
    for (int yi = 0; yi < nky; yi++)
    for (int xi = 0; xi < nkx; xi++){
        float v = ab[iyA[yi]*3 + ixA[xi]];
        const float4* wq = (const float4*)(wT1 + (kyA[yi]*3 + kxA[xi])*32);
        #pragma unroll
        for (int q = 0; q < 8; q++){ float4 w = wq[q]; FMA4(acc[q].v, w, v); }
    }
    float* ob = out + (size_t)idx*32;
    #pragma unroll
    for (int q = 0; q < 8; q++){
        float4 g; g.x=gelu_f(acc[q].a[0]); g.y=gelu_f(acc[q].a[1]);
        g.z=gelu_f(acc[q].a[2]); g.w=gelu_f(acc[q].a[3]);
        ((float4*)ob)[q] = g;
    }
}

// ------------- ct 32->32, stride2 pad1 k3, gelu, channel-last. 2 blocks/sample.
template<int HIN>
__global__ __launch_bounds__(512) void k_ct32c(const float* __restrict__ in,
                                               const float* __restrict__ wT,
                                               const float* __restrict__ bias,
                                               float* __restrict__ out){
    constexpr int HOUT = 2*HIN - 1;
    constexpr int HINP = (HIN + 3) & ~3;
    constexpr int OCT  = (HOUT + 7) / 8;
    constexpr int UPR  = OCT * 4;
    constexpr int NODD = (HOUT/2) * UPR;
    constexpr int TOT  = HOUT * UPR;
    constexpr int HT   = (TOT + 1) / 2;
    constexpr int INEL = 32*HIN*HINP;
    __shared__ __align__(16) float lds[INEL + 9216 + 32];
    float* in_s   = lds;
    float* w_s    = lds + INEL;
    float* bias_s = lds + INEL + 9216;
    const int b = blockIdx.x >> 1, h = blockIdx.x & 1;
    const int tid = threadIdx.x;
    { const float4* src = (const float4*)wT; float4* dst = (float4*)w_s;
      for (int i = tid; i < 2304; i += 512) dst[i] = src[i]; }
    if (tid < 32) bias_s[tid] = bias[tid];
    { const float* gi = in + (size_t)b * (32*HIN*HIN);
      for (int i = tid; i < 32*HIN*HIN; i += 512){
        int ci = i & 31, px = i >> 5;
        int y = px / HIN, x = px % HIN;
        in_s[ci*(HIN*HINP) + y*HINP + x] = gi[i];
      } }
    __syncthreads();
    float* ob0 = out + (size_t)b*(HOUT*HOUT*32);
    const int u0 = h*HT, u1 = (u0 + HT < TOT) ? (u0 + HT) : TOT;
    for (int u = u0 + tid; u < u1; u += 512){
        int r, s;
        if (u < NODD){ r = 2*(u/UPR) + 1; s = u % UPR; }
        else { int v = u - NODD; r = 2*(v/UPR); s = v % UPR; }
        const int m = s >> 2, cog = s & 3;
        const int x4 = 4*m;
        F4 acc[8][2];
        { float4 b0 = ((const float4*)bias_s)[cog*2];
          float4 b1 = ((const float4*)bias_s)[cog*2+1];
          #pragma unroll
          for (int p = 0; p < 8; p++){ acc[p][0].v = b0; acc[p][1].v = b1; } }
        int nky, kyA[2], iyA[2];
        if (r & 1){ int rI = r >> 1; nky = 2; kyA[0]=0; iyA[0]=rI+1; kyA[1]=2; iyA[1]=rI; }
        else      { nky = 1; kyA[0]=1; iyA[0]= r >> 1; kyA[1]=1; iyA[1]=0; }
        for (int yi = 0; yi < nky; yi++){
            const float* ip = in_s + iyA[yi]*HINP + x4;
            const float* wp = w_s + kyA[yi]*3*1024 + cog*8;
            #pragma unroll 2
            for (int ci = 0; ci < 32; ci++){
                F4 iv0, iv1;
                iv0.v = *(const float4*)(ip);
                iv1.v = *(const float4*)(ip + 4);
                float4 w0a = *(const float4*)(wp);
                float4 w0b = *(const float4*)(wp + 4);
                float4 w1a = *(const float4*)(wp + 1024);
                float4 w1b = *(const float4*)(wp + 1028);
                float4 w2a = *(const float4*)(wp + 2048);
                float4 w2b = *(const float4*)(wp + 2052);
                #pragma unroll
                for (int p = 0; p < 4; p++){
                    float ev = iv0.a[p];
                    FMA4(acc[2*p][0].v, w1a, ev);
                    FMA4(acc[2*p][1].v, w1b, ev);
                    float o0 = (p < 3) ? iv0.a[p+1] : iv1.a[0];
                    FMA4(acc[2*p+1][0].v, w0a, o0);
                    FMA4(acc[2*p+1][1].v, w0b, o0);
                    FMA4(acc[2*p+1][0].v, w2a, ev);
                    FMA4(acc[2*p+1][1].v, w2b, ev);
                }
                ip += HIN*HINP;
                wp += 32;
            }
        }
        int lim = HOUT - 8*m; if (lim > 8) lim = 8;
        float* ob = ob0 + ((size_t)r*HOUT + 8*m)*32 + cog*8;
        for (int e = 0; e < lim; e++){
            float4 g0, g1;
            g0.x=gelu_f(acc[e][0].a[0]); g0.y=gelu_f(acc[e][0].a[1]);
            g0.z=gelu_f(acc[e][0].a[2]); g0.w=gelu_f(acc[e][0].a[3]);
            g1.x=gelu_f(acc[e][1].a[0]); g1.y=gelu_f(acc[e][1].a[1]);
            g1.z=gelu_f(acc[e][1].a[2]); g1.w=gelu_f(acc[e][1].a[3]);
            *(float4*)(ob + (size_t)e*32)     = g0;
            *(float4*)(ob + (size_t)e*32 + 4) = g1;
        }
    }
}

// ---- ct5 (32->2) + build v rows 0..31 (interleaved) + dv --------------------
__global__ __launch_bounds__(512) void k_ct5v(const float* __restrict__ in,
                                              const float* __restrict__ wT5,
                                              const float* __restrict__ bias,
                                              float* __restrict__ vcg,
                                              float* __restrict__ dvg){
    __shared__ float ws5[576];
    __shared__ float c5s[2*NN];
    const int b = blockIdx.x, tid = threadIdx.x;
    for (int i = tid; i < 576; i += 512) ws5[i] = wT5[i];
    __syncthreads();
    const float* ib = in + (size_t)b * (32*33*33);
    float b0 = bias[0], b1 = bias[1];
    for (int p = tid; p < NN; p += 512){
        int oy = p / ND, ox = p % ND;
        float a0 = b0, a1 = b1;
        int nky, kyA[2], iyA[2];
        if ((oy & 1) == 0){ nky=2; kyA[0]=0; iyA[0]=oy/2+1; kyA[1]=2; iyA[1]=oy/2; }
        else              { nky=1; kyA[0]=1; iyA[0]=(oy+1)/2; kyA[1]=1; iyA[1]=0; }
        int nkx, kxA[2], ixA[2];
        if ((ox & 1) == 0){ nkx=2; kxA[0]=0; ixA[0]=ox/2+1; kxA[1]=2; ixA[1]=ox/2; }
        else              { nkx=1; kxA[0]=1; ixA[0]=(ox+1)/2; kxA[1]=1; ixA[1]=0; }
        for (int yi = 0; yi < nky; yi++)
        for (int xi = 0; xi < nkx; xi++){
            const float* ip = ib + ((size_t)iyA[yi]*33 + ixA[xi])*32;
            const float* wp = ws5 + (kyA[yi]*3 + kxA[xi])*64;
            #pragma unroll
            for (int g = 0; g < 8; g++){
                F4 iv; iv.v = *(const float4*)(ip + 4*g);
                #pragma unroll
                for (int q = 0; q < 4; q++){
                    int ci = 4*g + q;
                    a0 = fmaf(iv.a[q], wp[ci*2],   a0);
                    a1 = fmaf(iv.a[q], wp[ci*2+1], a1);
                }
            }
        }
        c5s[p]      = a0;
        c5s[NN + p] = a1;
    }
    __syncthreads();
    const float sc = 1.0f / 3969.0f;
    float4* vc4 = (float4*)vcg;
    for (int i = tid; i < 1024; i += 512){
        int ky = i >> 5, ct2 = i & 31;
        float4 o;
        #pragma unroll
        for (int j = 0; j < 2; j++){
            int kx = 2*ct2 + j;
            float re = 0.f, im = 0.f;
            if (kx <= 31){ int o2 = 2*(ky*ND + kx); re = c5s[o2]*sc; im = c5s[o2+1]*sc; }
            else if (kx <= 62){
                int sy = (ND - ky) % ND, sx = ND - kx;
                int o2 = 2*(sy*ND + sx); re = c5s[o2]*sc; im = -c5s[o2+1]*sc;
            }
            if (j == 0){ o.x = re; o.y = im; } else { o.z = re; o.w = im; }
        }
        vc4[(size_t)b*1024 + i] = o;
    }
    if (tid < 32){
        float2* dv2 = (float2*)dvg;
        float2 d = {0.f, 0.f};
        if (tid >= 1){
            int iA = (ND - tid) * ND, iB = tid * ND;
            d.x = (c5s[2*iA]     - c5s[2*iB])     * sc;
            d.y = (c5s[2*iA + 1] + c5s[2*iB + 1]) * sc;
        }
        dv2[b*32 + tid] = d;
    }
}

// ---------------- mega solver, 512 threads, Hermitian-halved DFT -------------
// 512 threads: VGPR cap 128 (r5 proved 88, no spill). 1024-thread blocks get a
// hard 64-VGPR budget on this toolchain and spill 4 GB (r6/r7) — never again.
__global__ __launch_bounds__(512) void k_solve(const float* __restrict__ x0g,
                                               const float* __restrict__ f,
                                               const float* __restrict__ kAg,
                                               const float* __restrict__ w1g,
                                               const float* __restrict__ w2g,
                                               const float* __restrict__ Frg,
                                               const float* __restrict__ Fig,
                                               const float* __restrict__ vcg,
                                               const float* __restrict__ dvg,
                                               float* __restrict__ accg){
    __shared__ __align__(16) float xs[63*68 + 8];    // row stride 68
    __shared__ __align__(16) float U[8576];          // rs|tc  /  rP|TtC|MC|CC
    __shared__ float w1s[148], w2s[148], dvs[64], ds_r[32], ds_i[32], red[8];
    const int b = blockIdx.x, tid = threadIdx.x;
    float* rs = U;                       // 63*68 (+4 slack)
    float* tc = U + 4288;                // 63*68 (+4 slack)
    float*  rP  = U;                     // 64x64
    float2* rP2 = (float2*)U;
    float2* TtC = (float2*)(U + 4096);   // 64 cols x 32 swizzled slots (f2)
    float4* MC4 = (float4*)U;            // 32 x 32 f4 (col pairs)
    float2* MC2 = (float2*)U;
    float4* CC4 = (float4*)(U + 4096);   // 32 x 33 f4
    const float2* F2r = (const float2*)Frg;
    const float2* F2i = (const float2*)Fig;
    const float* fg = f + (size_t)b*NN;
    float ka[9];
    #pragma unroll
    for (int i = 0; i < 9; i++) ka[i] = kAg[b*9 + i];
    if (tid < 147){ w1s[tid] = w1g[b*147 + tid]; w2s[tid] = w2g[b*147 + tid]; }
    if (tid < 64) dvs[tid] = dvg[b*64 + tid];
    for (int i = tid; i < NN; i += 512) xs[(i/ND)*68 + (i%ND)] = x0g[(size_t)b*NN + i];
    __syncthreads();

    for (int it = 0; it < 5; it++){
        // ---- zero union ----
        { float4 z = {0.f,0.f,0.f,0.f}; float4* U4 = (float4*)U;
          for (int i = tid; i < 2144; i += 512) U4[i] = z; }
        __syncthreads();
        // ---- residual -> rs (col c at idx c+3) ----
        for (int i = tid; i < NN; i += 512){
            int y = i / ND, xx = i % ND;
            float s = 0.f;
            #pragma unroll
            for (int dy = 0; dy < 3; dy++){
                int u = y + dy;
                #pragma unroll
                for (int dx = 0; dx < 3; dx++){
                    int v = xx + dx;
                    float p;
                    if (u == 64 || v == 64)    p = 1.0f;
                    else if (u == 0 || v == 0) p = 0.0f;
                    else                       p = xs[(u-1)*68 + (v-1)];
                    s = fmaf(p, ka[dy*3 + dx], s);
                }
            }
            rs[y*68 + 3 + xx] = fg[i] - s;
        }
        __syncthreads();
        // ---- smoother: 1-row x 8-px units, 504 active lanes (r5-proven) ----
        const bool act = tid < 504;
        const int y0 = tid >> 3, x0c = 8*(tid & 7);
        float acc2[8] = {};
        for (int c = 0; c < 3; c++){
            if (act){
                float a1[8] = {};
                for (int dy = 0; dy < 7; dy++){
                    int ry = y0 + dy - 3;
                    if (ry < 0 || ry >= 63) continue;
                    W16 w16;
                    const float4* rp = (const float4*)(rs + ry*68 + x0c);
                    w16.v[0]=rp[0]; w16.v[1]=rp[1]; w16.v[2]=rp[2]; w16.v[3]=rp[3];
                    #pragma unroll
                    for (int dx = 0; dx < 7; dx++){
                        float wv = w1s[c*49 + dy*7 + dx];
                        #pragma unroll
                        for (int t = 0; t < 8; t++) a1[t] = fmaf(wv, w16.a[t+dx], a1[t]);
                    }
                }
                int nw = 63 - x0c; if (nw > 8) nw = 8;
                for (int t = 0; t < nw; t++) tc[y0*68 + 3 + x0c + t] = a1[t];
            }
            __syncthreads();
            if (act){
                for (int dy = 0; dy < 7; dy++){
                    int ry = y0 + dy - 3;
                    if (ry < 0 || ry >= 63) continue;
                    W16 w16;
                    const float4* tp = (const float4*)(tc + ry*68 + x0c);
                    w16.v[0]=tp[0]; w16.v[1]=tp[1]; w16.v[2]=tp[2]; w16.v[3]=tp[3];
                    #pragma unroll
                    for (int dx = 0; dx < 7; dx++){
                        float wv = w2s[c*49 + dy*7 + dx];
                        #pragma unroll
                        for (int t = 0; t < 8; t++) acc2[t] = fmaf(wv, w16.a[t+dx], acc2[t]);
                    }
                }
            }
            __syncthreads();
        }
        if (act){
            int nw = 63 - x0c; if (nw > 8) nw = 8;
            for (int t = 0; t < nw; t++) xs[y0*68 + x0c + t] += acc2[t];
        }
        __syncthreads();
        // ---- residual of updated x -> rP (64x64, zero pad) ----
        for (int i = tid; i < 4096; i += 512){
            int y = i >> 6, xx = i & 63;
            float val = 0.f;
            if (y < 63 && xx < 63){
                float s = 0.f;
                #pragma unroll
                for (int dy = 0; dy < 3; dy++){
                    int u = y + dy;
                    #pragma unroll
                    for (int dx = 0; dx < 3; dx++){
                        int v = xx + dx;
                        float p;
                        if (u == 64 || v == 64)    p = 1.0f;
                        else if (u == 0 || v == 0) p = 0.0f;
                        else                       p = xs[(u-1)*68 + (v-1)];
                        s = fmaf(p, ka[dy*3 + dx], s);
                    }
                }
                val = fg[y*ND + xx] - s;
            }
            rP[i] = val;
        }
        __syncthreads();
        // ---- Phase A: T[k,c] = sum_m F[k,m] r[m,c], k=0..31; 2 reps --------
        {
            const int ct2 = tid & 31;
            #pragma unroll
            for (int rep = 0; rep < 2; rep++){
                const int k = (tid >> 5) + 16*rep;
                float t0r=0.f,t0i=0.f,t1r=0.f,t1i=0.f;
                for (int m = 0; m < 63; m++){
                    float fr = Frg[m*64 + k], fi = Fig[m*64 + k];
                    float2 rv = rP2[m*32 + ct2];
                    t0r = fmaf(fr, rv.x, t0r); t0i = fmaf(fi, rv.x, t0i);
                    t1r = fmaf(fr, rv.y, t1r); t1i = fmaf(fi, rv.y, t1i);
                }
                int n0 = 2*ct2;
                TtC[n0*32     + ((k + n0)     & 31)] = make_float2(t0r, t0i);
                TtC[(n0+1)*32 + ((k + n0 + 1) & 31)] = make_float2(t1r, t1i);
            }
        }
        __syncthreads();
        // ---- Phase B: R = T F (rows 0..31), M = R.*v ; d-vector; 2 reps ----
        {
            const int kt = tid >> 4;
            #pragma unroll
            for (int rep = 0; rep < 2; rep++){
                const int c2 = (tid & 15) + 16*rep;
                float R0r=0.f,R0i=0.f,R1r=0.f,R1i=0.f;
                for (int n = 0; n < 63; n++){
                    float2 T = TtC[n*32 + ((kt + n) & 31)];
                    float2 fr = F2r[n*32 + c2], fi = F2i[n*32 + c2];
                    R0r = fmaf(T.x, fr.x, R0r); R0r = fmaf(-T.y, fi.x, R0r);
                    R0i = fmaf(T.x, fi.x, R0i); R0i = fmaf( T.y, fr.x, R0i);
                    R1r = fmaf(T.x, fr.y, R1r); R1r = fmaf(-T.y, fi.y, R1r);
                    R1i = fmaf(T.x, fi.y, R1i); R1i = fmaf( T.y, fr.y, R1i);
                }
                if (rep == 0 && (tid & 15) == 0){
                    float2 dv = ((const float2*)dvs)[kt];
                    ds_r[kt] = R0r*dv.x + R0i*dv.y;
                    ds_i[kt] = R0r*dv.y - R0i*dv.x;
                }
                float4 vv = ((const float4*)vcg)[(size_t)b*1024 + kt*32 + c2];
                float4 Mv;
                Mv.x = R0r*vv.x - R0i*vv.y;  Mv.y = R0r*vv.y + R0i*vv.x;
                Mv.z = R1r*vv.z - R1i*vv.w;  Mv.w = R1r*vv.w + R1i*vv.z;
                MC4[kt*32 + c2] = Mv;
            }
        }
        __syncthreads();
        // ---- Phase D: C[n,q] = sum_l M[n,l] conj(F[l,q]), n=0..31; 2 reps --
        {
            const int kt = tid >> 4;
            #pragma unroll
            for (int rep = 0; rep < 2; rep++){
                const int q2 = (tid & 15) + 16*rep;
                float C0r=0.f,C0i=0.f,C1r=0.f,C1i=0.f;
                for (int l = 0; l < 63; l++){
                    float2 Mv = MC2[kt*64 + l];
                    float2 fr = F2r[l*32 + q2], fi = F2i[l*32 + q2];
                    C0r = fmaf(Mv.x, fr.x, C0r); C0r = fmaf( Mv.y, fi.x, C0r);
                    C0i = fmaf(Mv.y, fr.x, C0i); C0i = fmaf(-Mv.x, fi.x, C0i);
                    C1r = fmaf(Mv.x, fr.y, C1r); C1r = fmaf( Mv.y, fi.y, C1r);
                    C1i = fmaf(Mv.y, fr.y, C1i); C1i = fmaf(-Mv.x, fi.y, C1i);
                }
                float scale = (kt == 0) ? 0.5f : 1.0f;
                CC4[kt*33 + q2] = make_float4(C0r*scale, C0i*scale, C1r*scale, C1i*scale);
            }
        }
        __syncthreads();
        // ---- Phase E: y = 2 Re-fold + e[p]; two rows per lane --------------
        {
            const int pA = tid >> 4, ctE = tid & 15;
            const int pB = pA + 32;
            float yA0=0.f,yA1=0.f,yA2=0.f,yA3=0.f,eA=0.f;
            float yB0=0.f,yB1=0.f,yB2=0.f,yB3=0.f,eB=0.f;
            for (int n = 0; n < 32; n++){
                float frA = Frg[n*64 + pA], fiA = Fig[n*64 + pA];
                float frB = Frg[n*64 + pB], fiB = Fig[n*64 + pB];
                float4 cA = CC4[n*33 + 2*ctE];
                float4 cB = CC4[n*33 + 2*ctE + 1];
                float dsr = ds_r[n], dsi = ds_i[n];
                yA0 = fmaf(frA, cA.x, yA0); yA0 = fmaf(fiA, cA.y, yA0);
                yA1 = fmaf(frA, cA.z, yA1); yA1 = fmaf(fiA, cA.w, yA1);
                yA2 = fmaf(frA, cB.x, yA2); yA2 = fmaf(fiA, cB.y, yA2);
                yA3 = fmaf(frA, cB.z, yA3); yA3 = fmaf(fiA, cB.w, yA3);
                eA  = fmaf(frA, dsr, eA);   eA  = fmaf(-fiA, dsi, eA);
                yB0 = fmaf(frB, cA.x, yB0); yB0 = fmaf(fiB, cA.y, yB0);
                yB1 = fmaf(frB, cA.z, yB1); yB1 = fmaf(fiB, cA.w, yB1);
                yB2 = fmaf(frB, cB.x, yB2); yB2 = fmaf(fiB, cB.y, yB2);
                yB3 = fmaf(frB, cB.z, yB3); yB3 = fmaf(fiB, cB.w, yB3);
                eB  = fmaf(frB, dsr, eB);   eB  = fmaf(-fiB, dsi, eB);
            }
            {
                float4* xp = (float4*)(xs + pA*68 + 4*ctE);
                float4 xv = *xp;
                xv.x += 2.f*yA0 + eA; xv.y += 2.f*yA1 + eA;
                xv.z += 2.f*yA2 + eA; xv.w += 2.f*yA3 + eA;
                *xp = xv;
            }
            if (pB < 63){
                float4* xp = (float4*)(xs + pB*68 + 4*ctE);
                float4 xv = *xp;
                xv.x += 2.f*yB0 + eB; xv.y += 2.f*yB1 + eB;
                xv.z += 2.f*yB2 + eB; xv.w += 2.f*yB3 + eB;
                *xp = xv;
            }
        }
        __syncthreads();
    }
    // ---- final residual + norm ----
    float s = 0.f;
    for (int i = tid; i < NN; i += 512){
        int y = i / ND, xx = i % ND;
        float cv = 0.f;
        #pragma unroll
        for (int dy = 0; dy < 3; dy++){
            int u = y + dy;
            #pragma unroll
            for (int dx = 0; dx < 3; dx++){
                int v = xx + dx;
                float p;
                if (u == 64 || v == 64)    p = 1.0f;
                else if (u == 0 || v == 0) p = 0.0f;
                else                       p = xs[(u-1)*68 + (v-1)];
                cv = fmaf(p, ka[dy*3 + dx], cv);
            }
        }
        float r = fg[i] - cv;
        s = fmaf(r, r, s);
    }
    #pragma unroll
    for (int off = 32; off > 0; off >>= 1) s += __shfl_down(s, off, 64);
    int lane = tid & 63, w = tid >> 6;
    if (lane == 0) red[w] = s;
    __syncthreads();
    if (tid == 0){
        float t = 0.f;
        #pragma unroll
        for (int i = 0; i < 8; i++) t += red[i];
        atomicAdd(accg, t);
    }
}

__global__ void k_final(const float* __restrict__ acc, float* __restrict__ out){
    if (threadIdx.x == 0 && blockIdx.x == 0) out[0] = sqrtf(acc[0]) * (1.0f/256.0f);
}

// ---------------- host ------------------------------------------------------
extern "C" void kernel_launch(void* const* d_in, const int* in_sizes, int n_in,
                              void* d_out, int out_size, void* d_ws, size_t ws_size,
                              hipStream_t stream){
    const float* x0     = (const float*)d_in[0];
    const float* f      = (const float*)d_in[1];
    const float* kA     = (const float*)d_in[2];
    const float* fc1_w1 = (const float*)d_in[3];
    const float* fc1_b1 = (const float*)d_in[4];
    const float* fc1_w2 = (const float*)d_in[5];
    const float* fc1_b2 = (const float*)d_in[6];
    const float* fc2_w1 = (const float*)d_in[7];
    const float* fc2_b1 = (const float*)d_in[8];
    const float* fc2_w2 = (const float*)d_in[9];
    const float* fc2_b2 = (const float*)d_in[10];
    const float* ct1_w  = (const float*)d_in[11];
    const float* ct1_b  = (const float*)d_in[12];
    const float* ct2_w  = (const float*)d_in[13];
    const float* ct2_b  = (const float*)d_in[14];
    const float* ct3_w  = (const float*)d_in[15];
    const float* ct3_b  = (const float*)d_in[16];
    const float* ct4_w  = (const float*)d_in[17];
    const float* ct4_b  = (const float*)d_in[18];
    const float* ct5_w  = (const float*)d_in[19];
    const float* ct5_b  = (const float*)d_in[20];
    float* out = (float*)d_out;

    float* ws = (float*)d_ws;
    size_t off = 0;
    auto take = [&](size_t n){ float* p = ws + off; off += (n + 63) & ~(size_t)63; return p; };
    float* Fr  = take(4096);
    float* Fi  = take(4096);
    float* acc = take(64);
    float* w1b = take((size_t)NB*147);
    float* w2b = take((size_t)NB*147);
    float* vc  = take((size_t)NB*4096);
    float* dvg = take((size_t)NB*64);
    float* c1  = take((size_t)NB*32*25);
    float* c2  = take((size_t)NB*32*81);
    float* c3  = take((size_t)NB*32*289);
    float* c4  = take((size_t)NB*32*1089);
    float* wT1 = take(288);
    float* wT2 = take(9216);
    float* wT3 = take(9216);
    float* wT4 = take(9216);
    float* wT5 = take(576);
    (void)ws_size; (void)in_sizes; (void)n_in; (void)out_size;

    k_tables<<<16, 256, 0, stream>>>(Fr, Fi, acc);
    k_wprep<<<36, 256, 0, stream>>>(ct1_w, ct2_w, ct3_w, ct4_w, ct5_w,
                                    wT1, wT2, wT3, wT4, wT5);
    k_hyper<<<NB, 192, 0, stream>>>(kA, fc1_w1, fc1_b1, fc1_w2, fc1_b2,
                                    fc2_w1, fc2_b1, fc2_w2, fc2_b2, w1b, w2b);
    k_ct1c<<<(NB*25 + 255)/256, 256, 0, stream>>>(kA, wT1, ct1_b, c1);
    k_ct32c<5> <<<NB*2, 512, 0, stream>>>(c1, wT2, ct2_b, c2);
    k_ct32c<9> <<<NB*2, 512, 0, stream>>>(c2, wT3, ct3_b, c3);
    k_ct32c<17><<<NB*2, 512, 0, stream>>>(c3, wT4, ct4_b, c4);
    k_ct5v<<<NB, 512, 0, stream>>>(c4, wT5, ct5_b, vc, dvg);
    k_solve<<<NB, 512, 0, stream>>>(x0, f, kA, w1b, w2b, Fr, Fi, vc, dvg, acc);
    k_final<<<1, 64, 0, stream>>>(acc, out);
}

// Round 9
// 523.472 us; speedup vs baseline: 3.3908x; 2.7632x over previous
//
#include <hip/hip_runtime.h>
#include <math.h>

#define NB   256
#define ND   63
#define NN   3969        // 63*63
#define MIDc 32

__device__ __forceinline__ float gelu_f(float v){
    return 0.5f * v * (1.0f + erff(v * 0.70710678118654752440f));
}

#define FMA4(A, W, S) { (A).x=fmaf((W).x,(S),(A).x); (A).y=fmaf((W).y,(S),(A).y); \
                        (A).z=fmaf((W).z,(S),(A).z); (A).w=fmaf((W).w,(S),(A).w); }

union F4 { float4 v; float a[4]; };
union W16 { float4 v[4]; float a[16]; };

// ---------------- DFT tables (64x64, row/col 63 zeroed) + acc reset ----------
__global__ void k_tables(float* __restrict__ Fr, float* __restrict__ Fi, float* __restrict__ acc){
    int idx = blockIdx.x * blockDim.x + threadIdx.x;
    if (idx < 4096){
        int r = idx >> 6, c = idx & 63;
        float vr = 0.f, vi = 0.f;
        if (r < 63 && c < 63){
            int m = (r * c) % 63;
            float ang = 6.283185307179586f * (float)m / 63.0f;
            vr = cosf(ang); vi = -sinf(ang);
        }
        Fr[idx] = vr; Fi[idx] = vi;
    }
    if (idx == 0) acc[0] = 0.f;
}

// -------- weight prep ---------------------------------------------------------
__global__ void k_wprep(const float* __restrict__ w1, const float* __restrict__ w2,
                        const float* __restrict__ w3, const float* __restrict__ w4,
                        const float* __restrict__ w5,
                        float* __restrict__ o1, float* __restrict__ o2,
                        float* __restrict__ o3, float* __restrict__ o4,
                        float* __restrict__ o5){
    int idx = blockIdx.x * blockDim.x + threadIdx.x;
    if (idx < 9216){
        int co = idx & 31, t = idx >> 5;
        int ci = t & 31, tap = t >> 5;
        int ky = tap / 3, kx = tap % 3;
        int src = ((ci*32 + co)*3 + ky)*3 + kx;
        o2[idx] = w2[src]; o3[idx] = w3[src]; o4[idx] = w4[src];
    }
    if (idx < 576){
        int co = idx & 1, t = idx >> 1;
        int ci = t & 31, tap = t >> 5;
        int ky = tap / 3, kx = tap % 3;
        o5[idx] = w5[((ci*2 + co)*3 + ky)*3 + kx];
    }
    if (idx < 288){
        int co = idx & 31, tap = idx >> 5;
        int ky = tap / 3, kx = tap % 3;
        o1[idx] = w1[(co*3 + ky)*3 + kx];
    }
}

// ---------------- hypernet ----------------------------------------------------
__global__ void k_hyper(const float* __restrict__ kA,
                        const float* __restrict__ w1a, const float* __restrict__ b1a,
                        const float* __restrict__ w2a, const float* __restrict__ b2a,
                        const float* __restrict__ w1b, const float* __restrict__ b1b,
                        const float* __restrict__ w2b, const float* __restrict__ b2b,
                        float* __restrict__ out1, float* __restrict__ out2){
    __shared__ float a[9];
    __shared__ float hid[100];
    int b = blockIdx.x, tid = threadIdx.x;
    if (tid < 9) a[tid] = kA[b*9 + tid];
    __syncthreads();
    if (tid < 100){
        float s = b1a[tid];
        #pragma unroll
        for (int i = 0; i < 9; i++) s = fmaf(a[i], w1a[i*100 + tid], s);
        hid[tid] = gelu_f(s);
    }
    __syncthreads();
    if (tid < 147){
        float s = b2a[tid];
        for (int k = 0; k < 100; k++) s = fmaf(hid[k], w2a[k*147 + tid], s);
        out1[b*147 + tid] = s;
    }
    __syncthreads();
    if (tid < 100){
        float s = b1b[tid];
        #pragma unroll
        for (int i = 0; i < 9; i++) s = fmaf(a[i], w1b[i*100 + tid], s);
        hid[tid] = gelu_f(s);
    }
    __syncthreads();
    if (tid < 147){
        float s = b2b[tid];
        for (int k = 0; k < 100; k++) s = fmaf(hid[k], w2b[k*147 + tid], s);
        out2[b*147 + tid] = s;
    }
}

// ---------------- ct1: 1->32, channel-last out --------------------------------
__global__ void k_ct1c(const float* __restrict__ kA, const float* __restrict__ wT1,
                       const float* __restrict__ bias, float* __restrict__ out){
    int idx = blockIdx.x * blockDim.x + threadIdx.x;
    if (idx >= NB*25) return;
    int p = idx % 25, b = idx / 25;
    int oy = p / 5, ox = p % 5;
    F4 acc[8];
    #pragma unroll
    for (int q = 0; q < 8; q++) acc[q].v = ((const float4*)bias)[q];
    int nky, kyA[2], iyA[2];
    if (oy & 1){ nky=2; kyA[0]=0; iyA[0]=(oy+1)/2; kyA[1]=2; iyA[1]=(oy-1)/2; }
    else       { nky=1; kyA[0]=1; iyA[0]=oy/2; kyA[1]=1; iyA[1]=0; }
    int nkx, kxA[2], ixA[2];
    if (ox & 1){ nkx=2; kxA[0]=0; ixA[0]=(ox+1)/2; kxA[1]=2; ixA[1]=(ox-1)/2; }
    else       { nkx=1; kxA[0]=1; ixA[0]=ox/2; kxA[1]=1; ixA[1]=0; }
    const float* ab = kA + b*9;
    for (int yi = 0; yi < nky; yi++)
    for (int xi = 0; xi < nkx; xi++){
        float v = ab[iyA[yi]*3 + ixA[xi]];
        const float4* wq = (const float4*)(wT1 + (kyA[yi]*3 + kxA[xi])*32);
        #pragma unroll
        for (int q = 0; q < 8; q++){ float4 w = wq[q]; FMA4(acc[q].v, w, v); }
    }
    float* ob = out + (size_t)idx*32;
    #pragma unroll
    for (int q = 0; q < 8; q++){
        float4 g; g.x=gelu_f(acc[q].a[0]); g.y=gelu_f(acc[q].a[1]);
        g.z=gelu_f(acc[q].a[2]); g.w=gelu_f(acc[q].a[3]);
        ((float4*)ob)[q] = g;
    }
}

// ------------- ct 32->32, stride2 pad1 k3, gelu, channel-last. 2 blocks/sample.
template<int HIN>
__global__ __launch_bounds__(512) void k_ct32c(const float* __restrict__ in,
                                               const float* __restrict__ wT,
                                               const float* __restrict__ bias,
                                               float* __restrict__ out){
    constexpr int HOUT = 2*HIN - 1;
    constexpr int HINP = (HIN + 3) & ~3;
    constexpr int OCT  = (HOUT + 7) / 8;
    constexpr int UPR  = OCT * 4;
    constexpr int NODD = (HOUT/2) * UPR;
    constexpr int TOT  = HOUT * UPR;
    constexpr int HT   = (TOT + 1) / 2;
    constexpr int INEL = 32*HIN*HINP;
    __shared__ __align__(16) float lds[INEL + 9216 + 32];
    float* in_s   = lds;
    float* w_s    = lds + INEL;
    float* bias_s = lds + INEL + 9216;
    const int b = blockIdx.x >> 1, h = blockIdx.x & 1;
    const int tid = threadIdx.x;
    { const float4* src = (const float4*)wT; float4* dst = (float4*)w_s;
      for (int i = tid; i < 2304; i += 512) dst[i] = src[i]; }
    if (tid < 32) bias_s[tid] = bias[tid];
    { const float* gi = in + (size_t)b * (32*HIN*HIN);
      for (int i = tid; i < 32*HIN*HIN; i += 512){
        int ci = i & 31, px = i >> 5;
        int y = px / HIN, x = px % HIN;
        in_s[ci*(HIN*HINP) + y*HINP + x] = gi[i];
      } }
    __syncthreads();
    float* ob0 = out + (size_t)b*(HOUT*HOUT*32);
    const int u0 = h*HT, u1 = (u0 + HT < TOT) ? (u0 + HT) : TOT;
    for (int u = u0 + tid; u < u1; u += 512){
        int r, s;
        if (u < NODD){ r = 2*(u/UPR) + 1; s = u % UPR; }
        else { int v = u - NODD; r = 2*(v/UPR); s = v % UPR; }
        const int m = s >> 2, cog = s & 3;
        const int x4 = 4*m;
        F4 acc[8][2];
        { float4 b0 = ((const float4*)bias_s)[cog*2];
          float4 b1 = ((const float4*)bias_s)[cog*2+1];
          #pragma unroll
          for (int p = 0; p < 8; p++){ acc[p][0].v = b0; acc[p][1].v = b1; } }
        int nky, kyA[2], iyA[2];
        if (r & 1){ int rI = r >> 1; nky = 2; kyA[0]=0; iyA[0]=rI+1; kyA[1]=2; iyA[1]=rI; }
        else      { nky = 1; kyA[0]=1; iyA[0]= r >> 1; kyA[1]=1; iyA[1]=0; }
        for (int yi = 0; yi < nky; yi++){
            const float* ip = in_s + iyA[yi]*HINP + x4;
            const float* wp = w_s + kyA[yi]*3*1024 + cog*8;
            #pragma unroll 2
            for (int ci = 0; ci < 32; ci++){
                F4 iv0, iv1;
                iv0.v = *(const float4*)(ip);
                iv1.v = *(const float4*)(ip + 4);
                float4 w0a = *(const float4*)(wp);
                float4 w0b = *(const float4*)(wp + 4);
                float4 w1a = *(const float4*)(wp + 1024);
                float4 w1b = *(const float4*)(wp + 1028);
                float4 w2a = *(const float4*)(wp + 2048);
                float4 w2b = *(const float4*)(wp + 2052);
                #pragma unroll
                for (int p = 0; p < 4; p++){
                    float ev = iv0.a[p];
                    FMA4(acc[2*p][0].v, w1a, ev);
                    FMA4(acc[2*p][1].v, w1b, ev);
                    float o0 = (p < 3) ? iv0.a[p+1] : iv1.a[0];
                    FMA4(acc[2*p+1][0].v, w0a, o0);
                    FMA4(acc[2*p+1][1].v, w0b, o0);
                    FMA4(acc[2*p+1][0].v, w2a, ev);
                    FMA4(acc[2*p+1][1].v, w2b, ev);
                }
                ip += HIN*HINP;
                wp += 32;
            }
        }
        int lim = HOUT - 8*m; if (lim > 8) lim = 8;
        float* ob = ob0 + ((size_t)r*HOUT + 8*m)*32 + cog*8;
        for (int e = 0; e < lim; e++){
            float4 g0, g1;
            g0.x=gelu_f(acc[e][0].a[0]); g0.y=gelu_f(acc[e][0].a[1]);
            g0.z=gelu_f(acc[e][0].a[2]); g0.w=gelu_f(acc[e][0].a[3]);
            g1.x=gelu_f(acc[e][1].a[0]); g1.y=gelu_f(acc[e][1].a[1]);
            g1.z=gelu_f(acc[e][1].a[2]); g1.w=gelu_f(acc[e][1].a[3]);
            *(float4*)(ob + (size_t)e*32)     = g0;
            *(float4*)(ob + (size_t)e*32 + 4) = g1;
        }
    }
}

// ---- ct5 (32->2) + build v rows 0..31 (interleaved) + dv --------------------
__global__ __launch_bounds__(512) void k_ct5v(const float* __restrict__ in,
                                              const float* __restrict__ wT5,
                                              const float* __restrict__ bias,
                                              float* __restrict__ vcg,
                                              float* __restrict__ dvg){
    __shared__ float ws5[576];
    __shared__ float c5s[2*NN];
    const int b = blockIdx.x, tid = threadIdx.x;
    for (int i = tid; i < 576; i += 512) ws5[i] = wT5[i];
    __syncthreads();
    const float* ib = in + (size_t)b * (32*33*33);
    float b0 = bias[0], b1 = bias[1];
    for (int p = tid; p < NN; p += 512){
        int oy = p / ND, ox = p % ND;
        float a0 = b0, a1 = b1;
        int nky, kyA[2], iyA[2];
        if ((oy & 1) == 0){ nky=2; kyA[0]=0; iyA[0]=oy/2+1; kyA[1]=2; iyA[1]=oy/2; }
        else              { nky=1; kyA[0]=1; iyA[0]=(oy+1)/2; kyA[1]=1; iyA[1]=0; }
        int nkx, kxA[2], ixA[2];
        if ((ox & 1) == 0){ nkx=2; kxA[0]=0; ixA[0]=ox/2+1; kxA[1]=2; ixA[1]=ox/2; }
        else              { nkx=1; kxA[0]=1; ixA[0]=(ox+1)/2; kxA[1]=1; ixA[1]=0; }
        for (int yi = 0; yi < nky; yi++)
        for (int xi = 0; xi < nkx; xi++){
            const float* ip = ib + ((size_t)iyA[yi]*33 + ixA[xi])*32;
            const float* wp = ws5 + (kyA[yi]*3 + kxA[xi])*64;
            #pragma unroll
            for (int g = 0; g < 8; g++){
                F4 iv; iv.v = *(const float4*)(ip + 4*g);
                #pragma unroll
                for (int q = 0; q < 4; q++){
                    int ci = 4*g + q;
                    a0 = fmaf(iv.a[q], wp[ci*2],   a0);
                    a1 = fmaf(iv.a[q], wp[ci*2+1], a1);
                }
            }
        }
        c5s[p]      = a0;
        c5s[NN + p] = a1;
    }
    __syncthreads();
    const float sc = 1.0f / 3969.0f;
    float4* vc4 = (float4*)vcg;
    for (int i = tid; i < 1024; i += 512){
        int ky = i >> 5, ct2 = i & 31;
        float4 o;
        #pragma unroll
        for (int j = 0; j < 2; j++){
            int kx = 2*ct2 + j;
            float re = 0.f, im = 0.f;
            if (kx <= 31){ int o2 = 2*(ky*ND + kx); re = c5s[o2]*sc; im = c5s[o2+1]*sc; }
            else if (kx <= 62){
                int sy = (ND - ky) % ND, sx = ND - kx;
                int o2 = 2*(sy*ND + sx); re = c5s[o2]*sc; im = -c5s[o2+1]*sc;
            }
            if (j == 0){ o.x = re; o.y = im; } else { o.z = re; o.w = im; }
        }
        vc4[(size_t)b*1024 + i] = o;
    }
    if (tid < 32){
        float2* dv2 = (float2*)dvg;
        float2 d = {0.f, 0.f};
        if (tid >= 1){
            int iA = (ND - tid) * ND, iB = tid * ND;
            d.x = (c5s[2*iA]     - c5s[2*iB])     * sc;
            d.y = (c5s[2*iA + 1] + c5s[2*iB + 1]) * sc;
        }
        dv2[b*32 + tid] = d;
    }
}

// ---------------- mega solver, 512 threads, Hermitian-halved DFT -------------
// 512 threads only (1024-thread blocks hard-cap at 64 VGPR and spill — r6/r7).
// Every DFT phase is ONE pass, <=10 accumulators/lane (r8's rep-unrolled
// double-tiles pushed past the 128-VGPR cap and spilled 1.6 GB).
__global__ __launch_bounds__(512) void k_solve(const float* __restrict__ x0g,
                                               const float* __restrict__ f,
                                               const float* __restrict__ kAg,
                                               const float* __restrict__ w1g,
                                               const float* __restrict__ w2g,
                                               const float* __restrict__ Frg,
                                               const float* __restrict__ Fig,
                                               const float* __restrict__ vcg,
                                               const float* __restrict__ dvg,
                                               float* __restrict__ accg){
    __shared__ __align__(16) float xs[63*68 + 8];    // row stride 68
    __shared__ __align__(16) float U[8576];          // rs|tc  /  rP->MC | TtC->CC
    __shared__ float w1s[148], w2s[148], dvs[64], ds_r[32], ds_i[32], red[8];
    const int b = blockIdx.x, tid = threadIdx.x;
    float* rs = U;                       // 63*68 (+4 slack)
    float* tc = U + 4288;                // 63*68 (+4 slack)
    float*  rP  = U;                     // 64x64 (dead after phase A)
    const float4* rP4 = (const float4*)U;
    float2* TtC = (float2*)(U + 4096);   // 64 cols x 32 swizzled slots (f2)
    float2* MC2 = (float2*)U;            // 32 rows x 64 rotated slots (f2)
    float4* CC4 = (float4*)(U + 4096);   // 32 x 33 f4
    const float4* F4r = (const float4*)Frg;
    const float4* F4i = (const float4*)Fig;
    const float4* vc4g = (const float4*)vcg;
    const float* fg = f + (size_t)b*NN;
    float ka[9];
    #pragma unroll
    for (int i = 0; i < 9; i++) ka[i] = kAg[b*9 + i];
    if (tid < 147){ w1s[tid] = w1g[b*147 + tid]; w2s[tid] = w2g[b*147 + tid]; }
    if (tid < 64) dvs[tid] = dvg[b*64 + tid];
    for (int i = tid; i < NN; i += 512) xs[(i/ND)*68 + (i%ND)] = x0g[(size_t)b*NN + i];
    __syncthreads();

    const int kt = tid >> 4, cg = tid & 15;   // DFT A/B/D tiling: 32 rows x 16 col-groups

    for (int it = 0; it < 5; it++){
        // ---- zero union ----
        { float4 z = {0.f,0.f,0.f,0.f}; float4* U4 = (float4*)U;
          for (int i = tid; i < 2144; i += 512) U4[i] = z; }
        __syncthreads();
        // ---- residual -> rs (col c at idx c+3) ----
        for (int i = tid; i < NN; i += 512){
            int y = i / ND, xx = i % ND;
            float s = 0.f;
            #pragma unroll
            for (int dy = 0; dy < 3; dy++){
                int u = y + dy;
                #pragma unroll
                for (int dx = 0; dx < 3; dx++){
                    int v = xx + dx;
                    float p;
                    if (u == 64 || v == 64)    p = 1.0f;
                    else if (u == 0 || v == 0) p = 0.0f;
                    else                       p = xs[(u-1)*68 + (v-1)];
                    s = fmaf(p, ka[dy*3 + dx], s);
                }
            }
            rs[y*68 + 3 + xx] = fg[i] - s;
        }
        __syncthreads();
        // ---- smoother: 1-row x 8-px units, 504 active lanes (r5-proven) ----
        const bool act = tid < 504;
        const int y0 = tid >> 3, x0c = 8*(tid & 7);
        float acc2[8] = {};
        for (int c = 0; c < 3; c++){
            if (act){
                float a1[8] = {};
                for (int dy = 0; dy < 7; dy++){
                    int ry = y0 + dy - 3;
                    if (ry < 0 || ry >= 63) continue;
                    W16 w16;
                    const float4* rp = (const float4*)(rs + ry*68 + x0c);
                    w16.v[0]=rp[0]; w16.v[1]=rp[1]; w16.v[2]=rp[2]; w16.v[3]=rp[3];
                    #pragma unroll
                    for (int dx = 0; dx < 7; dx++){
                        float wv = w1s[c*49 + dy*7 + dx];
                        #pragma unroll
                        for (int t = 0; t < 8; t++) a1[t] = fmaf(wv, w16.a[t+dx], a1[t]);
                    }
                }
                int nw = 63 - x0c; if (nw > 8) nw = 8;
                for (int t = 0; t < nw; t++) tc[y0*68 + 3 + x0c + t] = a1[t];
            }
            __syncthreads();
            if (act){
                for (int dy = 0; dy < 7; dy++){
                    int ry = y0 + dy - 3;
                    if (ry < 0 || ry >= 63) continue;
                    W16 w16;
                    const float4* tp = (const float4*)(tc + ry*68 + x0c);
                    w16.v[0]=tp[0]; w16.v[1]=tp[1]; w16.v[2]=tp[2]; w16.v[3]=tp[3];
                    #pragma unroll
                    for (int dx = 0; dx < 7; dx++){
                        float wv = w2s[c*49 + dy*7 + dx];
                        #pragma unroll
                        for (int t = 0; t < 8; t++) acc2[t] = fmaf(wv, w16.a[t+dx], acc2[t]);
                    }
                }
            }
            __syncthreads();
        }
        if (act){
            int nw = 63 - x0c; if (nw > 8) nw = 8;
            for (int t = 0; t < nw; t++) xs[y0*68 + x0c + t] += acc2[t];
        }
        __syncthreads();
        // ---- residual of updated x -> rP (64x64, zero pad) ----
        for (int i = tid; i < 4096; i += 512){
            int y = i >> 6, xx = i & 63;
            float val = 0.f;
            if (y < 63 && xx < 63){
                float s = 0.f;
                #pragma unroll
                for (int dy = 0; dy < 3; dy++){
                    int u = y + dy;
                    #pragma unroll
                    for (int dx = 0; dx < 3; dx++){
                        int v = xx + dx;
                        float p;
                        if (u == 64 || v == 64)    p = 1.0f;
                        else if (u == 0 || v == 0) p = 0.0f;
                        else                       p = xs[(u-1)*68 + (v-1)];
                        s = fmaf(p, ka[dy*3 + dx], s);
                    }
                }
                val = fg[y*ND + xx] - s;
            }
            rP[i] = val;
        }
        __syncthreads();
        // ---- Phase A: T[k,c] = sum_m F[k,m] r[m,c]; lane = (kt, 4 cols) ----
        {
            float tr0=0.f,ti0=0.f,tr1=0.f,ti1=0.f,tr2=0.f,ti2=0.f,tr3=0.f,ti3=0.f;
            for (int m = 0; m < 63; m++){
                float fr = Frg[m*64 + kt], fi = Fig[m*64 + kt];
                F4 rv; rv.v = rP4[m*16 + cg];
                tr0 = fmaf(fr, rv.a[0], tr0); ti0 = fmaf(fi, rv.a[0], ti0);
                tr1 = fmaf(fr, rv.a[1], tr1); ti1 = fmaf(fi, rv.a[1], ti1);
                tr2 = fmaf(fr, rv.a[2], tr2); ti2 = fmaf(fi, rv.a[2], ti2);
                tr3 = fmaf(fr, rv.a[3], tr3); ti3 = fmaf(fi, rv.a[3], ti3);
            }
            const int c0 = 4*cg;
            TtC[(c0+0)*32 + ((kt + c0 + 0) & 31)] = make_float2(tr0, ti0);
            TtC[(c0+1)*32 + ((kt + c0 + 1) & 31)] = make_float2(tr1, ti1);
            TtC[(c0+2)*32 + ((kt + c0 + 2) & 31)] = make_float2(tr2, ti2);
            TtC[(c0+3)*32 + ((kt + c0 + 3) & 31)] = make_float2(tr3, ti3);
        }
        __syncthreads();
        // ---- Phase B: R = T F, M = R.*v -> MC (rotated); d-vector ----------
        {
            float R0r=0.f,R0i=0.f,R1r=0.f,R1i=0.f,R2r=0.f,R2i=0.f,R3r=0.f,R3i=0.f;
            for (int n = 0; n < 63; n++){
                float2 T = TtC[n*32 + ((kt + n) & 31)];
                F4 fr, fi;
                fr.v = F4r[n*16 + cg];
                fi.v = F4i[n*16 + cg];
                R0r = fmaf(T.x, fr.a[0], R0r); R0r = fmaf(-T.y, fi.a[0], R0r);
                R0i = fmaf(T.x, fi.a[0], R0i); R0i = fmaf( T.y, fr.a[0], R0i);
                R1r = fmaf(T.x, fr.a[1], R1r); R1r = fmaf(-T.y, fi.a[1], R1r);
                R1i = fmaf(T.x, fi.a[1], R1i); R1i = fmaf( T.y, fr.a[1], R1i);
                R2r = fmaf(T.x, fr.a[2], R2r); R2r = fmaf(-T.y, fi.a[2], R2r);
                R2i = fmaf(T.x, fi.a[2], R2i); R2i = fmaf( T.y, fr.a[2], R2i);
                R3r = fmaf(T.x, fr.a[3], R3r); R3r = fmaf(-T.y, fi.a[3], R3r);
                R3i = fmaf(T.x, fi.a[3], R3i); R3i = fmaf( T.y, fr.a[3], R3i);
            }
            if (cg == 0){
                float2 dv = ((const float2*)dvs)[kt];
                ds_r[kt] = R0r*dv.x + R0i*dv.y;
                ds_i[kt] = R0r*dv.y - R0i*dv.x;
            }
            float4 vA = vc4g[(size_t)b*1024 + kt*32 + 2*cg];
            float4 vB = vc4g[(size_t)b*1024 + kt*32 + 2*cg + 1];
            const int c0 = 4*cg, rot = 2*kt;
            MC2[kt*64 + ((c0+0 + rot) & 63)] = make_float2(R0r*vA.x - R0i*vA.y, R0r*vA.y + R0i*vA.x);
            MC2[kt*64 + ((c0+1 + rot) & 63)] = make_float2(R1r*vA.z - R1i*vA.w, R1r*vA.w + R1i*vA.z);
            MC2[kt*64 + ((c0+2 + rot) & 63)] = make_float2(R2r*vB.x - R2i*vB.y, R2r*vB.y + R2i*vB.x);
            MC2[kt*64 + ((c0+3 + rot) & 63)] = make_float2(R3r*vB.z - R3i*vB.w, R3r*vB.w + R3i*vB.z);
        }
        __syncthreads();
        // ---- Phase D: C[kt,q] = sum_l M[kt,l] conj(F[l,q]) -> CC -----------
        {
            float C0r=0.f,C0i=0.f,C1r=0.f,C1i=0.f,C2r=0.f,C2i=0.f,C3r=0.f,C3i=0.f;
            const int rot = 2*kt;
            for (int l = 0; l < 63; l++){
                float2 Mv = MC2[kt*64 + ((l + rot) & 63)];
                F4 fr, fi;
                fr.v = F4r[l*16 + cg];
                fi.v = F4i[l*16 + cg];
                C0r = fmaf(Mv.x, fr.a[0], C0r); C0r = fmaf( Mv.y, fi.a[0], C0r);
                C0i = fmaf(Mv.y, fr.a[0], C0i); C0i = fmaf(-Mv.x, fi.a[0], C0i);
                C1r = fmaf(Mv.x, fr.a[1], C1r); C1r = fmaf( Mv.y, fi.a[1], C1r);
                C1i = fmaf(Mv.y, fr.a[1], C1i); C1i = fmaf(-Mv.x, fi.a[1], C1i);
                C2r = fmaf(Mv.x, fr.a[2], C2r); C2r = fmaf( Mv.y, fi.a[2], C2r);
                C2i = fmaf(Mv.y, fr.a[2], C2i); C2i = fmaf(-Mv.x, fi.a[2], C2i);
                C3r = fmaf(Mv.x, fr.a[3], C3r); C3r = fmaf( Mv.y, fi.a[3], C3r);
                C3i = fmaf(Mv.y, fr.a[3], C3i); C3i = fmaf(-Mv.x, fi.a[3], C3i);
            }
            float sc2 = (kt == 0) ? 0.5f : 1.0f;
            CC4[kt*33 + 2*cg]     = make_float4(C0r*sc2, C0i*sc2, C1r*sc2, C1i*sc2);
            CC4[kt*33 + 2*cg + 1] = make_float4(C2r*sc2, C2i*sc2, C3r*sc2, C3i*sc2);
        }
        __syncthreads();
        // ---- Phase E: y[p,q] = 2 sum_n (Fr*Cr + Fi*Ci) + e[p]; xs += y -----
        {
            const int p = tid >> 3, q2 = 4*(tid & 7);
            if (p < 63){
                float y0=0.f,y1=0.f,y2=0.f,y3=0.f,y4=0.f,y5=0.f,y6=0.f,y7=0.f,e=0.f;
                for (int n = 0; n < 32; n++){
                    float fr = Frg[n*64 + p], fi = Fig[n*64 + p];
                    float4 cA = CC4[n*33 + q2];
                    float4 cB = CC4[n*33 + q2 + 1];
                    float4 cC = CC4[n*33 + q2 + 2];
                    float4 cD = CC4[n*33 + q2 + 3];
                    y0 = fmaf(fr, cA.x, y0); y0 = fmaf(fi, cA.y, y0);
                    y1 = fmaf(fr, cA.z, y1); y1 = fmaf(fi, cA.w, y1);
                    y2 = fmaf(fr, cB.x, y2); y2 = fmaf(fi, cB.y, y2);
                    y3 = fmaf(fr, cB.z, y3); y3 = fmaf(fi, cB.w, y3);
                    y4 = fmaf(fr, cC.x, y4); y4 = fmaf(fi, cC.y, y4);
                    y5 = fmaf(fr, cC.z, y5); y5 = fmaf(fi, cC.w, y5);
                    y6 = fmaf(fr, cD.x, y6); y6 = fmaf(fi, cD.y, y6);
                    y7 = fmaf(fr, cD.z, y7); y7 = fmaf(fi, cD.w, y7);
                    e  = fmaf(fr, ds_r[n], e); e = fmaf(-fi, ds_i[n], e);
                }
                float4* xp = (float4*)(xs + p*68 + 8*(tid & 7));
                float4 xv0 = xp[0], xv1 = xp[1];
                xv0.x += 2.f*y0 + e; xv0.y += 2.f*y1 + e;
                xv0.z += 2.f*y2 + e; xv0.w += 2.f*y3 + e;
                xv1.x += 2.f*y4 + e; xv1.y += 2.f*y5 + e;
                xv1.z += 2.f*y6 + e; xv1.w += 2.f*y7 + e;
                xp[0] = xv0; xp[1] = xv1;
            }
        }
        __syncthreads();
    }
    // ---- final residual + norm ----
    float s = 0.f;
    for (int i = tid; i < NN; i += 512){
        int y = i / ND, xx = i % ND;
        float cv = 0.f;
        #pragma unroll
        for (int dy = 0; dy < 3; dy++){
            int u = y + dy;
            #pragma unroll
            for (int dx = 0; dx < 3; dx++){
                int v = xx + dx;
                float p;
                if (u == 64 || v == 64)    p = 1.0f;
                else if (u == 0 || v == 0) p = 0.0f;
                else                       p = xs[(u-1)*68 + (v-1)];
                cv = fmaf(p, ka[dy*3 + dx], cv);
            }
        }
        float r = fg[i] - cv;
        s = fmaf(r, r, s);
    }
    #pragma unroll
    for (int off = 32; off > 0; off >>= 1) s += __shfl_down(s, off, 64);
    int lane = tid & 63, w = tid >> 6;
    if (lane == 0) red[w] = s;
    __syncthreads();
    if (tid == 0){
        float t = 0.f;
        #pragma unroll
        for (int i = 0; i < 8; i++) t += red[i];
        atomicAdd(accg, t);
    }
}

__global__ void k_final(const float* __restrict__ acc, float* __restrict__ out){
    if (threadIdx.x == 0 && blockIdx.x == 0) out[0] = sqrtf(acc[0]) * (1.0f/256.0f);
}

// ---------------- host ------------------------------------------------------
extern "C" void kernel_launch(void* const* d_in, const int* in_sizes, int n_in,
                              void* d_out, int out_size, void* d_ws, size_t ws_size,
                              hipStream_t stream){
    const float* x0     = (const float*)d_in[0];
    const float* f      = (const float*)d_in[1];
    const float* kA     = (const float*)d_in[2];
    const float* fc1_w1 = (const float*)d_in[3];
    const float* fc1_b1 = (const float*)d_in[4];
    const float* fc1_w2 = (const float*)d_in[5];
    const float* fc1_b2 = (const float*)d_in[6];
    const float* fc2_w1 = (const float*)d_in[7];
    const float* fc2_b1 = (const float*)d_in[8];
    const float* fc2_w2 = (const float*)d_in[9];
    const float* fc2_b2 = (const float*)d_in[10];
    const float* ct1_w  = (const float*)d_in[11];
    const float* ct1_b  = (const float*)d_in[12];
    const float* ct2_w  = (const float*)d_in[13];
    const float* ct2_b  = (const float*)d_in[14];
    const float* ct3_w  = (const float*)d_in[15];
    const float* ct3_b  = (const float*)d_in[16];
    const float* ct4_w  = (const float*)d_in[17];
    const float* ct4_b  = (const float*)d_in[18];
    const float* ct5_w  = (const float*)d_in[19];
    const float* ct5_b  = (const float*)d_in[20];
    float* out = (float*)d_out;

    float* ws = (float*)d_ws;
    size_t off = 0;
    auto take = [&](size_t n){ float* p = ws + off; off += (n + 63) & ~(size_t)63; return p; };
    float* Fr  = take(4096);
    float* Fi  = take(4096);
    float* acc = take(64);
    float* w1b = take((size_t)NB*147);
    float* w2b = take((size_t)NB*147);
    float* vc  = take((size_t)NB*4096);
    float* dvg = take((size_t)NB*64);
    float* c1  = take((size_t)NB*32*25);
    float* c2  = take((size_t)NB*32*81);
    float* c3  = take((size_t)NB*32*289);
    float* c4  = take((size_t)NB*32*1089);
    float* wT1 = take(288);
    float* wT2 = take(9216);
    float* wT3 = take(9216);
    float* wT4 = take(9216);
    float* wT5 = take(576);
    (void)ws_size; (void)in_sizes; (void)n_in; (void)out_size;

    k_tables<<<16, 256, 0, stream>>>(Fr, Fi, acc);
    k_wprep<<<36, 256, 0, stream>>>(ct1_w, ct2_w, ct3_w, ct4_w, ct5_w,
                                    wT1, wT2, wT3, wT4, wT5);
    k_hyper<<<NB, 192, 0, stream>>>(kA, fc1_w1, fc1_b1, fc1_w2, fc1_b2,
                                    fc2_w1, fc2_b1, fc2_w2, fc2_b2, w1b, w2b);
    k_ct1c<<<(NB*25 + 255)/256, 256, 0, stream>>>(kA, wT1, ct1_b, c1);
    k_ct32c<5> <<<NB*2, 512, 0, stream>>>(c1, wT2, ct2_b, c2);
    k_ct32c<9> <<<NB*2, 512, 0, stream>>>(c2, wT3, ct3_b, c3);
    k_ct32c<17><<<NB*2, 512, 0, stream>>>(c3, wT4, ct4_b, c4);
    k_ct5v<<<NB, 512, 0, stream>>>(c4, wT5, ct5_b, vc, dvg);
    k_solve<<<NB, 512, 0, stream>>>(x0, f, kA, w1b, w2b, Fr, Fi, vc, dvg, acc);
    k_final<<<1, 64, 0, stream>>>(acc, out);
}

// Round 10
// 495.794 us; speedup vs baseline: 3.5800x; 1.0558x over previous
//
#include <hip/hip_runtime.h>
#include <math.h>

#define NB   256
#define ND   63
#define NN   3969        // 63*63
#define MIDc 32

__device__ __forceinline__ float gelu_f(float v){
    return 0.5f * v * (1.0f + erff(v * 0.70710678118654752440f));
}

#define FMA4(A, W, S) { (A).x=fmaf((W).x,(S),(A).x); (A).y=fmaf((W).y,(S),(A).y); \
                        (A).z=fmaf((W).z,(S),(A).z); (A).w=fmaf((W).w,(S),(A).w); }

union F4 { float4 v; float a[4]; };
union W16 { float4 v[4]; float a[16]; };

// -------- DFT tables + weight prep + acc reset (merged, independent work) ----
__global__ void k_prep(const float* __restrict__ w1, const float* __restrict__ w2,
                       const float* __restrict__ w3, const float* __restrict__ w4,
                       const float* __restrict__ w5,
                       float* __restrict__ o1, float* __restrict__ o2,
                       float* __restrict__ o3, float* __restrict__ o4,
                       float* __restrict__ o5,
                       float* __restrict__ Fr, float* __restrict__ Fi,
                       float* __restrict__ acc){
    int idx = blockIdx.x * blockDim.x + threadIdx.x;
    if (idx < 4096){
        int r = idx >> 6, c = idx & 63;
        float vr = 0.f, vi = 0.f;
        if (r < 63 && c < 63){
            int m = (r * c) % 63;
            float ang = 6.283185307179586f * (float)m / 63.0f;
            vr = cosf(ang); vi = -sinf(ang);
        }
        Fr[idx] = vr; Fi[idx] = vi;
    }
    if (idx < 9216){
        int co = idx & 31, t = idx >> 5;
        int ci = t & 31, tap = t >> 5;
        int ky = tap / 3, kx = tap % 3;
        int src = ((ci*32 + co)*3 + ky)*3 + kx;
        o2[idx] = w2[src]; o3[idx] = w3[src]; o4[idx] = w4[src];
    }
    if (idx < 576){
        int co = idx & 1, t = idx >> 1;
        int ci = t & 31, tap = t >> 5;
        int ky = tap / 3, kx = tap % 3;
        o5[idx] = w5[((ci*2 + co)*3 + ky)*3 + kx];
    }
    if (idx < 288){
        int co = idx & 31, tap = idx >> 5;
        int ky = tap / 3, kx = tap % 3;
        o1[idx] = w1[(co*3 + ky)*3 + kx];
    }
    if (idx == 0) acc[0] = 0.f;
}

// ---------------- hypernet ----------------------------------------------------
__global__ void k_hyper(const float* __restrict__ kA,
                        const float* __restrict__ w1a, const float* __restrict__ b1a,
                        const float* __restrict__ w2a, const float* __restrict__ b2a,
                        const float* __restrict__ w1b, const float* __restrict__ b1b,
                        const float* __restrict__ w2b, const float* __restrict__ b2b,
                        float* __restrict__ out1, float* __restrict__ out2){
    __shared__ float a[9];
    __shared__ float hid[100];
    int b = blockIdx.x, tid = threadIdx.x;
    if (tid < 9) a[tid] = kA[b*9 + tid];
    __syncthreads();
    if (tid < 100){
        float s = b1a[tid];
        #pragma unroll
        for (int i = 0; i < 9; i++) s = fmaf(a[i], w1a[i*100 + tid], s);
        hid[tid] = gelu_f(s);
    }
    __syncthreads();
    if (tid < 147){
        float s = b2a[tid];
        for (int k = 0; k < 100; k++) s = fmaf(hid[k], w2a[k*147 + tid], s);
        out1[b*147 + tid] = s;
    }
    __syncthreads();
    if (tid < 100){
        float s = b1b[tid];
        #pragma unroll
        for (int i = 0; i < 9; i++) s = fmaf(a[i], w1b[i*100 + tid], s);
        hid[tid] = gelu_f(s);
    }
    __syncthreads();
    if (tid < 147){
        float s = b2b[tid];
        for (int k = 0; k < 100; k++) s = fmaf(hid[k], w2b[k*147 + tid], s);
        out2[b*147 + tid] = s;
    }
}

// ---------------- ct1: 1->32, channel-last out --------------------------------
__global__ void k_ct1c(const float* __restrict__ kA, const float* __restrict__ wT1,
                       const float* __restrict__ bias, float* __restrict__ out){
    int idx = blockIdx.x * blockDim.x + threadIdx.x;
    if (idx >= NB*25) return;
    int p = idx % 25, b = idx / 25;
    int oy = p / 5, ox = p % 5;
    F4 acc[8];
    #pragma unroll
    for (int q = 0; q < 8; q++) acc[q].v = ((const float4*)bias)[q];
    int nky, kyA[2], iyA[2];
    if (oy & 1){ nky=2; kyA[0]=0; iyA[0]=(oy+1)/2; kyA[1]=2; iyA[1]=(oy-1)/2; }
    else       { nky=1; kyA[0]=1; iyA[0]=oy/2; kyA[1]=1; iyA[1]=0; }
    int nkx, kxA[2], ixA[2];
    if (ox & 1){ nkx=2; kxA[0]=0; ixA[0]=(ox+1)/2; kxA[1]=2; ixA[1]=(ox-1)/2; }
    else       { nkx=1; kxA[0]=1; ixA[0]=ox/2; kxA[1]=1; ixA[1]=0; }
    const float* ab = kA + b*9;
    for (int yi = 0; yi < nky; yi++)
    for (int xi = 0; xi < nkx; xi++){
        float v = ab[iyA[yi]*3 + ixA[xi]];
        const float4* wq = (const float4*)(wT1 + (kyA[yi]*3 + kxA[xi])*32);
        #pragma unroll
        for (int q = 0; q < 8; q++){ float4 w = wq[q]; FMA4(acc[q].v, w, v); }
    }
    float* ob = out + (size_t)idx*32;
    #pragma unroll
    for (int q = 0; q < 8; q++){
        float4 g; g.x=gelu_f(acc[q].a[0]); g.y=gelu_f(acc[q].a[1]);
        g.z=gelu_f(acc[q].a[2]); g.w=gelu_f(acc[q].a[3]);
        ((float4*)ob)[q] = g;
    }
}

// ------------- ct 32->32, stride2 pad1 k3, gelu, channel-last. 2 blocks/sample.
template<int HIN>
__global__ __launch_bounds__(512) void k_ct32c(const float* __restrict__ in,
                                               const float* __restrict__ wT,
                                               const float* __restrict__ bias,
                                               float* __restrict__ out){
    constexpr int HOUT = 2*HIN - 1;
    constexpr int HINP = (HIN + 3) & ~3;
    constexpr int OCT  = (HOUT + 7) / 8;
    constexpr int UPR  = OCT * 4;
    constexpr int NODD = (HOUT/2) * UPR;
    constexpr int TOT  = HOUT * UPR;
    constexpr int HT   = (TOT + 1) / 2;
    constexpr int INEL = 32*HIN*HINP;
    __shared__ __align__(16) float lds[INEL + 9216 + 32];
    float* in_s   = lds;
    float* w_s    = lds + INEL;
    float* bias_s = lds + INEL + 9216;
    const int b = blockIdx.x >> 1, h = blockIdx.x & 1;
    const int tid = threadIdx.x;
    { const float4* src = (const float4*)wT; float4* dst = (float4*)w_s;
      for (int i = tid; i < 2304; i += 512) dst[i] = src[i]; }
    if (tid < 32) bias_s[tid] = bias[tid];
    { const float* gi = in + (size_t)b * (32*HIN*HIN);
      for (int i = tid; i < 32*HIN*HIN; i += 512){
        int ci = i & 31, px = i >> 5;
        int y = px / HIN, x = px % HIN;
        in_s[ci*(HIN*HINP) + y*HINP + x] = gi[i];
      } }
    __syncthreads();
    float* ob0 = out + (size_t)b*(HOUT*HOUT*32);
    const int u0 = h*HT, u1 = (u0 + HT < TOT) ? (u0 + HT) : TOT;
    for (int u = u0 + tid; u < u1; u += 512){
        int r, s;
        if (u < NODD){ r = 2*(u/UPR) + 1; s = u % UPR; }
        else { int v = u - NODD; r = 2*(v/UPR); s = v % UPR; }
        const int m = s >> 2, cog = s & 3;
        const int x4 = 4*m;
        F4 acc[8][2];
        { float4 b0 = ((const float4*)bias_s)[cog*2];
          float4 b1 = ((const float4*)bias_s)[cog*2+1];
          #pragma unroll
          for (int p = 0; p < 8; p++){ acc[p][0].v = b0; acc[p][1].v = b1; } }
        int nky, kyA[2], iyA[2];
        if (r & 1){ int rI = r >> 1; nky = 2; kyA[0]=0; iyA[0]=rI+1; kyA[1]=2; iyA[1]=rI; }
        else      { nky = 1; kyA[0]=1; iyA[0]= r >> 1; kyA[1]=1; iyA[1]=0; }
        for (int yi = 0; yi < nky; yi++){
            const float* ip = in_s + iyA[yi]*HINP + x4;
            const float* wp = w_s + kyA[yi]*3*1024 + cog*8;
            #pragma unroll 2
            for (int ci = 0; ci < 32; ci++){
                F4 iv0, iv1;
                iv0.v = *(const float4*)(ip);
                iv1.v = *(const float4*)(ip + 4);
                float4 w0a = *(const float4*)(wp);
                float4 w0b = *(const float4*)(wp + 4);
                float4 w1a = *(const float4*)(wp + 1024);
                float4 w1b = *(const float4*)(wp + 1028);
                float4 w2a = *(const float4*)(wp + 2048);
                float4 w2b = *(const float4*)(wp + 2052);
                #pragma unroll
                for (int p = 0; p < 4; p++){
                    float ev = iv0.a[p];
                    FMA4(acc[2*p][0].v, w1a, ev);
                    FMA4(acc[2*p][1].v, w1b, ev);
                    float o0 = (p < 3) ? iv0.a[p+1] : iv1.a[0];
                    FMA4(acc[2*p+1][0].v, w0a, o0);
                    FMA4(acc[2*p+1][1].v, w0b, o0);
                    FMA4(acc[2*p+1][0].v, w2a, ev);
                    FMA4(acc[2*p+1][1].v, w2b, ev);
                }
                ip += HIN*HINP;
                wp += 32;
            }
        }
        int lim = HOUT - 8*m; if (lim > 8) lim = 8;
        float* ob = ob0 + ((size_t)r*HOUT + 8*m)*32 + cog*8;
        for (int e = 0; e < lim; e++){
            float4 g0, g1;
            g0.x=gelu_f(acc[e][0].a[0]); g0.y=gelu_f(acc[e][0].a[1]);
            g0.z=gelu_f(acc[e][0].a[2]); g0.w=gelu_f(acc[e][0].a[3]);
            g1.x=gelu_f(acc[e][1].a[0]); g1.y=gelu_f(acc[e][1].a[1]);
            g1.z=gelu_f(acc[e][1].a[2]); g1.w=gelu_f(acc[e][1].a[3]);
            *(float4*)(ob + (size_t)e*32)     = g0;
            *(float4*)(ob + (size_t)e*32 + 4) = g1;
        }
    }
}

// ---- ct5 (32->2) + build v rows 0..31 (interleaved) + dv --------------------
__global__ __launch_bounds__(512) void k_ct5v(const float* __restrict__ in,
                                              const float* __restrict__ wT5,
                                              const float* __restrict__ bias,
                                              float* __restrict__ vcg,
                                              float* __restrict__ dvg){
    __shared__ float ws5[576];
    __shared__ float c5s[2*NN];
    const int b = blockIdx.x, tid = threadIdx.x;
    for (int i = tid; i < 576; i += 512) ws5[i] = wT5[i];
    __syncthreads();
    const float* ib = in + (size_t)b * (32*33*33);
    float b0 = bias[0], b1 = bias[1];
    for (int p = tid; p < NN; p += 512){
        int oy = p / ND, ox = p % ND;
        float a0 = b0, a1 = b1;
        int nky, kyA[2], iyA[2];
        if ((oy & 1) == 0){ nky=2; kyA[0]=0; iyA[0]=oy/2+1; kyA[1]=2; iyA[1]=oy/2; }
        else              { nky=1; kyA[0]=1; iyA[0]=(oy+1)/2; kyA[1]=1; iyA[1]=0; }
        int nkx, kxA[2], ixA[2];
        if ((ox & 1) == 0){ nkx=2; kxA[0]=0; ixA[0]=ox/2+1; kxA[1]=2; ixA[1]=ox/2; }
        else              { nkx=1; kxA[0]=1; ixA[0]=(ox+1)/2; kxA[1]=1; ixA[1]=0; }
        for (int yi = 0; yi < nky; yi++)
        for (int xi = 0; xi < nkx; xi++){
            const float* ip = ib + ((size_t)iyA[yi]*33 + ixA[xi])*32;
            const float* wp = ws5 + (kyA[yi]*3 + kxA[xi])*64;
            #pragma unroll
            for (int g = 0; g < 8; g++){
                F4 iv; iv.v = *(const float4*)(ip + 4*g);
                #pragma unroll
                for (int q = 0; q < 4; q++){
                    int ci = 4*g + q;
                    a0 = fmaf(iv.a[q], wp[ci*2],   a0);
                    a1 = fmaf(iv.a[q], wp[ci*2+1], a1);
                }
            }
        }
        c5s[p]      = a0;
        c5s[NN + p] = a1;
    }
    __syncthreads();
    const float sc = 1.0f / 3969.0f;
    float4* vc4 = (float4*)vcg;
    for (int i = tid; i < 1024; i += 512){
        int ky = i >> 5, ct2 = i & 31;
        float4 o;
        #pragma unroll
        for (int j = 0; j < 2; j++){
            int kx = 2*ct2 + j;
            float re = 0.f, im = 0.f;
            if (kx <= 31){ int o2 = 2*(ky*ND + kx); re = c5s[o2]*sc; im = c5s[o2+1]*sc; }
            else if (kx <= 62){
                int sy = (ND - ky) % ND, sx = ND - kx;
                int o2 = 2*(sy*ND + sx); re = c5s[o2]*sc; im = -c5s[o2+1]*sc;
            }
            if (j == 0){ o.x = re; o.y = im; } else { o.z = re; o.w = im; }
        }
        vc4[(size_t)b*1024 + i] = o;
    }
    if (tid < 32){
        float2* dv2 = (float2*)dvg;
        float2 d = {0.f, 0.f};
        if (tid >= 1){
            int iA = (ND - tid) * ND, iB = tid * ND;
            d.x = (c5s[2*iA]     - c5s[2*iB])     * sc;
            d.y = (c5s[2*iA + 1] + c5s[2*iB + 1]) * sc;
        }
        dv2[b*32 + tid] = d;
    }
}

// ---------------- mega solver, 512 threads, Hermitian-halved DFT -------------
// 512 threads only (1024-thread blocks hard-cap at 64 VGPR and spill — r6/r7).
// One pass per phase, <=10 acc/lane (r8 lesson). F tables staged in LDS (r9's
// ~440 L2-latency global loads/lane/iter were the main stall source at 8 waves).
__global__ __launch_bounds__(512) void k_solve(const float* __restrict__ x0g,
                                               const float* __restrict__ f,
                                               const float* __restrict__ kAg,
                                               const float* __restrict__ w1g,
                                               const float* __restrict__ w2g,
                                               const float* __restrict__ Frg,
                                               const float* __restrict__ Fig,
                                               const float* __restrict__ vcg,
                                               const float* __restrict__ dvg,
                                               float* __restrict__ accg){
    __shared__ __align__(16) float xs[63*68 + 8];    // row stride 68
    __shared__ __align__(16) float U[8576];          // rs|tc  /  rP->MC | TtC->CC
    __shared__ __align__(16) float Fs_r[4096];       // F real  (64x64)
    __shared__ __align__(16) float Fs_i[4096];       // F imag
    __shared__ float w1s[148], w2s[148], dvs[64], ds_r[32], ds_i[32], red[8];
    const int b = blockIdx.x, tid = threadIdx.x;
    float* rs = U;                       // 63*68 (+4 slack)
    float* tc = U + 4288;                // 63*68 (+4 slack)
    float*  rP  = U;                     // 64x64 (dead after phase A)
    const float4* rP4 = (const float4*)U;
    float2* TtC = (float2*)(U + 4096);   // 64 cols x 32 swizzled slots (f2)
    float2* MC2 = (float2*)U;            // 32 rows x 64 rotated slots (f2)
    float4* CC4 = (float4*)(U + 4096);   // 32 x 33 f4
    const float4* F4r = (const float4*)Fs_r;
    const float4* F4i = (const float4*)Fs_i;
    const float4* vc4g = (const float4*)vcg;
    const float* fg = f + (size_t)b*NN;
    float ka[9];
    #pragma unroll
    for (int i = 0; i < 9; i++) ka[i] = kAg[b*9 + i];
    if (tid < 147){ w1s[tid] = w1g[b*147 + tid]; w2s[tid] = w2g[b*147 + tid]; }
    if (tid < 64) dvs[tid] = dvg[b*64 + tid];
    for (int i = tid; i < 4096; i += 512){ Fs_r[i] = Frg[i]; Fs_i[i] = Fig[i]; }
    for (int i = tid; i < NN; i += 512) xs[(i/ND)*68 + (i%ND)] = x0g[(size_t)b*NN + i];
    __syncthreads();

    const int kt = tid >> 4, cg = tid & 15;   // DFT A/B/D tiling: 32 rows x 16 col-groups

    for (int it = 0; it < 5; it++){
        // ---- zero union ----
        { float4 z = {0.f,0.f,0.f,0.f}; float4* U4 = (float4*)U;
          for (int i = tid; i < 2144; i += 512) U4[i] = z; }
        __syncthreads();
        // ---- residual -> rs (col c at idx c+3) ----
        for (int i = tid; i < NN; i += 512){
            int y = i / ND, xx = i % ND;
            float s = 0.f;
            #pragma unroll
            for (int dy = 0; dy < 3; dy++){
                int u = y + dy;
                #pragma unroll
                for (int dx = 0; dx < 3; dx++){
                    int v = xx + dx;
                    float p;
                    if (u == 64 || v == 64)    p = 1.0f;
                    else if (u == 0 || v == 0) p = 0.0f;
                    else                       p = xs[(u-1)*68 + (v-1)];
                    s = fmaf(p, ka[dy*3 + dx], s);
                }
            }
            rs[y*68 + 3 + xx] = fg[i] - s;
        }
        __syncthreads();
        // ---- smoother: 1-row x 8-px units, 504 active lanes (r5-proven) ----
        const bool act = tid < 504;
        const int y0 = tid >> 3, x0c = 8*(tid & 7);
        float acc2[8] = {};
        for (int c = 0; c < 3; c++){
            if (act){
                float a1[8] = {};
                for (int dy = 0; dy < 7; dy++){
                    int ry = y0 + dy - 3;
                    if (ry < 0 || ry >= 63) continue;
                    W16 w16;
                    const float4* rp = (const float4*)(rs + ry*68 + x0c);
                    w16.v[0]=rp[0]; w16.v[1]=rp[1]; w16.v[2]=rp[2]; w16.v[3]=rp[3];
                    #pragma unroll
                    for (int dx = 0; dx < 7; dx++){
                        float wv = w1s[c*49 + dy*7 + dx];
                        #pragma unroll
                        for (int t = 0; t < 8; t++) a1[t] = fmaf(wv, w16.a[t+dx], a1[t]);
                    }
                }
                int nw = 63 - x0c; if (nw > 8) nw = 8;
                for (int t = 0; t < nw; t++) tc[y0*68 + 3 + x0c + t] = a1[t];
            }
            __syncthreads();
            if (act){
                for (int dy = 0; dy < 7; dy++){
                    int ry = y0 + dy - 3;
                    if (ry < 0 || ry >= 63) continue;
                    W16 w16;
                    const float4* tp = (const float4*)(tc + ry*68 + x0c);
                    w16.v[0]=tp[0]; w16.v[1]=tp[1]; w16.v[2]=tp[2]; w16.v[3]=tp[3];
                    #pragma unroll
                    for (int dx = 0; dx < 7; dx++){
                        float wv = w2s[c*49 + dy*7 + dx];
                        #pragma unroll
                        for (int t = 0; t < 8; t++) acc2[t] = fmaf(wv, w16.a[t+dx], acc2[t]);
                    }
                }
            }
            __syncthreads();
        }
        if (act){
            int nw = 63 - x0c; if (nw > 8) nw = 8;
            for (int t = 0; t < nw; t++) xs[y0*68 + x0c + t] += acc2[t];
        }
        __syncthreads();
        // ---- residual of updated x -> rP (64x64, zero pad) ----
        for (int i = tid; i < 4096; i += 512){
            int y = i >> 6, xx = i & 63;
            float val = 0.f;
            if (y < 63 && xx < 63){
                float s = 0.f;
                #pragma unroll
                for (int dy = 0; dy < 3; dy++){
                    int u = y + dy;
                    #pragma unroll
                    for (int dx = 0; dx < 3; dx++){
                        int v = xx + dx;
                        float p;
                        if (u == 64 || v == 64)    p = 1.0f;
                        else if (u == 0 || v == 0) p = 0.0f;
                        else                       p = xs[(u-1)*68 + (v-1)];
                        s = fmaf(p, ka[dy*3 + dx], s);
                    }
                }
                val = fg[y*ND + xx] - s;
            }
            rP[i] = val;
        }
        __syncthreads();
        // ---- Phase A: T[k,c] = sum_m F[k,m] r[m,c]; lane = (kt, 4 cols) ----
        {
            float tr0=0.f,ti0=0.f,tr1=0.f,ti1=0.f,tr2=0.f,ti2=0.f,tr3=0.f,ti3=0.f;
            for (int m = 0; m < 63; m++){
                float fr = Fs_r[m*64 + kt], fi = Fs_i[m*64 + kt];
                F4 rv; rv.v = rP4[m*16 + cg];
                tr0 = fmaf(fr, rv.a[0], tr0); ti0 = fmaf(fi, rv.a[0], ti0);
                tr1 = fmaf(fr, rv.a[1], tr1); ti1 = fmaf(fi, rv.a[1], ti1);
                tr2 = fmaf(fr, rv.a[2], tr2); ti2 = fmaf(fi, rv.a[2], ti2);
                tr3 = fmaf(fr, rv.a[3], tr3); ti3 = fmaf(fi, rv.a[3], ti3);
            }
            const int c0 = 4*cg;
            TtC[(c0+0)*32 + ((kt + c0 + 0) & 31)] = make_float2(tr0, ti0);
            TtC[(c0+1)*32 + ((kt + c0 + 1) & 31)] = make_float2(tr1, ti1);
            TtC[(c0+2)*32 + ((kt + c0 + 2) & 31)] = make_float2(tr2, ti2);
            TtC[(c0+3)*32 + ((kt + c0 + 3) & 31)] = make_float2(tr3, ti3);
        }
        __syncthreads();
        // ---- Phase B: R = T F, M = R.*v -> MC (rotated); d-vector ----------
        {
            float R0r=0.f,R0i=0.f,R1r=0.f,R1i=0.f,R2r=0.f,R2i=0.f,R3r=0.f,R3i=0.f;
            for (int n = 0; n < 63; n++){
                float2 T = TtC[n*32 + ((kt + n) & 31)];
                F4 fr, fi;
                fr.v = F4r[n*16 + cg];
                fi.v = F4i[n*16 + cg];
                R0r = fmaf(T.x, fr.a[0], R0r); R0r = fmaf(-T.y, fi.a[0], R0r);
                R0i = fmaf(T.x, fi.a[0], R0i); R0i = fmaf( T.y, fr.a[0], R0i);
                R1r = fmaf(T.x, fr.a[1], R1r); R1r = fmaf(-T.y, fi.a[1], R1r);
                R1i = fmaf(T.x, fi.a[1], R1i); R1i = fmaf( T.y, fr.a[1], R1i);
                R2r = fmaf(T.x, fr.a[2], R2r); R2r = fmaf(-T.y, fi.a[2], R2r);
                R2i = fmaf(T.x, fi.a[2], R2i); R2i = fmaf( T.y, fr.a[2], R2i);
                R3r = fmaf(T.x, fr.a[3], R3r); R3r = fmaf(-T.y, fi.a[3], R3r);
                R3i = fmaf(T.x, fi.a[3], R3i); R3i = fmaf( T.y, fr.a[3], R3i);
            }
            if (cg == 0){
                float2 dv = ((const float2*)dvs)[kt];
                ds_r[kt] = R0r*dv.x + R0i*dv.y;
                ds_i[kt] = R0r*dv.y - R0i*dv.x;
            }
            float4 vA = vc4g[(size_t)b*1024 + kt*32 + 2*cg];
            float4 vB = vc4g[(size_t)b*1024 + kt*32 + 2*cg + 1];
            const int c0 = 4*cg, rot = 2*kt;
            MC2[kt*64 + ((c0+0 + rot) & 63)] = make_float2(R0r*vA.x - R0i*vA.y, R0r*vA.y + R0i*vA.x);
            MC2[kt*64 + ((c0+1 + rot) & 63)] = make_float2(R1r*vA.z - R1i*vA.w, R1r*vA.w + R1i*vA.z);
            MC2[kt*64 + ((c0+2 + rot) & 63)] = make_float2(R2r*vB.x - R2i*vB.y, R2r*vB.y + R2i*vB.x);
            MC2[kt*64 + ((c0+3 + rot) & 63)] = make_float2(R3r*vB.z - R3i*vB.w, R3r*vB.w + R3i*vB.z);
        }
        __syncthreads();
        // ---- Phase D: C[kt,q] = sum_l M[kt,l] conj(F[l,q]) -> CC -----------
        {
            float C0r=0.f,C0i=0.f,C1r=0.f,C1i=0.f,C2r=0.f,C2i=0.f,C3r=0.f,C3i=0.f;
            const int rot = 2*kt;
            for (int l = 0; l < 63; l++){
                float2 Mv = MC2[kt*64 + ((l + rot) & 63)];
                F4 fr, fi;
                fr.v = F4r[l*16 + cg];
                fi.v = F4i[l*16 + cg];
                C0r = fmaf(Mv.x, fr.a[0], C0r); C0r = fmaf( Mv.y, fi.a[0], C0r);
                C0i = fmaf(Mv.y, fr.a[0], C0i); C0i = fmaf(-Mv.x, fi.a[0], C0i);
                C1r = fmaf(Mv.x, fr.a[1], C1r); C1r = fmaf( Mv.y, fi.a[1], C1r);
                C1i = fmaf(Mv.y, fr.a[1], C1i); C1i = fmaf(-Mv.x, fi.a[1], C1i);
                C2r = fmaf(Mv.x, fr.a[2], C2r); C2r = fmaf( Mv.y, fi.a[2], C2r);
                C2i = fmaf(Mv.y, fr.a[2], C2i); C2i = fmaf(-Mv.x, fi.a[2], C2i);
                C3r = fmaf(Mv.x, fr.a[3], C3r); C3r = fmaf( Mv.y, fi.a[3], C3r);
                C3i = fmaf(Mv.y, fr.a[3], C3i); C3i = fmaf(-Mv.x, fi.a[3], C3i);
            }
            float sc2 = (kt == 0) ? 0.5f : 1.0f;
            CC4[kt*33 + 2*cg]     = make_float4(C0r*sc2, C0i*sc2, C1r*sc2, C1i*sc2);
            CC4[kt*33 + 2*cg + 1] = make_float4(C2r*sc2, C2i*sc2, C3r*sc2, C3i*sc2);
        }
        __syncthreads();
        // ---- Phase E: strided-q tiling (qb, qb+8, qb+16, qb+24) ------------
        // Per-instruction CC4 bank residue = (n+qb) mod 8 -> all 8 groups,
        // conflict-free (r9's q2=4*(tid&7) hit only 2 groups -> 4-way).
        {
            const int p = tid >> 3, qb = tid & 7;
            if (p < 63){
                float y0=0.f,y1=0.f,y2=0.f,y3=0.f,y4=0.f,y5=0.f,y6=0.f,y7=0.f,e=0.f;
                for (int n = 0; n < 32; n++){
                    float fr = Fs_r[n*64 + p], fi = Fs_i[n*64 + p];
                    float4 cA = CC4[n*33 + qb];
                    float4 cB = CC4[n*33 + qb + 8];
                    float4 cC = CC4[n*33 + qb + 16];
                    float4 cD = CC4[n*33 + qb + 24];
                    y0 = fmaf(fr, cA.x, y0); y0 = fmaf(fi, cA.y, y0);
                    y1 = fmaf(fr, cA.z, y1); y1 = fmaf(fi, cA.w, y1);
                    y2 = fmaf(fr, cB.x, y2); y2 = fmaf(fi, cB.y, y2);
                    y3 = fmaf(fr, cB.z, y3); y3 = fmaf(fi, cB.w, y3);
                    y4 = fmaf(fr, cC.x, y4); y4 = fmaf(fi, cC.y, y4);
                    y5 = fmaf(fr, cC.z, y5); y5 = fmaf(fi, cC.w, y5);
                    y6 = fmaf(fr, cD.x, y6); y6 = fmaf(fi, cD.y, y6);
                    y7 = fmaf(fr, cD.z, y7); y7 = fmaf(fi, cD.w, y7);
                    e  = fmaf(fr, ds_r[n], e); e = fmaf(-fi, ds_i[n], e);
                }
                float* xrow = xs + p*68;
                float2* xp0 = (float2*)(xrow + 2*qb);
                float2* xp1 = (float2*)(xrow + 2*qb + 16);
                float2* xp2 = (float2*)(xrow + 2*qb + 32);
                float2* xp3 = (float2*)(xrow + 2*qb + 48);
                float2 v0 = *xp0, v1 = *xp1, v2 = *xp2, v3 = *xp3;
                v0.x += 2.f*y0 + e; v0.y += 2.f*y1 + e;
                v1.x += 2.f*y2 + e; v1.y += 2.f*y3 + e;
                v2.x += 2.f*y4 + e; v2.y += 2.f*y5 + e;
                v3.x += 2.f*y6 + e; v3.y += 2.f*y7 + e;
                *xp0 = v0; *xp1 = v1; *xp2 = v2; *xp3 = v3;
            }
        }
        __syncthreads();
    }
    // ---- final residual + norm ----
    float s = 0.f;
    for (int i = tid; i < NN; i += 512){
        int y = i / ND, xx = i % ND;
        float cv = 0.f;
        #pragma unroll
        for (int dy = 0; dy < 3; dy++){
            int u = y + dy;
            #pragma unroll
            for (int dx = 0; dx < 3; dx++){
                int v = xx + dx;
                float p;
                if (u == 64 || v == 64)    p = 1.0f;
                else if (u == 0 || v == 0) p = 0.0f;
                else                       p = xs[(u-1)*68 + (v-1)];
                cv = fmaf(p, ka[dy*3 + dx], cv);
            }
        }
        float r = fg[i] - cv;
        s = fmaf(r, r, s);
    }
    #pragma unroll
    for (int off = 32; off > 0; off >>= 1) s += __shfl_down(s, off, 64);
    int lane = tid & 63, w = tid >> 6;
    if (lane == 0) red[w] = s;
    __syncthreads();
    if (tid == 0){
        float t = 0.f;
        #pragma unroll
        for (int i = 0; i < 8; i++) t += red[i];
        atomicAdd(accg, t);
    }
}

__global__ void k_final(const float* __restrict__ acc, float* __restrict__ out){
    if (threadIdx.x == 0 && blockIdx.x == 0) out[0] = sqrtf(acc[0]) * (1.0f/256.0f);
}

// ---------------- host ------------------------------------------------------
extern "C" void kernel_launch(void* const* d_in, const int* in_sizes, int n_in,
                              void* d_out, int out_size, void* d_ws, size_t ws_size,
                              hipStream_t stream){
    const float* x0     = (const float*)d_in[0];
    const float* f      = (const float*)d_in[1];
    const float* kA     = (const float*)d_in[2];
    const float* fc1_w1 = (const float*)d_in[3];
    const float* fc1_b1 = (const float*)d_in[4];
    const float* fc1_w2 = (const float*)d_in[5];
    const float* fc1_b2 = (const float*)d_in[6];
    const float* fc2_w1 = (const float*)d_in[7];
    const float* fc2_b1 = (const float*)d_in[8];
    const float* fc2_w2 = (const float*)d_in[9];
    const float* fc2_b2 = (const float*)d_in[10];
    const float* ct1_w  = (const float*)d_in[11];
    const float* ct1_b  = (const float*)d_in[12];
    const float* ct2_w  = (const float*)d_in[13];
    const float* ct2_b  = (const float*)d_in[14];
    const float* ct3_w  = (const float*)d_in[15];
    const float* ct3_b  = (const float*)d_in[16];
    const float* ct4_w  = (const float*)d_in[17];
    const float* ct4_b  = (const float*)d_in[18];
    const float* ct5_w  = (const float*)d_in[19];
    const float* ct5_b  = (const float*)d_in[20];
    float* out = (float*)d_out;

    float* ws = (float*)d_ws;
    size_t off = 0;
    auto take = [&](size_t n){ float* p = ws + off; off += (n + 63) & ~(size_t)63; return p; };
    float* Fr  = take(4096);
    float* Fi  = take(4096);
    float* acc = take(64);
    float* w1b = take((size_t)NB*147);
    float* w2b = take((size_t)NB*147);
    float* vc  = take((size_t)NB*4096);
    float* dvg = take((size_t)NB*64);
    float* c1  = take((size_t)NB*32*25);
    float* c2  = take((size_t)NB*32*81);
    float* c3  = take((size_t)NB*32*289);
    float* c4  = take((size_t)NB*32*1089);
    float* wT1 = take(288);
    float* wT2 = take(9216);
    float* wT3 = take(9216);
    float* wT4 = take(9216);
    float* wT5 = take(576);
    (void)ws_size; (void)in_sizes; (void)n_in; (void)out_size;

    k_prep<<<36, 256, 0, stream>>>(ct1_w, ct2_w, ct3_w, ct4_w, ct5_w,
                                   wT1, wT2, wT3, wT4, wT5, Fr, Fi, acc);
    k_hyper<<<NB, 192, 0, stream>>>(kA, fc1_w1, fc1_b1, fc1_w2, fc1_b2,
                                    fc2_w1, fc2_b1, fc2_w2, fc2_b2, w1b, w2b);
    k_ct1c<<<(NB*25 + 255)/256, 256, 0, stream>>>(kA, wT1, ct1_b, c1);
    k_ct32c<5> <<<NB*2, 512, 0, stream>>>(c1, wT2, ct2_b, c2);
    k_ct32c<9> <<<NB*2, 512, 0, stream>>>(c2, wT3, ct3_b, c3);
    k_ct32c<17><<<NB*2, 512, 0, stream>>>(c3, wT4, ct4_b, c4);
    k_ct5v<<<NB, 512, 0, stream>>>(c4, wT5, ct5_b, vc, dvg);
    k_solve<<<NB, 512, 0, stream>>>(x0, f, kA, w1b, w2b, Fr, Fi, vc, dvg, acc);
    k_final<<<1, 64, 0, stream>>>(acc, out);
}

// Round 11
// 438.523 us; speedup vs baseline: 4.0476x; 1.1306x over previous
//
#include <hip/hip_runtime.h>
#include <math.h>

#define NB   256
#define ND   63
#define NN   3969        // 63*63
#define MIDc 32

__device__ __forceinline__ float gelu_f(float v){
    return 0.5f * v * (1.0f + erff(v * 0.70710678118654752440f));
}

#define FMA4(A, W, S) { (A).x=fmaf((W).x,(S),(A).x); (A).y=fmaf((W).y,(S),(A).y); \
                        (A).z=fmaf((W).z,(S),(A).z); (A).w=fmaf((W).w,(S),(A).w); }

union F4 { float4 v; float a[4]; };
union W16 { float4 v[4]; float a[16]; };

// ---- hypernet + (DFT tables, weight transposition, acc reset) merged --------
__global__ void k_hyperprep(const float* __restrict__ kA,
                            const float* __restrict__ w1a, const float* __restrict__ b1a,
                            const float* __restrict__ w2a, const float* __restrict__ b2a,
                            const float* __restrict__ w1b, const float* __restrict__ b1b,
                            const float* __restrict__ w2b, const float* __restrict__ b2b,
                            float* __restrict__ out1, float* __restrict__ out2,
                            const float* __restrict__ cw1, const float* __restrict__ cw2,
                            const float* __restrict__ cw3, const float* __restrict__ cw4,
                            const float* __restrict__ cw5,
                            float* __restrict__ o1, float* __restrict__ o2,
                            float* __restrict__ o3, float* __restrict__ o4,
                            float* __restrict__ o5,
                            float* __restrict__ Fr, float* __restrict__ Fi,
                            float* __restrict__ acc){
    __shared__ float a[9];
    __shared__ float hid[100];
    int b = blockIdx.x, tid = threadIdx.x;
    // ---- prep part (blocks 0..35 carry it; no barriers inside) ----
    {
        int idx = b * 256 + tid;
        if (idx < 4096){
            int r = idx >> 6, c = idx & 63;
            float vr = 0.f, vi = 0.f;
            if (r < 63 && c < 63){
                int m = (r * c) % 63;
                float ang = 6.283185307179586f * (float)m / 63.0f;
                vr = cosf(ang); vi = -sinf(ang);
            }
            Fr[idx] = vr; Fi[idx] = vi;
        }
        if (idx < 9216){
            int co = idx & 31, t = idx >> 5;
            int ci = t & 31, tap = t >> 5;
            int ky = tap / 3, kx = tap % 3;
            int src = ((ci*32 + co)*3 + ky)*3 + kx;
            o2[idx] = cw2[src]; o3[idx] = cw3[src]; o4[idx] = cw4[src];
        }
        if (idx < 576){
            int co = idx & 1, t = idx >> 1;
            int ci = t & 31, tap = t >> 5;
            int ky = tap / 3, kx = tap % 3;
            o5[idx] = cw5[((ci*2 + co)*3 + ky)*3 + kx];
        }
        if (idx < 288){
            int co = idx & 31, tap = idx >> 5;
            int ky = tap / 3, kx = tap % 3;
            o1[idx] = cw1[(co*3 + ky)*3 + kx];
        }
        if (idx == 0) acc[0] = 0.f;
    }
    // ---- hypernet part ----
    if (tid < 9) a[tid] = kA[b*9 + tid];
    __syncthreads();
    if (tid < 100){
        float s = b1a[tid];
        #pragma unroll
        for (int i = 0; i < 9; i++) s = fmaf(a[i], w1a[i*100 + tid], s);
        hid[tid] = gelu_f(s);
    }
    __syncthreads();
    if (tid < 147){
        float s = b2a[tid];
        for (int k = 0; k < 100; k++) s = fmaf(hid[k], w2a[k*147 + tid], s);
        out1[b*147 + tid] = s;
    }
    __syncthreads();
    if (tid < 100){
        float s = b1b[tid];
        #pragma unroll
        for (int i = 0; i < 9; i++) s = fmaf(a[i], w1b[i*100 + tid], s);
        hid[tid] = gelu_f(s);
    }
    __syncthreads();
    if (tid < 147){
        float s = b2b[tid];
        for (int k = 0; k < 100; k++) s = fmaf(hid[k], w2b[k*147 + tid], s);
        out2[b*147 + tid] = s;
    }
}

// ---- fused ct1+ct2+ct3 per sample: c1,c2 in LDS (pad-33 layout), c3 global --
__global__ __launch_bounds__(512) void k_ct123(const float* __restrict__ kA,
                                               const float* __restrict__ wT1,
                                               const float* __restrict__ wT2,
                                               const float* __restrict__ wT3,
                                               const float* __restrict__ b1,
                                               const float* __restrict__ b2,
                                               const float* __restrict__ b3,
                                               float* __restrict__ c3out){
    __shared__ __align__(16) float wbuf[9216];   // wT2 then wT3 [tap][ci][co32]
    __shared__ float w1s[288];
    __shared__ float c1s[25*33];                 // [px][ci] stride 33
    __shared__ float c2s[81*33];
    __shared__ float b1s[32], b2s[32], b3s[32];
    const int b = blockIdx.x, tid = threadIdx.x;
    { const float4* src = (const float4*)wT2; float4* dst = (float4*)wbuf;
      for (int i = tid; i < 2304; i += 512) dst[i] = src[i]; }
    if (tid < 288) w1s[tid] = wT1[tid];
    if (tid < 32){ b1s[tid] = b1[tid]; b2s[tid] = b2[tid]; b3s[tid] = b3[tid]; }
    __syncthreads();
    // ---- ct1: 3x3 -> 5x5, 1->32ch. 200 units = 25 px x 8 co-quads ----------
    if (tid < 200){
        int px = tid >> 3, q = tid & 7;
        int oy = px / 5, ox = px % 5;
        F4 acc; acc.v = ((const float4*)b1s)[q];
        int nky, kyA[2], iyA[2];
        if (oy & 1){ nky=2; kyA[0]=0; iyA[0]=(oy+1)/2; kyA[1]=2; iyA[1]=(oy-1)/2; }
        else       { nky=1; kyA[0]=1; iyA[0]=oy/2; kyA[1]=1; iyA[1]=0; }
        int nkx, kxA[2], ixA[2];
        if (ox & 1){ nkx=2; kxA[0]=0; ixA[0]=(ox+1)/2; kxA[1]=2; ixA[1]=(ox-1)/2; }
        else       { nkx=1; kxA[0]=1; ixA[0]=ox/2; kxA[1]=1; ixA[1]=0; }
        const float* ab = kA + b*9;
        for (int yi = 0; yi < nky; yi++)
        for (int xi = 0; xi < nkx; xi++){
            float v = ab[iyA[yi]*3 + ixA[xi]];
            float4 w = *(const float4*)(w1s + (kyA[yi]*3 + kxA[xi])*32 + 4*q);
            FMA4(acc.v, w, v);
        }
        float* op = c1s + px*33 + 4*q;
        op[0]=gelu_f(acc.a[0]); op[1]=gelu_f(acc.a[1]);
        op[2]=gelu_f(acc.a[2]); op[3]=gelu_f(acc.a[3]);
    }
    __syncthreads();
    // ---- ct2: 5x5 -> 9x9, 32->32. 648 units = 81 px x 8 co-quads -----------
    for (int u = tid; u < 648; u += 512){
        int px = u >> 3, q = u & 7;
        int oy = px / 9, ox = px % 9;
        F4 acc; acc.v = ((const float4*)b2s)[q];
        int nky, kyA[2], iyA[2];
        if (oy & 1){ nky=2; kyA[0]=0; iyA[0]=(oy+1)/2; kyA[1]=2; iyA[1]=(oy-1)/2; }
        else       { nky=1; kyA[0]=1; iyA[0]=oy/2; kyA[1]=1; iyA[1]=0; }
        int nkx, kxA[2], ixA[2];
        if (ox & 1){ nkx=2; kxA[0]=0; ixA[0]=(ox+1)/2; kxA[1]=2; ixA[1]=(ox-1)/2; }
        else       { nkx=1; kxA[0]=1; ixA[0]=ox/2; kxA[1]=1; ixA[1]=0; }
        for (int yi = 0; yi < nky; yi++)
        for (int xi = 0; xi < nkx; xi++){
            const float* ip = c1s + (iyA[yi]*5 + ixA[xi])*33;
            const float* wp = wbuf + (kyA[yi]*3 + kxA[xi])*1024 + 4*q;
            #pragma unroll 8
            for (int ci = 0; ci < 32; ci++){
                float v = ip[ci];
                float4 w = *(const float4*)(wp + ci*32);
                FMA4(acc.v, w, v);
            }
        }
        float* op = c2s + px*33 + 4*q;
        op[0]=gelu_f(acc.a[0]); op[1]=gelu_f(acc.a[1]);
        op[2]=gelu_f(acc.a[2]); op[3]=gelu_f(acc.a[3]);
    }
    __syncthreads();
    // ---- reload weight buffer with wT3 ----
    { const float4* src = (const float4*)wT3; float4* dst = (float4*)wbuf;
      for (int i = tid; i < 2304; i += 512) dst[i] = src[i]; }
    __syncthreads();
    // ---- ct3: 9x9 -> 17x17, 32->32. 2312 units = 289 px x 8 co-quads -------
    float* ob = c3out + (size_t)b * (289*32);
    for (int u = tid; u < 2312; u += 512){
        int px = u >> 3, q = u & 7;
        int oy = px / 17, ox = px % 17;
        F4 acc; acc.v = ((const float4*)b3s)[q];
        int nky, kyA[2], iyA[2];
        if (oy & 1){ nky=2; kyA[0]=0; iyA[0]=(oy+1)/2; kyA[1]=2; iyA[1]=(oy-1)/2; }
        else       { nky=1; kyA[0]=1; iyA[0]=oy/2; kyA[1]=1; iyA[1]=0; }
        int nkx, kxA[2], ixA[2];
        if (ox & 1){ nkx=2; kxA[0]=0; ixA[0]=(ox+1)/2; kxA[1]=2; ixA[1]=(ox-1)/2; }
        else       { nkx=1; kxA[0]=1; ixA[0]=ox/2; kxA[1]=1; ixA[1]=0; }
        for (int yi = 0; yi < nky; yi++)
        for (int xi = 0; xi < nkx; xi++){
            const float* ip = c2s + (iyA[yi]*9 + ixA[xi])*33;
            const float* wp = wbuf + (kyA[yi]*3 + kxA[xi])*1024 + 4*q;
            #pragma unroll 8
            for (int ci = 0; ci < 32; ci++){
                float v = ip[ci];
                float4 w = *(const float4*)(wp + ci*32);
                FMA4(acc.v, w, v);
            }
        }
        float4 g;
        g.x=gelu_f(acc.a[0]); g.y=gelu_f(acc.a[1]);
        g.z=gelu_f(acc.a[2]); g.w=gelu_f(acc.a[3]);
        *(float4*)(ob + (size_t)px*32 + 4*q) = g;
    }
}

// ------------- ct4 32->32, stride2 pad1 k3, gelu, channel-last. 2 blk/sample.
template<int HIN>
__global__ __launch_bounds__(512) void k_ct32c(const float* __restrict__ in,
                                               const float* __restrict__ wT,
                                               const float* __restrict__ bias,
                                               float* __restrict__ out){
    constexpr int HOUT = 2*HIN - 1;
    constexpr int HINP = (HIN + 3) & ~3;
    constexpr int OCT  = (HOUT + 7) / 8;
    constexpr int UPR  = OCT * 4;
    constexpr int NODD = (HOUT/2) * UPR;
    constexpr int TOT  = HOUT * UPR;
    constexpr int HT   = (TOT + 1) / 2;
    constexpr int INEL = 32*HIN*HINP;
    __shared__ __align__(16) float lds[INEL + 9216 + 32];
    float* in_s   = lds;
    float* w_s    = lds + INEL;
    float* bias_s = lds + INEL + 9216;
    const int b = blockIdx.x >> 1, h = blockIdx.x & 1;
    const int tid = threadIdx.x;
    { const float4* src = (const float4*)wT; float4* dst = (float4*)w_s;
      for (int i = tid; i < 2304; i += 512) dst[i] = src[i]; }
    if (tid < 32) bias_s[tid] = bias[tid];
    { const float* gi = in + (size_t)b * (32*HIN*HIN);
      for (int i = tid; i < 32*HIN*HIN; i += 512){
        int ci = i & 31, px = i >> 5;
        int y = px / HIN, x = px % HIN;
        in_s[ci*(HIN*HINP) + y*HINP + x] = gi[i];
      } }
    __syncthreads();
    float* ob0 = out + (size_t)b*(HOUT*HOUT*32);
    const int u0 = h*HT, u1 = (u0 + HT < TOT) ? (u0 + HT) : TOT;
    for (int u = u0 + tid; u < u1; u += 512){
        int r, s;
        if (u < NODD){ r = 2*(u/UPR) + 1; s = u % UPR; }
        else { int v = u - NODD; r = 2*(v/UPR); s = v % UPR; }
        const int m = s >> 2, cog = s & 3;
        const int x4 = 4*m;
        F4 acc[8][2];
        { float4 b0 = ((const float4*)bias_s)[cog*2];
          float4 b1 = ((const float4*)bias_s)[cog*2+1];
          #pragma unroll
          for (int p = 0; p < 8; p++){ acc[p][0].v = b0; acc[p][1].v = b1; } }
        int nky, kyA[2], iyA[2];
        if (r & 1){ int rI = r >> 1; nky = 2; kyA[0]=0; iyA[0]=rI+1; kyA[1]=2; iyA[1]=rI; }
        else      { nky = 1; kyA[0]=1; iyA[0]= r >> 1; kyA[1]=1; iyA[1]=0; }
        for (int yi = 0; yi < nky; yi++){
            const float* ip = in_s + iyA[yi]*HINP + x4;
            const float* wp = w_s + kyA[yi]*3*1024 + cog*8;
            #pragma unroll 2
            for (int ci = 0; ci < 32; ci++){
                F4 iv0, iv1;
                iv0.v = *(const float4*)(ip);
                iv1.v = *(const float4*)(ip + 4);
                float4 w0a = *(const float4*)(wp);
                float4 w0b = *(const float4*)(wp + 4);
                float4 w1a = *(const float4*)(wp + 1024);
                float4 w1b = *(const float4*)(wp + 1028);
                float4 w2a = *(const float4*)(wp + 2048);
                float4 w2b = *(const float4*)(wp + 2052);
                #pragma unroll
                for (int p = 0; p < 4; p++){
                    float ev = iv0.a[p];
                    FMA4(acc[2*p][0].v, w1a, ev);
                    FMA4(acc[2*p][1].v, w1b, ev);
                    float o0 = (p < 3) ? iv0.a[p+1] : iv1.a[0];
                    FMA4(acc[2*p+1][0].v, w0a, o0);
                    FMA4(acc[2*p+1][1].v, w0b, o0);
                    FMA4(acc[2*p+1][0].v, w2a, ev);
                    FMA4(acc[2*p+1][1].v, w2b, ev);
                }
                ip += HIN*HINP;
                wp += 32;
            }
        }
        int lim = HOUT - 8*m; if (lim > 8) lim = 8;
        float* ob = ob0 + ((size_t)r*HOUT + 8*m)*32 + cog*8;
        for (int e = 0; e < lim; e++){
            float4 g0, g1;
            g0.x=gelu_f(acc[e][0].a[0]); g0.y=gelu_f(acc[e][0].a[1]);
            g0.z=gelu_f(acc[e][0].a[2]); g0.w=gelu_f(acc[e][0].a[3]);
            g1.x=gelu_f(acc[e][1].a[0]); g1.y=gelu_f(acc[e][1].a[1]);
            g1.z=gelu_f(acc[e][1].a[2]); g1.w=gelu_f(acc[e][1].a[3]);
            *(float4*)(ob + (size_t)e*32)     = g0;
            *(float4*)(ob + (size_t)e*32 + 4) = g1;
        }
    }
}

// ---- ct5 (32->2) + build v rows 0..31 (interleaved) + dv --------------------
__global__ __launch_bounds__(512) void k_ct5v(const float* __restrict__ in,
                                              const float* __restrict__ wT5,
                                              const float* __restrict__ bias,
                                              float* __restrict__ vcg,
                                              float* __restrict__ dvg){
    __shared__ float ws5[576];
    __shared__ float c5s[2*NN];
    const int b = blockIdx.x, tid = threadIdx.x;
    for (int i = tid; i < 576; i += 512) ws5[i] = wT5[i];
    __syncthreads();
    const float* ib = in + (size_t)b * (32*33*33);
    float b0 = bias[0], b1 = bias[1];
    for (int p = tid; p < NN; p += 512){
        int oy = p / ND, ox = p % ND;
        float a0 = b0, a1 = b1;
        int nky, kyA[2], iyA[2];
        if ((oy & 1) == 0){ nky=2; kyA[0]=0; iyA[0]=oy/2+1; kyA[1]=2; iyA[1]=oy/2; }
        else              { nky=1; kyA[0]=1; iyA[0]=(oy+1)/2; kyA[1]=1; iyA[1]=0; }
        int nkx, kxA[2], ixA[2];
        if ((ox & 1) == 0){ nkx=2; kxA[0]=0; ixA[0]=ox/2+1; kxA[1]=2; ixA[1]=ox/2; }
        else              { nkx=1; kxA[0]=1; ixA[0]=(ox+1)/2; kxA[1]=1; ixA[1]=0; }
        for (int yi = 0; yi < nky; yi++)
        for (int xi = 0; xi < nkx; xi++){
            const float* ip = ib + ((size_t)iyA[yi]*33 + ixA[xi])*32;
            const float* wp = ws5 + (kyA[yi]*3 + kxA[xi])*64;
            #pragma unroll
            for (int g = 0; g < 8; g++){
                F4 iv; iv.v = *(const float4*)(ip + 4*g);
                #pragma unroll
                for (int q = 0; q < 4; q++){
                    int ci = 4*g + q;
                    a0 = fmaf(iv.a[q], wp[ci*2],   a0);
                    a1 = fmaf(iv.a[q], wp[ci*2+1], a1);
                }
            }
        }
        c5s[p]      = a0;
        c5s[NN + p] = a1;
    }
    __syncthreads();
    const float sc = 1.0f / 3969.0f;
    float4* vc4 = (float4*)vcg;
    for (int i = tid; i < 1024; i += 512){
        int ky = i >> 5, ct2 = i & 31;
        float4 o;
        #pragma unroll
        for (int j = 0; j < 2; j++){
            int kx = 2*ct2 + j;
            float re = 0.f, im = 0.f;
            if (kx <= 31){ int o2 = 2*(ky*ND + kx); re = c5s[o2]*sc; im = c5s[o2+1]*sc; }
            else if (kx <= 62){
                int sy = (ND - ky) % ND, sx = ND - kx;
                int o2 = 2*(sy*ND + sx); re = c5s[o2]*sc; im = -c5s[o2+1]*sc;
            }
            if (j == 0){ o.x = re; o.y = im; } else { o.z = re; o.w = im; }
        }
        vc4[(size_t)b*1024 + i] = o;
    }
    if (tid < 32){
        float2* dv2 = (float2*)dvg;
        float2 d = {0.f, 0.f};
        if (tid >= 1){
            int iA = (ND - tid) * ND, iB = tid * ND;
            d.x = (c5s[2*iA]     - c5s[2*iB])     * sc;
            d.y = (c5s[2*iA + 1] + c5s[2*iB + 1]) * sc;
        }
        dv2[b*32 + tid] = d;
    }
}

// ---------------- mega solver, 512 threads, Hermitian-halved DFT -------------
// 512 threads only (1024-thread blocks hard-cap at 64 VGPR and spill — r6/r7).
// One pass per phase, <=10 acc/lane (r8 lesson). F tables in LDS (r10 win).
// Grid = 256 = 1 block/CU: occupancy is grid-capped at 8 waves — by design.
__global__ __launch_bounds__(512) void k_solve(const float* __restrict__ x0g,
                                               const float* __restrict__ f,
                                               const float* __restrict__ kAg,
                                               const float* __restrict__ w1g,
                                               const float* __restrict__ w2g,
                                               const float* __restrict__ Frg,
                                               const float* __restrict__ Fig,
                                               const float* __restrict__ vcg,
                                               const float* __restrict__ dvg,
                                               float* __restrict__ accg){
    __shared__ __align__(16) float xs[63*68 + 8];    // row stride 68
    __shared__ __align__(16) float U[8576];          // rs|tc  /  rP->MC | TtC->CC
    __shared__ __align__(16) float Fs_r[4096];       // F real  (64x64)
    __shared__ __align__(16) float Fs_i[4096];       // F imag
    __shared__ float w1s[148], w2s[148], dvs[64], ds_r[32], ds_i[32], red[8];
    const int b = blockIdx.x, tid = threadIdx.x;
    float* rs = U;                       // 63*68 (+4 slack)
    float* tc = U + 4288;                // 63*68 (+4 slack)
    float*  rP  = U;                     // 64x64 (dead after phase A)
    const float4* rP4 = (const float4*)U;
    float2* TtC = (float2*)(U + 4096);   // 64 cols x 32 swizzled slots (f2)
    float2* MC2 = (float2*)U;            // 32 rows x 64 rotated slots (f2)
    float4* CC4 = (float4*)(U + 4096);   // 32 x 33 f4
    const float4* F4r = (const float4*)Fs_r;
    const float4* F4i = (const float4*)Fs_i;
    const float4* vc4g = (const float4*)vcg;
    const float* fg = f + (size_t)b*NN;
    float ka[9];
    #pragma unroll
    for (int i = 0; i < 9; i++) ka[i] = kAg[b*9 + i];
    if (tid < 147){ w1s[tid] = w1g[b*147 + tid]; w2s[tid] = w2g[b*147 + tid]; }
    if (tid < 64) dvs[tid] = dvg[b*64 + tid];
    for (int i = tid; i < 4096; i += 512){ Fs_r[i] = Frg[i]; Fs_i[i] = Fig[i]; }
    for (int i = tid; i < NN; i += 512) xs[(i/ND)*68 + (i%ND)] = x0g[(size_t)b*NN + i];
    __syncthreads();

    const int kt = tid >> 4, cg = tid & 15;   // DFT A/B/D tiling: 32 rows x 16 col-groups

    for (int it = 0; it < 5; it++){
        // ---- zero union ----
        { float4 z = {0.f,0.f,0.f,0.f}; float4* U4 = (float4*)U;
          for (int i = tid; i < 2144; i += 512) U4[i] = z; }
        __syncthreads();
        // ---- residual -> rs (col c at idx c+3) ----
        for (int i = tid; i < NN; i += 512){
            int y = i / ND, xx = i % ND;
            float s = 0.f;
            #pragma unroll
            for (int dy = 0; dy < 3; dy++){
                int u = y + dy;
                #pragma unroll
                for (int dx = 0; dx < 3; dx++){
                    int v = xx + dx;
                    float p;
                    if (u == 64 || v == 64)    p = 1.0f;
                    else if (u == 0 || v == 0) p = 0.0f;
                    else                       p = xs[(u-1)*68 + (v-1)];
                    s = fmaf(p, ka[dy*3 + dx], s);
                }
            }
            rs[y*68 + 3 + xx] = fg[i] - s;
        }
        __syncthreads();
        // ---- smoother: 1-row x 8-px units, 504 active lanes (r5-proven) ----
        const bool act = tid < 504;
        const int y0 = tid >> 3, x0c = 8*(tid & 7);
        float acc2[8] = {};
        for (int c = 0; c < 3; c++){
            if (act){
                float a1[8] = {};
                for (int dy = 0; dy < 7; dy++){
                    int ry = y0 + dy - 3;
                    if (ry < 0 || ry >= 63) continue;
                    W16 w16;
                    const float4* rp = (const float4*)(rs + ry*68 + x0c);
                    w16.v[0]=rp[0]; w16.v[1]=rp[1]; w16.v[2]=rp[2]; w16.v[3]=rp[3];
                    #pragma unroll
                    for (int dx = 0; dx < 7; dx++){
                        float wv = w1s[c*49 + dy*7 + dx];
                        #pragma unroll
                        for (int t = 0; t < 8; t++) a1[t] = fmaf(wv, w16.a[t+dx], a1[t]);
                    }
                }
                int nw = 63 - x0c; if (nw > 8) nw = 8;
                for (int t = 0; t < nw; t++) tc[y0*68 + 3 + x0c + t] = a1[t];
            }
            __syncthreads();
            if (act){
                for (int dy = 0; dy < 7; dy++){
                    int ry = y0 + dy - 3;
                    if (ry < 0 || ry >= 63) continue;
                    W16 w16;
                    const float4* tp = (const float4*)(tc + ry*68 + x0c);
                    w16.v[0]=tp[0]; w16.v[1]=tp[1]; w16.v[2]=tp[2]; w16.v[3]=tp[3];
                    #pragma unroll
                    for (int dx = 0; dx < 7; dx++){
                        float wv = w2s[c*49 + dy*7 + dx];
                        #pragma unroll
                        for (int t = 0; t < 8; t++) acc2[t] = fmaf(wv, w16.a[t+dx], acc2[t]);
                    }
                }
            }
            __syncthreads();
        }
        if (act){
            int nw = 63 - x0c; if (nw > 8) nw = 8;
            for (int t = 0; t < nw; t++) xs[y0*68 + x0c + t] += acc2[t];
        }
        __syncthreads();
        // ---- residual of updated x -> rP (64x64, zero pad) ----
        for (int i = tid; i < 4096; i += 512){
            int y = i >> 6, xx = i & 63;
            float val = 0.f;
            if (y < 63 && xx < 63){
                float s = 0.f;
                #pragma unroll
                for (int dy = 0; dy < 3; dy++){
                    int u = y + dy;
                    #pragma unroll
                    for (int dx = 0; dx < 3; dx++){
                        int v = xx + dx;
                        float p;
                        if (u == 64 || v == 64)    p = 1.0f;
                        else if (u == 0 || v == 0) p = 0.0f;
                        else                       p = xs[(u-1)*68 + (v-1)];
                        s = fmaf(p, ka[dy*3 + dx], s);
                    }
                }
                val = fg[y*ND + xx] - s;
            }
            rP[i] = val;
        }
        __syncthreads();
        // ---- Phase A: T[k,c] = sum_m F[k,m] r[m,c]; lane = (kt, 4 cols) ----
        {
            float tr0=0.f,ti0=0.f,tr1=0.f,ti1=0.f,tr2=0.f,ti2=0.f,tr3=0.f,ti3=0.f;
            for (int m = 0; m < 63; m++){
                float fr = Fs_r[m*64 + kt], fi = Fs_i[m*64 + kt];
                F4 rv; rv.v = rP4[m*16 + cg];
                tr0 = fmaf(fr, rv.a[0], tr0); ti0 = fmaf(fi, rv.a[0], ti0);
                tr1 = fmaf(fr, rv.a[1], tr1); ti1 = fmaf(fi, rv.a[1], ti1);
                tr2 = fmaf(fr, rv.a[2], tr2); ti2 = fmaf(fi, rv.a[2], ti2);
                tr3 = fmaf(fr, rv.a[3], tr3); ti3 = fmaf(fi, rv.a[3], ti3);
            }
            const int c0 = 4*cg;
            TtC[(c0+0)*32 + ((kt + c0 + 0) & 31)] = make_float2(tr0, ti0);
            TtC[(c0+1)*32 + ((kt + c0 + 1) & 31)] = make_float2(tr1, ti1);
            TtC[(c0+2)*32 + ((kt + c0 + 2) & 31)] = make_float2(tr2, ti2);
            TtC[(c0+3)*32 + ((kt + c0 + 3) & 31)] = make_float2(tr3, ti3);
        }
        __syncthreads();
        // ---- Phase B: R = T F, M = R.*v -> MC (rot=kt, conflict-free) ------
        {
            float R0r=0.f,R0i=0.f,R1r=0.f,R1i=0.f,R2r=0.f,R2i=0.f,R3r=0.f,R3i=0.f;
            for (int n = 0; n < 63; n++){
                float2 T = TtC[n*32 + ((kt + n) & 31)];
                F4 fr, fi;
                fr.v = F4r[n*16 + cg];
                fi.v = F4i[n*16 + cg];
                R0r = fmaf(T.x, fr.a[0], R0r); R0r = fmaf(-T.y, fi.a[0], R0r);
                R0i = fmaf(T.x, fi.a[0], R0i); R0i = fmaf( T.y, fr.a[0], R0i);
                R1r = fmaf(T.x, fr.a[1], R1r); R1r = fmaf(-T.y, fi.a[1], R1r);
                R1i = fmaf(T.x, fi.a[1], R1i); R1i = fmaf( T.y, fr.a[1], R1i);
                R2r = fmaf(T.x, fr.a[2], R2r); R2r = fmaf(-T.y, fi.a[2], R2r);
                R2i = fmaf(T.x, fi.a[2], R2i); R2i = fmaf( T.y, fr.a[2], R2i);
                R3r = fmaf(T.x, fr.a[3], R3r); R3r = fmaf(-T.y, fi.a[3], R3r);
                R3i = fmaf(T.x, fi.a[3], R3i); R3i = fmaf( T.y, fr.a[3], R3i);
            }
            if (cg == 0){
                float2 dv = ((const float2*)dvs)[kt];
                ds_r[kt] = R0r*dv.x + R0i*dv.y;
                ds_i[kt] = R0r*dv.y - R0i*dv.x;
            }
            float4 vA = vc4g[(size_t)b*1024 + kt*32 + 2*cg];
            float4 vB = vc4g[(size_t)b*1024 + kt*32 + 2*cg + 1];
            const int c0 = 4*cg, rot = kt;
            MC2[kt*64 + ((c0+0 + rot) & 63)] = make_float2(R0r*vA.x - R0i*vA.y, R0r*vA.y + R0i*vA.x);
            MC2[kt*64 + ((c0+1 + rot) & 63)] = make_float2(R1r*vA.z - R1i*vA.w, R1r*vA.w + R1i*vA.z);
            MC2[kt*64 + ((c0+2 + rot) & 63)] = make_float2(R2r*vB.x - R2i*vB.y, R2r*vB.y + R2i*vB.x);
            MC2[kt*64 + ((c0+3 + rot) & 63)] = make_float2(R3r*vB.z - R3i*vB.w, R3r*vB.w + R3i*vB.z);
        }
        __syncthreads();
        // ---- Phase D: C[kt,q] = sum_l M[kt,l] conj(F[l,q]) -> CC -----------
        {
            float C0r=0.f,C0i=0.f,C1r=0.f,C1i=0.f,C2r=0.f,C2i=0.f,C3r=0.f,C3i=0.f;
            const int rot = kt;
            for (int l = 0; l < 63; l++){
                float2 Mv = MC2[kt*64 + ((l + rot) & 63)];
                F4 fr, fi;
                fr.v = F4r[l*16 + cg];
                fi.v = F4i[l*16 + cg];
                C0r = fmaf(Mv.x, fr.a[0], C0r); C0r = fmaf( Mv.y, fi.a[0], C0r);
                C0i = fmaf(Mv.y, fr.a[0], C0i); C0i = fmaf(-Mv.x, fi.a[0], C0i);
                C1r = fmaf(Mv.x, fr.a[1], C1r); C1r = fmaf( Mv.y, fi.a[1], C1r);
                C1i = fmaf(Mv.y, fr.a[1], C1i); C1i = fmaf(-Mv.x, fi.a[1], C1i);
                C2r = fmaf(Mv.x, fr.a[2], C2r); C2r = fmaf( Mv.y, fi.a[2], C2r);
                C2i = fmaf(Mv.y, fr.a[2], C2i); C2i = fmaf(-Mv.x, fi.a[2], C2i);
                C3r = fmaf(Mv.x, fr.a[3], C3r); C3r = fmaf( Mv.y, fi.a[3], C3r);
                C3i = fmaf(Mv.y, fr.a[3], C3i); C3i = fmaf(-Mv.x, fi.a[3], C3i);
            }
            float sc2 = (kt == 0) ? 0.5f : 1.0f;
            CC4[kt*33 + 2*cg]     = make_float4(C0r*sc2, C0i*sc2, C1r*sc2, C1i*sc2);
            CC4[kt*33 + 2*cg + 1] = make_float4(C2r*sc2, C2i*sc2, C3r*sc2, C3i*sc2);
        }
        __syncthreads();
        // ---- Phase E: strided-q tiling (qb, qb+8, qb+16, qb+24) ------------
        {
            const int p = tid >> 3, qb = tid & 7;
            if (p < 63){
                float y0v=0.f,y1v=0.f,y2v=0.f,y3v=0.f,y4v=0.f,y5v=0.f,y6v=0.f,y7v=0.f,e=0.f;
                for (int n = 0; n < 32; n++){
                    float fr = Fs_r[n*64 + p], fi = Fs_i[n*64 + p];
                    float4 cA = CC4[n*33 + qb];
                    float4 cB = CC4[n*33 + qb + 8];
                    float4 cC = CC4[n*33 + qb + 16];
                    float4 cD = CC4[n*33 + qb + 24];
                    y0v = fmaf(fr, cA.x, y0v); y0v = fmaf(fi, cA.y, y0v);
                    y1v = fmaf(fr, cA.z, y1v); y1v = fmaf(fi, cA.w, y1v);
                    y2v = fmaf(fr, cB.x, y2v); y2v = fmaf(fi, cB.y, y2v);
                    y3v = fmaf(fr, cB.z, y3v); y3v = fmaf(fi, cB.w, y3v);
                    y4v = fmaf(fr, cC.x, y4v); y4v = fmaf(fi, cC.y, y4v);
                    y5v = fmaf(fr, cC.z, y5v); y5v = fmaf(fi, cC.w, y5v);
                    y6v = fmaf(fr, cD.x, y6v); y6v = fmaf(fi, cD.y, y6v);
                    y7v = fmaf(fr, cD.z, y7v); y7v = fmaf(fi, cD.w, y7v);
                    e  = fmaf(fr, ds_r[n], e); e = fmaf(-fi, ds_i[n], e);
                }
                float* xrow = xs + p*68;
                float2* xp0 = (float2*)(xrow + 2*qb);
                float2* xp1 = (float2*)(xrow + 2*qb + 16);
                float2* xp2 = (float2*)(xrow + 2*qb + 32);
                float2* xp3 = (float2*)(xrow + 2*qb + 48);
                float2 v0 = *xp0, v1 = *xp1, v2 = *xp2, v3 = *xp3;
                v0.x += 2.f*y0v + e; v0.y += 2.f*y1v + e;
                v1.x += 2.f*y2v + e; v1.y += 2.f*y3v + e;
                v2.x += 2.f*y4v + e; v2.y += 2.f*y5v + e;
                v3.x += 2.f*y6v + e; v3.y += 2.f*y7v + e;
                *xp0 = v0; *xp1 = v1; *xp2 = v2; *xp3 = v3;
            }
        }
        __syncthreads();
    }
    // ---- final residual + norm ----
    float s = 0.f;
    for (int i = tid; i < NN; i += 512){
        int y = i / ND, xx = i % ND;
        float cv = 0.f;
        #pragma unroll
        for (int dy = 0; dy < 3; dy++){
            int u = y + dy;
            #pragma unroll
            for (int dx = 0; dx < 3; dx++){
                int v = xx + dx;
                float p;
                if (u == 64 || v == 64)    p = 1.0f;
                else if (u == 0 || v == 0) p = 0.0f;
                else                       p = xs[(u-1)*68 + (v-1)];
                cv = fmaf(p, ka[dy*3 + dx], cv);
            }
        }
        float r = fg[i] - cv;
        s = fmaf(r, r, s);
    }
    #pragma unroll
    for (int off = 32; off > 0; off >>= 1) s += __shfl_down(s, off, 64);
    int lane = tid & 63, w = tid >> 6;
    if (lane == 0) red[w] = s;
    __syncthreads();
    if (tid == 0){
        float t = 0.f;
        #pragma unroll
        for (int i = 0; i < 8; i++) t += red[i];
        atomicAdd(accg, t);
    }
}

__global__ void k_final(const float* __restrict__ acc, float* __restrict__ out){
    if (threadIdx.x == 0 && blockIdx.x == 0) out[0] = sqrtf(acc[0]) * (1.0f/256.0f);
}

// ---------------- host ------------------------------------------------------
extern "C" void kernel_launch(void* const* d_in, const int* in_sizes, int n_in,
                              void* d_out, int out_size, void* d_ws, size_t ws_size,
                              hipStream_t stream){
    const float* x0     = (const float*)d_in[0];
    const float* f      = (const float*)d_in[1];
    const float* kA     = (const float*)d_in[2];
    const float* fc1_w1 = (const float*)d_in[3];
    const float* fc1_b1 = (const float*)d_in[4];
    const float* fc1_w2 = (const float*)d_in[5];
    const float* fc1_b2 = (const float*)d_in[6];
    const float* fc2_w1 = (const float*)d_in[7];
    const float* fc2_b1 = (const float*)d_in[8];
    const float* fc2_w2 = (const float*)d_in[9];
    const float* fc2_b2 = (const float*)d_in[10];
    const float* ct1_w  = (const float*)d_in[11];
    const float* ct1_b  = (const float*)d_in[12];
    const float* ct2_w  = (const float*)d_in[13];
    const float* ct2_b  = (const float*)d_in[14];
    const float* ct3_w  = (const float*)d_in[15];
    const float* ct3_b  = (const float*)d_in[16];
    const float* ct4_w  = (const float*)d_in[17];
    const float* ct4_b  = (const float*)d_in[18];
    const float* ct5_w  = (const float*)d_in[19];
    const float* ct5_b  = (const float*)d_in[20];
    float* out = (float*)d_out;

    float* ws = (float*)d_ws;
    size_t off = 0;
    auto take = [&](size_t n){ float* p = ws + off; off += (n + 63) & ~(size_t)63; return p; };
    float* Fr  = take(4096);
    float* Fi  = take(4096);
    float* acc = take(64);
    float* w1b = take((size_t)NB*147);
    float* w2b = take((size_t)NB*147);
    float* vc  = take((size_t)NB*4096);
    float* dvg = take((size_t)NB*64);
    float* c3  = take((size_t)NB*32*289);
    float* c4  = take((size_t)NB*32*1089);
    float* wT1 = take(288);
    float* wT2 = take(9216);
    float* wT3 = take(9216);
    float* wT4 = take(9216);
    float* wT5 = take(576);
    (void)ws_size; (void)in_sizes; (void)n_in; (void)out_size;

    k_hyperprep<<<NB, 256, 0, stream>>>(kA, fc1_w1, fc1_b1, fc1_w2, fc1_b2,
                                        fc2_w1, fc2_b1, fc2_w2, fc2_b2, w1b, w2b,
                                        ct1_w, ct2_w, ct3_w, ct4_w, ct5_w,
                                        wT1, wT2, wT3, wT4, wT5, Fr, Fi, acc);
    k_ct123<<<NB, 512, 0, stream>>>(kA, wT1, wT2, wT3, ct1_b, ct2_b, ct3_b, c3);
    k_ct32c<17><<<NB*2, 512, 0, stream>>>(c3, wT4, ct4_b, c4);
    k_ct5v<<<NB, 512, 0, stream>>>(c4, wT5, ct5_b, vc, dvg);
    k_solve<<<NB, 512, 0, stream>>>(x0, f, kA, w1b, w2b, Fr, Fi, vc, dvg, acc);
    k_final<<<1, 64, 0, stream>>>(acc, out);
}

// Round 12
// 435.631 us; speedup vs baseline: 4.0745x; 1.0066x over previous
//
#include <hip/hip_runtime.h>
#include <math.h>

#define NB   256
#define ND   63
#define NN   3969        // 63*63

__device__ __forceinline__ float gelu_f(float v){
    return 0.5f * v * (1.0f + erff(v * 0.70710678118654752440f));
}

#define FMA4(A, W, S) { (A).x=fmaf((W).x,(S),(A).x); (A).y=fmaf((W).y,(S),(A).y); \
                        (A).z=fmaf((W).z,(S),(A).z); (A).w=fmaf((W).w,(S),(A).w); }

union F4 { float4 v; float a[4]; };
union W16 { float4 v[4]; float a[16]; };

// ---- fused ct1..ct4 per sample. Raw weights transposed in-block; c1/c2/c3
// ---- live in LDS; only c4 (33x33x32 channel-last) goes to global. ----------
__global__ __launch_bounds__(512) void k_ct1234(const float* __restrict__ kA,
                                                const float* __restrict__ cw1,
                                                const float* __restrict__ cw2,
                                                const float* __restrict__ cw3,
                                                const float* __restrict__ cw4,
                                                const float* __restrict__ b1,
                                                const float* __restrict__ b2,
                                                const float* __restrict__ b3,
                                                const float* __restrict__ b4,
                                                float* __restrict__ c4out,
                                                float* __restrict__ acc){
    __shared__ __align__(16) float wbuf[9216];   // [tap][ci][co32], reloaded per stage
    __shared__ float w1s[288];                   // [tap][co32]
    __shared__ float c1s[25*33];                 // [px][ci] stride 33
    __shared__ float c2s[81*33];
    __shared__ float c3s[289*33];
    __shared__ float b1s[32], b2s[32], b3s[32], b4s[32];
    const int b = blockIdx.x, tid = threadIdx.x;
    if (b == 0 && tid == 0) acc[0] = 0.f;
    for (int i = tid; i < 9216; i += 512){
        int ci = i / 288, co = (i / 9) & 31, tap = i % 9;
        wbuf[tap*1024 + ci*32 + co] = cw2[i];
    }
    if (tid < 288) w1s[(tid % 9)*32 + tid/9] = cw1[tid];
    if (tid < 32){ b1s[tid]=b1[tid]; b2s[tid]=b2[tid]; b3s[tid]=b3[tid]; b4s[tid]=b4[tid]; }
    __syncthreads();
    // ---- ct1: 3x3 -> 5x5, 1->32. 200 units ----
    if (tid < 200){
        int px = tid >> 3, q = tid & 7;
        int oy = px / 5, ox = px % 5;
        F4 a4; a4.v = ((const float4*)b1s)[q];
        int nky, kyA[2], iyA[2];
        if (oy & 1){ nky=2; kyA[0]=0; iyA[0]=(oy+1)/2; kyA[1]=2; iyA[1]=(oy-1)/2; }
        else       { nky=1; kyA[0]=1; iyA[0]=oy/2; kyA[1]=1; iyA[1]=0; }
        int nkx, kxA[2], ixA[2];
        if (ox & 1){ nkx=2; kxA[0]=0; ixA[0]=(ox+1)/2; kxA[1]=2; ixA[1]=(ox-1)/2; }
        else       { nkx=1; kxA[0]=1; ixA[0]=ox/2; kxA[1]=1; ixA[1]=0; }
        const float* ab = kA + b*9;
        for (int yi = 0; yi < nky; yi++)
        for (int xi = 0; xi < nkx; xi++){
            float v = ab[iyA[yi]*3 + ixA[xi]];
            float4 w = *(const float4*)(w1s + (kyA[yi]*3 + kxA[xi])*32 + 4*q);
            FMA4(a4.v, w, v);
        }
        float* op = c1s + px*33 + 4*q;
        op[0]=gelu_f(a4.a[0]); op[1]=gelu_f(a4.a[1]);
        op[2]=gelu_f(a4.a[2]); op[3]=gelu_f(a4.a[3]);
    }
    __syncthreads();
    // ---- ct2: 5->9 ----
    for (int u = tid; u < 648; u += 512){
        int px = u >> 3, q = u & 7;
        int oy = px / 9, ox = px % 9;
        F4 a4; a4.v = ((const float4*)b2s)[q];
        int nky, kyA[2], iyA[2];
        if (oy & 1){ nky=2; kyA[0]=0; iyA[0]=(oy+1)/2; kyA[1]=2; iyA[1]=(oy-1)/2; }
        else       { nky=1; kyA[0]=1; iyA[0]=oy/2; kyA[1]=1; iyA[1]=0; }
        int nkx, kxA[2], ixA[2];
        if (ox & 1){ nkx=2; kxA[0]=0; ixA[0]=(ox+1)/2; kxA[1]=2; ixA[1]=(ox-1)/2; }
        else       { nkx=1; kxA[0]=1; ixA[0]=ox/2; kxA[1]=1; ixA[1]=0; }
        for (int yi = 0; yi < nky; yi++)
        for (int xi = 0; xi < nkx; xi++){
            const float* ip = c1s + (iyA[yi]*5 + ixA[xi])*33;
            const float* wp = wbuf + (kyA[yi]*3 + kxA[xi])*1024 + 4*q;
            #pragma unroll 8
            for (int ci = 0; ci < 32; ci++){
                float v = ip[ci];
                float4 w = *(const float4*)(wp + ci*32);
                FMA4(a4.v, w, v);
            }
        }
        float* op = c2s + px*33 + 4*q;
        op[0]=gelu_f(a4.a[0]); op[1]=gelu_f(a4.a[1]);
        op[2]=gelu_f(a4.a[2]); op[3]=gelu_f(a4.a[3]);
    }
    __syncthreads();
    for (int i = tid; i < 9216; i += 512){
        int ci = i / 288, co = (i / 9) & 31, tap = i % 9;
        wbuf[tap*1024 + ci*32 + co] = cw3[i];
    }
    __syncthreads();
    // ---- ct3: 9->17 ----
    for (int u = tid; u < 2312; u += 512){
        int px = u >> 3, q = u & 7;
        int oy = px / 17, ox = px % 17;
        F4 a4; a4.v = ((const float4*)b3s)[q];
        int nky, kyA[2], iyA[2];
        if (oy & 1){ nky=2; kyA[0]=0; iyA[0]=(oy+1)/2; kyA[1]=2; iyA[1]=(oy-1)/2; }
        else       { nky=1; kyA[0]=1; iyA[0]=oy/2; kyA[1]=1; iyA[1]=0; }
        int nkx, kxA[2], ixA[2];
        if (ox & 1){ nkx=2; kxA[0]=0; ixA[0]=(ox+1)/2; kxA[1]=2; ixA[1]=(ox-1)/2; }
        else       { nkx=1; kxA[0]=1; ixA[0]=ox/2; kxA[1]=1; ixA[1]=0; }
        for (int yi = 0; yi < nky; yi++)
        for (int xi = 0; xi < nkx; xi++){
            const float* ip = c2s + (iyA[yi]*9 + ixA[xi])*33;
            const float* wp = wbuf + (kyA[yi]*3 + kxA[xi])*1024 + 4*q;
            #pragma unroll 8
            for (int ci = 0; ci < 32; ci++){
                float v = ip[ci];
                float4 w = *(const float4*)(wp + ci*32);
                FMA4(a4.v, w, v);
            }
        }
        float* op = c3s + px*33 + 4*q;
        op[0]=gelu_f(a4.a[0]); op[1]=gelu_f(a4.a[1]);
        op[2]=gelu_f(a4.a[2]); op[3]=gelu_f(a4.a[3]);
    }
    __syncthreads();
    for (int i = tid; i < 9216; i += 512){
        int ci = i / 288, co = (i / 9) & 31, tap = i % 9;
        wbuf[tap*1024 + ci*32 + co] = cw4[i];
    }
    __syncthreads();
    // ---- ct4: 17->33, output to global channel-last ----
    float* ob = c4out + (size_t)b * (1089*32);
    for (int u = tid; u < 8712; u += 512){
        int px = u >> 3, q = u & 7;
        int oy = px / 33, ox = px % 33;
        F4 a4; a4.v = ((const float4*)b4s)[q];
        int nky, kyA[2], iyA[2];
        if (oy & 1){ nky=2; kyA[0]=0; iyA[0]=(oy+1)/2; kyA[1]=2; iyA[1]=(oy-1)/2; }
        else       { nky=1; kyA[0]=1; iyA[0]=oy/2; kyA[1]=1; iyA[1]=0; }
        int nkx, kxA[2], ixA[2];
        if (ox & 1){ nkx=2; kxA[0]=0; ixA[0]=(ox+1)/2; kxA[1]=2; ixA[1]=(ox-1)/2; }
        else       { nkx=1; kxA[0]=1; ixA[0]=ox/2; kxA[1]=1; ixA[1]=0; }
        for (int yi = 0; yi < nky; yi++)
        for (int xi = 0; xi < nkx; xi++){
            const float* ip = c3s + (iyA[yi]*17 + ixA[xi])*33;
            const float* wp = wbuf + (kyA[yi]*3 + kxA[xi])*1024 + 4*q;
            #pragma unroll 8
            for (int ci = 0; ci < 32; ci++){
                float v = ip[ci];
                float4 w = *(const float4*)(wp + ci*32);
                FMA4(a4.v, w, v);
            }
        }
        float4 g;
        g.x=gelu_f(a4.a[0]); g.y=gelu_f(a4.a[1]);
        g.z=gelu_f(a4.a[2]); g.w=gelu_f(a4.a[3]);
        *(float4*)(ob + (size_t)px*32 + 4*q) = g;
    }
}

// ---------------- mega solver, 512 threads, Hermitian-halved DFT -------------
// 512 threads only (1024-thread blocks hard-cap at 64 VGPR and spill — r6/r7).
// One pass per phase, <=10 acc/lane (r8). F tables generated locally; hypernet
// MLP + ct5 + v-build fused into the prologue (grid-capped occupancy -> LDS is
// free up to 160KB). Iteration loop identical to r11's proven code.
__global__ __launch_bounds__(512) void k_solve(const float* __restrict__ x0g,
                                               const float* __restrict__ f,
                                               const float* __restrict__ kAg,
                                               const float* __restrict__ w1a, const float* __restrict__ b1a,
                                               const float* __restrict__ w2a, const float* __restrict__ b2a,
                                               const float* __restrict__ w1b, const float* __restrict__ b1b,
                                               const float* __restrict__ w2b, const float* __restrict__ b2b,
                                               const float* __restrict__ cw5,
                                               const float* __restrict__ b5,
                                               const float* __restrict__ c4g,
                                               float* __restrict__ accg){
    __shared__ __align__(16) float xs[63*68 + 8];    // row stride 68
    __shared__ __align__(16) float U[8576];          // c5s / rs|tc / rP->MC | TtC->CC
    __shared__ __align__(16) float Fs_r[4096];       // F real (64x64)
    __shared__ __align__(16) float Fs_i[4096];       // F imag
    __shared__ __align__(16) float vcs[4096];        // v rows 0..31 interleaved (f4)
    __shared__ float ws5b[576];
    __shared__ float w1s[148], w2s[148], dvs[64], ds_r[32], ds_i[32], red[8], hs[100];
    const int b = blockIdx.x, tid = threadIdx.x;
    float* rs = U;
    float* tc = U + 4288;
    float*  rP  = U;
    const float4* rP4 = (const float4*)U;
    float2* TtC = (float2*)(U + 4096);
    float2* MC2 = (float2*)U;
    float4* CC4 = (float4*)(U + 4096);
    float* c5s = U;
    const float4* F4r = (const float4*)Fs_r;
    const float4* F4i = (const float4*)Fs_i;
    const float4* vc4s = (const float4*)vcs;
    const float* fg = f + (size_t)b*NN;
    float ka[9];
    #pragma unroll
    for (int i = 0; i < 9; i++) ka[i] = kAg[b*9 + i];

    // ================= prologue =================
    for (int i = tid; i < 4096; i += 512){
        int r = i >> 6, c = i & 63;
        float vr = 0.f, vi = 0.f;
        if (r < 63 && c < 63){
            int m = (r * c) % 63;
            float ang = 6.283185307179586f * (float)m / 63.0f;
            vr = cosf(ang); vi = -sinf(ang);
        }
        Fs_r[i] = vr; Fs_i[i] = vi;
    }
    for (int i = tid; i < 576; i += 512){
        int ci = i / 18, co = (i / 9) & 1, tap = i % 9;
        ws5b[tap*64 + ci*2 + co] = cw5[i];
    }
    for (int i = tid; i < NN; i += 512) xs[(i/ND)*68 + (i%ND)] = x0g[(size_t)b*NN + i];
    // hypernet MLP (both stacks), outputs straight into w1s/w2s
    if (tid < 100){
        float s = b1a[tid];
        #pragma unroll
        for (int i = 0; i < 9; i++) s = fmaf(ka[i], w1a[i*100 + tid], s);
        hs[tid] = gelu_f(s);
    }
    __syncthreads();
    if (tid < 147){
        float s = b2a[tid];
        for (int k = 0; k < 100; k++) s = fmaf(hs[k], w2a[k*147 + tid], s);
        w1s[tid] = s;
    }
    __syncthreads();
    if (tid < 100){
        float s = b1b[tid];
        #pragma unroll
        for (int i = 0; i < 9; i++) s = fmaf(ka[i], w1b[i*100 + tid], s);
        hs[tid] = gelu_f(s);
    }
    __syncthreads();
    if (tid < 147){
        float s = b2b[tid];
        for (int k = 0; k < 100; k++) s = fmaf(hs[k], w2b[k*147 + tid], s);
        w2s[tid] = s;
    }
    // ct5 from c4 -> c5s (in U)
    {
        const float* ib = c4g + (size_t)b * (1089*32);
        float bb0 = b5[0], bb1 = b5[1];
        for (int p = tid; p < NN; p += 512){
            int oy = p / ND, ox = p % ND;
            float a0 = bb0, a1 = bb1;
            int nky, kyA[2], iyA[2];
            if ((oy & 1) == 0){ nky=2; kyA[0]=0; iyA[0]=oy/2+1; kyA[1]=2; iyA[1]=oy/2; }
            else              { nky=1; kyA[0]=1; iyA[0]=(oy+1)/2; kyA[1]=1; iyA[1]=0; }
            int nkx, kxA[2], ixA[2];
            if ((ox & 1) == 0){ nkx=2; kxA[0]=0; ixA[0]=ox/2+1; kxA[1]=2; ixA[1]=ox/2; }
            else              { nkx=1; kxA[0]=1; ixA[0]=(ox+1)/2; kxA[1]=1; ixA[1]=0; }
            for (int yi = 0; yi < nky; yi++)
            for (int xi = 0; xi < nkx; xi++){
                const float* ip = ib + ((size_t)iyA[yi]*33 + ixA[xi])*32;
                const float* wp = ws5b + (kyA[yi]*3 + kxA[xi])*64;
                #pragma unroll
                for (int g = 0; g < 8; g++){
                    F4 iv; iv.v = *(const float4*)(ip + 4*g);
                    #pragma unroll
                    for (int q = 0; q < 4; q++){
                        int ci = 4*g + q;
                        a0 = fmaf(iv.a[q], wp[ci*2],   a0);
                        a1 = fmaf(iv.a[q], wp[ci*2+1], a1);
                    }
                }
            }
            c5s[p]      = a0;
            c5s[NN + p] = a1;
        }
    }
    __syncthreads();
    // build vcs (rows 0..31, interleaved re/im pairs) + dvs
    {
        const float sc = 1.0f / 3969.0f;
        float4* vout = (float4*)vcs;
        for (int i = tid; i < 1024; i += 512){
            int ky = i >> 5, ct2 = i & 31;
            float4 o;
            #pragma unroll
            for (int j = 0; j < 2; j++){
                int kx = 2*ct2 + j;
                float re = 0.f, im = 0.f;
                if (kx <= 31){ int o2 = 2*(ky*ND + kx); re = c5s[o2]*sc; im = c5s[o2+1]*sc; }
                else if (kx <= 62){
                    int sy = (ND - ky) % ND, sx = ND - kx;
                    int o2 = 2*(sy*ND + sx); re = c5s[o2]*sc; im = -c5s[o2+1]*sc;
                }
                if (j == 0){ o.x = re; o.y = im; } else { o.z = re; o.w = im; }
            }
            vout[i] = o;
        }
        if (tid < 32){
            float2 d = {0.f, 0.f};
            if (tid >= 1){
                int iA = (ND - tid) * ND, iB = tid * ND;
                d.x = (c5s[2*iA]     - c5s[2*iB])     * sc;
                d.y = (c5s[2*iA + 1] + c5s[2*iB + 1]) * sc;
            }
            ((float2*)dvs)[tid] = d;
        }
    }
    __syncthreads();

    const int kt = tid >> 4, cg = tid & 15;

    for (int it = 0; it < 5; it++){
        // ---- zero union ----
        { float4 z = {0.f,0.f,0.f,0.f}; float4* U4 = (float4*)U;
          for (int i = tid; i < 2144; i += 512) U4[i] = z; }
        __syncthreads();
        // ---- residual -> rs (col c at idx c+3) ----
        for (int i = tid; i < NN; i += 512){
            int y = i / ND, xx = i % ND;
            float s = 0.f;
            #pragma unroll
            for (int dy = 0; dy < 3; dy++){
                int u = y + dy;
                #pragma unroll
                for (int dx = 0; dx < 3; dx++){
                    int v = xx + dx;
                    float p;
                    if (u == 64 || v == 64)    p = 1.0f;
                    else if (u == 0 || v == 0) p = 0.0f;
                    else                       p = xs[(u-1)*68 + (v-1)];
                    s = fmaf(p, ka[dy*3 + dx], s);
                }
            }
            rs[y*68 + 3 + xx] = fg[i] - s;
        }
        __syncthreads();
        // ---- smoother ----
        const bool act = tid < 504;
        const int y0 = tid >> 3, x0c = 8*(tid & 7);
        float acc2[8] = {};
        for (int c = 0; c < 3; c++){
            if (act){
                float a1[8] = {};
                for (int dy = 0; dy < 7; dy++){
                    int ry = y0 + dy - 3;
                    if (ry < 0 || ry >= 63) continue;
                    W16 w16;
                    const float4* rp = (const float4*)(rs + ry*68 + x0c);
                    w16.v[0]=rp[0]; w16.v[1]=rp[1]; w16.v[2]=rp[2]; w16.v[3]=rp[3];
                    #pragma unroll
                    for (int dx = 0; dx < 7; dx++){
                        float wv = w1s[c*49 + dy*7 + dx];
                        #pragma unroll
                        for (int t = 0; t < 8; t++) a1[t] = fmaf(wv, w16.a[t+dx], a1[t]);
                    }
                }
                int nw = 63 - x0c; if (nw > 8) nw = 8;
                for (int t = 0; t < nw; t++) tc[y0*68 + 3 + x0c + t] = a1[t];
            }
            __syncthreads();
            if (act){
                for (int dy = 0; dy < 7; dy++){
                    int ry = y0 + dy - 3;
                    if (ry < 0 || ry >= 63) continue;
                    W16 w16;
                    const float4* tp = (const float4*)(tc + ry*68 + x0c);
                    w16.v[0]=tp[0]; w16.v[1]=tp[1]; w16.v[2]=tp[2]; w16.v[3]=tp[3];
                    #pragma unroll
                    for (int dx = 0; dx < 7; dx++){
                        float wv = w2s[c*49 + dy*7 + dx];
                        #pragma unroll
                        for (int t = 0; t < 8; t++) acc2[t] = fmaf(wv, w16.a[t+dx], acc2[t]);
                    }
                }
            }
            __syncthreads();
        }
        if (act){
            int nw = 63 - x0c; if (nw > 8) nw = 8;
            for (int t = 0; t < nw; t++) xs[y0*68 + x0c + t] += acc2[t];
        }
        __syncthreads();
        // ---- residual of updated x -> rP ----
        for (int i = tid; i < 4096; i += 512){
            int y = i >> 6, xx = i & 63;
            float val = 0.f;
            if (y < 63 && xx < 63){
                float s = 0.f;
                #pragma unroll
                for (int dy = 0; dy < 3; dy++){
                    int u = y + dy;
                    #pragma unroll
                    for (int dx = 0; dx < 3; dx++){
                        int v = xx + dx;
                        float p;
                        if (u == 64 || v == 64)    p = 1.0f;
                        else if (u == 0 || v == 0) p = 0.0f;
                        else                       p = xs[(u-1)*68 + (v-1)];
                        s = fmaf(p, ka[dy*3 + dx], s);
                    }
                }
                val = fg[y*ND + xx] - s;
            }
            rP[i] = val;
        }
        __syncthreads();
        // ---- Phase A ----
        {
            float tr0=0.f,ti0=0.f,tr1=0.f,ti1=0.f,tr2=0.f,ti2=0.f,tr3=0.f,ti3=0.f;
            for (int m = 0; m < 63; m++){
                float fr = Fs_r[m*64 + kt], fi = Fs_i[m*64 + kt];
                F4 rv; rv.v = rP4[m*16 + cg];
                tr0 = fmaf(fr, rv.a[0], tr0); ti0 = fmaf(fi, rv.a[0], ti0);
                tr1 = fmaf(fr, rv.a[1], tr1); ti1 = fmaf(fi, rv.a[1], ti1);
                tr2 = fmaf(fr, rv.a[2], tr2); ti2 = fmaf(fi, rv.a[2], ti2);
                tr3 = fmaf(fr, rv.a[3], tr3); ti3 = fmaf(fi, rv.a[3], ti3);
            }
            const int c0 = 4*cg;
            TtC[(c0+0)*32 + ((kt + c0 + 0) & 31)] = make_float2(tr0, ti0);
            TtC[(c0+1)*32 + ((kt + c0 + 1) & 31)] = make_float2(tr1, ti1);
            TtC[(c0+2)*32 + ((kt + c0 + 2) & 31)] = make_float2(tr2, ti2);
            TtC[(c0+3)*32 + ((kt + c0 + 3) & 31)] = make_float2(tr3, ti3);
        }
        __syncthreads();
        // ---- Phase B ----
        {
            float R0r=0.f,R0i=0.f,R1r=0.f,R1i=0.f,R2r=0.f,R2i=0.f,R3r=0.f,R3i=0.f;
            for (int n = 0; n < 63; n++){
                float2 T = TtC[n*32 + ((kt + n) & 31)];
                F4 fr, fi;
                fr.v = F4r[n*16 + cg];
                fi.v = F4i[n*16 + cg];
                R0r = fmaf(T.x, fr.a[0], R0r); R0r = fmaf(-T.y, fi.a[0], R0r);
                R0i = fmaf(T.x, fi.a[0], R0i); R0i = fmaf( T.y, fr.a[0], R0i);
                R1r = fmaf(T.x, fr.a[1], R1r); R1r = fmaf(-T.y, fi.a[1], R1r);
                R1i = fmaf(T.x, fi.a[1], R1i); R1i = fmaf( T.y, fr.a[1], R1i);
                R2r = fmaf(T.x, fr.a[2], R2r); R2r = fmaf(-T.y, fi.a[2], R2r);
                R2i = fmaf(T.x, fi.a[2], R2i); R2i = fmaf( T.y, fr.a[2], R2i);
                R3r = fmaf(T.x, fr.a[3], R3r); R3r = fmaf(-T.y, fi.a[3], R3r);
                R3i = fmaf(T.x, fi.a[3], R3i); R3i = fmaf( T.y, fr.a[3], R3i);
            }
            if (cg == 0){
                float2 dv = ((const float2*)dvs)[kt];
                ds_r[kt] = R0r*dv.x + R0i*dv.y;
                ds_i[kt] = R0r*dv.y - R0i*dv.x;
            }
            float4 vA = vc4s[kt*32 + 2*cg];
            float4 vB = vc4s[kt*32 + 2*cg + 1];
            const int c0 = 4*cg, rot = kt;
            MC2[kt*64 + ((c0+0 + rot) & 63)] = make_float2(R0r*vA.x - R0i*vA.y, R0r*vA.y + R0i*vA.x);
            MC2[kt*64 + ((c0+1 + rot) & 63)] = make_float2(R1r*vA.z - R1i*vA.w, R1r*vA.w + R1i*vA.z);
            MC2[kt*64 + ((c0+2 + rot) & 63)] = make_float2(R2r*vB.x - R2i*vB.y, R2r*vB.y + R2i*vB.x);
            MC2[kt*64 + ((c0+3 + rot) & 63)] = make_float2(R3r*vB.z - R3i*vB.w, R3r*vB.w + R3i*vB.z);
        }
        __syncthreads();
        // ---- Phase D ----
        {
            float C0r=0.f,C0i=0.f,C1r=0.f,C1i=0.f,C2r=0.f,C2i=0.f,C3r=0.f,C3i=0.f;
            const int rot = kt;
            for (int l = 0; l < 63; l++){
                float2 Mv = MC2[kt*64 + ((l + rot) & 63)];
                F4 fr, fi;
                fr.v = F4r[l*16 + cg];
                fi.v = F4i[l*16 + cg];
                C0r = fmaf(Mv.x, fr.a[0], C0r); C0r = fmaf( Mv.y, fi.a[0], C0r);
                C0i = fmaf(Mv.y, fr.a[0], C0i); C0i = fmaf(-Mv.x, fi.a[0], C0i);
                C1r = fmaf(Mv.x, fr.a[1], C1r); C1r = fmaf( Mv.y, fi.a[1], C1r);
                C1i = fmaf(Mv.y, fr.a[1], C1i); C1i = fmaf(-Mv.x, fi.a[1], C1i);
                C2r = fmaf(Mv.x, fr.a[2], C2r); C2r = fmaf( Mv.y, fi.a[2], C2r);
                C2i = fmaf(Mv.y, fr.a[2], C2i); C2i = fmaf(-Mv.x, fi.a[2], C2i);
                C3r = fmaf(Mv.x, fr.a[3], C3r); C3r = fmaf( Mv.y, fi.a[3], C3r);
                C3i = fmaf(Mv.y, fr.a[3], C3i); C3i = fmaf(-Mv.x, fi.a[3], C3i);
            }
            float sc2 = (kt == 0) ? 0.5f : 1.0f;
            CC4[kt*33 + 2*cg]     = make_float4(C0r*sc2, C0i*sc2, C1r*sc2, C1i*sc2);
            CC4[kt*33 + 2*cg + 1] = make_float4(C2r*sc2, C2i*sc2, C3r*sc2, C3i*sc2);
        }
        __syncthreads();
        // ---- Phase E ----
        {
            const int p = tid >> 3, qb = tid & 7;
            if (p < 63){
                float y0v=0.f,y1v=0.f,y2v=0.f,y3v=0.f,y4v=0.f,y5v=0.f,y6v=0.f,y7v=0.f,e=0.f;
                for (int n = 0; n < 32; n++){
                    float fr = Fs_r[n*64 + p], fi = Fs_i[n*64 + p];
                    float4 cA = CC4[n*33 + qb];
                    float4 cB = CC4[n*33 + qb + 8];
                    float4 cC = CC4[n*33 + qb + 16];
                    float4 cD = CC4[n*33 + qb + 24];
                    y0v = fmaf(fr, cA.x, y0v); y0v = fmaf(fi, cA.y, y0v);
                    y1v = fmaf(fr, cA.z, y1v); y1v = fmaf(fi, cA.w, y1v);
                    y2v = fmaf(fr, cB.x, y2v); y2v = fmaf(fi, cB.y, y2v);
                    y3v = fmaf(fr, cB.z, y3v); y3v = fmaf(fi, cB.w, y3v);
                    y4v = fmaf(fr, cC.x, y4v); y4v = fmaf(fi, cC.y, y4v);
                    y5v = fmaf(fr, cC.z, y5v); y5v = fmaf(fi, cC.w, y5v);
                    y6v = fmaf(fr, cD.x, y6v); y6v = fmaf(fi, cD.y, y6v);
                    y7v = fmaf(fr, cD.z, y7v); y7v = fmaf(fi, cD.w, y7v);
                    e  = fmaf(fr, ds_r[n], e); e = fmaf(-fi, ds_i[n], e);
                }
                float* xrow = xs + p*68;
                float2* xp0 = (float2*)(xrow + 2*qb);
                float2* xp1 = (float2*)(xrow + 2*qb + 16);
                float2* xp2 = (float2*)(xrow + 2*qb + 32);
                float2* xp3 = (float2*)(xrow + 2*qb + 48);
                float2 v0 = *xp0, v1 = *xp1, v2 = *xp2, v3 = *xp3;
                v0.x += 2.f*y0v + e; v0.y += 2.f*y1v + e;
                v1.x += 2.f*y2v + e; v1.y += 2.f*y3v + e;
                v2.x += 2.f*y4v + e; v2.y += 2.f*y5v + e;
                v3.x += 2.f*y6v + e; v3.y += 2.f*y7v + e;
                *xp0 = v0; *xp1 = v1; *xp2 = v2; *xp3 = v3;
            }
        }
        __syncthreads();
    }
    // ---- final residual + norm ----
    float s = 0.f;
    for (int i = tid; i < NN; i += 512){
        int y = i / ND, xx = i % ND;
        float cv = 0.f;
        #pragma unroll
        for (int dy = 0; dy < 3; dy++){
            int u = y + dy;
            #pragma unroll
            for (int dx = 0; dx < 3; dx++){
                int v = xx + dx;
                float p;
                if (u == 64 || v == 64)    p = 1.0f;
                else if (u == 0 || v == 0) p = 0.0f;
                else                       p = xs[(u-1)*68 + (v-1)];
                cv = fmaf(p, ka[dy*3 + dx], cv);
            }
        }
        float r = fg[i] - cv;
        s = fmaf(r, r, s);
    }
    #pragma unroll
    for (int off = 32; off > 0; off >>= 1) s += __shfl_down(s, off, 64);
    int lane = tid & 63, w = tid >> 6;
    if (lane == 0) red[w] = s;
    __syncthreads();
    if (tid == 0){
        float t = 0.f;
        #pragma unroll
        for (int i = 0; i < 8; i++) t += red[i];
        atomicAdd(accg, t);
    }
}

__global__ void k_final(const float* __restrict__ acc, float* __restrict__ out){
    if (threadIdx.x == 0 && blockIdx.x == 0) out[0] = sqrtf(acc[0]) * (1.0f/256.0f);
}

// ---------------- host ------------------------------------------------------
extern "C" void kernel_launch(void* const* d_in, const int* in_sizes, int n_in,
                              void* d_out, int out_size, void* d_ws, size_t ws_size,
                              hipStream_t stream){
    const float* x0     = (const float*)d_in[0];
    const float* f      = (const float*)d_in[1];
    const float* kA     = (const float*)d_in[2];
    const float* fc1_w1 = (const float*)d_in[3];
    const float* fc1_b1 = (const float*)d_in[4];
    const float* fc1_w2 = (const float*)d_in[5];
    const float* fc1_b2 = (const float*)d_in[6];
    const float* fc2_w1 = (const float*)d_in[7];
    const float* fc2_b1 = (const float*)d_in[8];
    const float* fc2_w2 = (const float*)d_in[9];
    const float* fc2_b2 = (const float*)d_in[10];
    const float* ct1_w  = (const float*)d_in[11];
    const float* ct1_b  = (const float*)d_in[12];
    const float* ct2_w  = (const float*)d_in[13];
    const float* ct2_b  = (const float*)d_in[14];
    const float* ct3_w  = (const float*)d_in[15];
    const float* ct3_b  = (const float*)d_in[16];
    const float* ct4_w  = (const float*)d_in[17];
    const float* ct4_b  = (const float*)d_in[18];
    const float* ct5_w  = (const float*)d_in[19];
    const float* ct5_b  = (const float*)d_in[20];
    float* out = (float*)d_out;

    float* ws = (float*)d_ws;
    size_t off = 0;
    auto take = [&](size_t n){ float* p = ws + off; off += (n + 63) & ~(size_t)63; return p; };
    float* acc = take(64);
    float* c4  = take((size_t)NB*32*1089);
    (void)ws_size; (void)in_sizes; (void)n_in; (void)out_size;

    k_ct1234<<<NB, 512, 0, stream>>>(kA, ct1_w, ct2_w, ct3_w, ct4_w,
                                     ct1_b, ct2_b, ct3_b, ct4_b, c4, acc);
    k_solve<<<NB, 512, 0, stream>>>(x0, f, kA,
                                    fc1_w1, fc1_b1, fc1_w2, fc1_b2,
                                    fc2_w1, fc2_b1, fc2_w2, fc2_b2,
                                    ct5_w, ct5_b, c4, acc);
    k_final<<<1, 64, 0, stream>>>(acc, out);
}